// Round 9
// baseline (3756.310 us; speedup 1.0000x reference)
//
#include <hip/hip_runtime.h>

#define DEV __device__ __forceinline__

static constexpr int NN = 50000;   // nodes
static constexpr int DD = 256;     // input dim
static constexpr int HH = 128;     // hidden
static constexpr int CC = 40;      // classes
static constexpr int KK = 4;       // envs
static constexpr int EE = 800000;  // edges
static constexpr int MP = 50176;   // padded node count (196*256, mult of 32)
static constexpr int SKV = 196;    // split-K blocks for ktv
static constexpr int CPB = 8;      // 32-node chunks per ktv block
static constexpr int CSB = 391;    // colstats / scan blocks (ceil(NN/128))

typedef __attribute__((ext_vector_type(8))) short bf16x8;
typedef __attribute__((ext_vector_type(4))) float f32x4;

DEV unsigned short f2bf(float f) {
  union { float f; unsigned int i; } c; c.f = f;
  unsigned int x = c.i;
  x += 0x7FFFu + ((x >> 16) & 1u);   // round-to-nearest-even
  return (unsigned short)(x >> 16);
}
DEV float bfbits2f(unsigned int hi16bits) {
  union { unsigned int i; float f; } c; c.i = hi16bits; return c.f;
}

// harness-named kernel (unused in pipeline)
__global__ void MLEI_12970801234193_kernel(float* out, int n) {
  int i = blockIdx.x * blockDim.x + threadIdx.x;
  if (i < n) out[i] = 7.0f;
}

__global__ void zero_i32_kernel(int* p, int n) {
  int i = blockIdx.x * blockDim.x + threadIdx.x;
  if (i < n) p[i] = 0;
}

// zero the pad columns [NN, MP) of the transposed bf16 k/v buffers
__global__ void padzero_kernel(unsigned short* kT, unsigned short* vT) {
  int i = blockIdx.x * blockDim.x + threadIdx.x;
  const int PW = MP - NN;  // 176
  if (i >= HH * PW) return;
  int f = i / PW, c = i - f * PW;
  kT[(size_t)f * MP + NN + c] = 0;
  vT[(size_t)f * MP + NN + c] = 0;
}

// transpose-convert: dst[m][n][k] = bf16(src[m][k][n]); nm matrices of K x N
__global__ void tcvt_kernel(const float* __restrict__ src, unsigned short* __restrict__ dst,
                            int K, int N, int nm) {
  int i = blockIdx.x * blockDim.x + threadIdx.x;
  int tot = nm * K * N;
  if (i >= tot) return;
  int m = i / (K * N);
  int rem = i - m * K * N;
  int k = rem / N;
  int n = rem - k * N;
  dst[(size_t)m * K * N + (size_t)n * K + k] = f2bf(src[i]);
}

// ---------------- generic bf16-MFMA GEMM (R3 structure + raw bf16 twin out) ----------------
__global__ __launch_bounds__(256) void mgemm_kernel(
    const float* __restrict__ A, const float* __restrict__ Aadd, int lda,
    const unsigned short* __restrict__ Bt, int K,
    int emode, float* __restrict__ out, int ldo,
    const float* __restrict__ bias, const float* __restrict__ resid, int ldr,
    const float* __restrict__ anorm, const float* __restrict__ red,
    unsigned short* __restrict__ outT,
    unsigned short* __restrict__ outBf, const float* __restrict__ rowscale,
    unsigned short* __restrict__ outBfRaw,
    int M, int Nd) {
  __shared__ unsigned short As[2][128][40];
  __shared__ unsigned short Bs[2][128][40];
  const int tid = threadIdx.x, lane = tid & 63, wave = tid >> 6;
  const int quad = lane >> 4, l16 = lane & 15;
  const int wm = (wave >> 1) * 64, wn = (wave & 1) * 64;
  const int bm = blockIdx.x * 128;
  const int srow = tid >> 1, skh = (tid & 1) * 16;
  const int grow = bm + srow;
  const bool rowok = grow < M;
  const bool colok = srow < Nd;
  const int NCH = K >> 5;

  f32x4 acc[4][4];
#pragma unroll
  for (int i = 0; i < 4; ++i)
#pragma unroll
    for (int j = 0; j < 4; ++j)
#pragma unroll
      for (int r = 0; r < 4; ++r) acc[i][j][r] = 0.f;

  float vaA[16], vaB[16];
  bf16x8 bA0, bA1, bB0, bB1;

  auto LOAD = [&](int kc, float (&va)[16], bf16x8& b0, bf16x8& b1) {
    int k0 = kc << 5;
    if (rowok) {
      const float* ap = A + (size_t)grow * lda + k0 + skh;
      float4 v0 = *(const float4*)(ap + 0), v1 = *(const float4*)(ap + 4);
      float4 v2 = *(const float4*)(ap + 8), v3 = *(const float4*)(ap + 12);
      va[0] = v0.x; va[1] = v0.y; va[2] = v0.z; va[3] = v0.w;
      va[4] = v1.x; va[5] = v1.y; va[6] = v1.z; va[7] = v1.w;
      va[8] = v2.x; va[9] = v2.y; va[10] = v2.z; va[11] = v2.w;
      va[12] = v3.x; va[13] = v3.y; va[14] = v3.z; va[15] = v3.w;
      if (Aadd) {
        const float* ap2 = Aadd + (size_t)grow * lda + k0 + skh;
        float4 w0 = *(const float4*)(ap2 + 0), w1 = *(const float4*)(ap2 + 4);
        float4 w2 = *(const float4*)(ap2 + 8), w3 = *(const float4*)(ap2 + 12);
        va[0] += w0.x; va[1] += w0.y; va[2] += w0.z; va[3] += w0.w;
        va[4] += w1.x; va[5] += w1.y; va[6] += w1.z; va[7] += w1.w;
        va[8] += w2.x; va[9] += w2.y; va[10] += w2.z; va[11] += w2.w;
        va[12] += w3.x; va[13] += w3.y; va[14] += w3.z; va[15] += w3.w;
      }
    }
    if (colok) {
      const unsigned short* bp = Bt + (size_t)srow * K + k0 + skh;
      b0 = *(const bf16x8*)(bp);
      b1 = *(const bf16x8*)(bp + 8);
    } else {
#pragma unroll
      for (int z = 0; z < 8; ++z) { b0[z] = 0; b1[z] = 0; }
    }
  };

  auto STORE = [&](int buf, const float (&va)[16], const bf16x8& b0, const bf16x8& b1) {
    bf16x8 p0, p1;
    if (rowok) {
#pragma unroll
      for (int z = 0; z < 8; ++z) { p0[z] = (short)f2bf(va[z]); p1[z] = (short)f2bf(va[z + 8]); }
    } else {
#pragma unroll
      for (int z = 0; z < 8; ++z) { p0[z] = 0; p1[z] = 0; }
    }
    *(bf16x8*)&As[buf][srow][skh] = p0;
    *(bf16x8*)&As[buf][srow][skh + 8] = p1;
    *(bf16x8*)&Bs[buf][srow][skh] = b0;
    *(bf16x8*)&Bs[buf][srow][skh + 8] = b1;
  };

  auto MFMA = [&](int buf) {
    bf16x8 af[4], bfr[4];
#pragma unroll
    for (int i = 0; i < 4; ++i) af[i] = *(const bf16x8*)&As[buf][wm + i * 16 + l16][quad * 8];
#pragma unroll
    for (int j = 0; j < 4; ++j) bfr[j] = *(const bf16x8*)&Bs[buf][wn + j * 16 + l16][quad * 8];
#pragma unroll
    for (int i = 0; i < 4; ++i)
#pragma unroll
      for (int j = 0; j < 4; ++j)
        acc[i][j] = __builtin_amdgcn_mfma_f32_16x16x32_bf16(af[i], bfr[j], acc[i][j], 0, 0, 0);
  };

  LOAD(0, vaA, bA0, bA1);
  if (NCH > 1) LOAD(1, vaB, bB0, bB1);
  STORE(0, vaA, bA0, bA1);
  __syncthreads();

  for (int kc = 0; kc < NCH; kc += 2) {
    if (kc + 2 < NCH) LOAD(kc + 2, vaA, bA0, bA1);
    MFMA(0);
    if (kc + 1 < NCH) STORE(1, vaB, bB0, bB1);
    __syncthreads();
    if (kc + 1 < NCH) {
      if (kc + 3 < NCH) LOAD(kc + 3, vaB, bB0, bB1);
      MFMA(1);
      if (kc + 2 < NCH) STORE(0, vaA, bA0, bA1);
      __syncthreads();
    }
  }

  float s2 = (emode == 3) ? red[2] : 0.f;
#pragma unroll
  for (int j = 0; j < 4; ++j) {
    int col = wn + j * 16 + l16;
    if (col >= Nd) continue;
    float bv = bias ? bias[col] : 0.f;
#pragma unroll
    for (int i = 0; i < 4; ++i) {
      int row0 = bm + wm + i * 16 + quad * 4;
      if (row0 >= M) continue;
      float o[4];
#pragma unroll
      for (int r = 0; r < 4; ++r) {
        float a = acc[i][j][r];
        int row = row0 + r;
        if (emode == 0) o[r] = a + bv;
        else if (emode == 1) o[r] = fmaxf(a + bv, 0.f);
        else if (emode == 3) o[r] = (resid[(size_t)row * ldr + col] + a * s2) / anorm[row];
        else o[r] = 0.5f * a + bv;
        out[(size_t)row * ldo + col] = o[r];
      }
      if (outT) {
        ushort4 pk;
        pk.x = f2bf(o[0]); pk.y = f2bf(o[1]); pk.z = f2bf(o[2]); pk.w = f2bf(o[3]);
        *(ushort4*)&outT[(size_t)col * MP + row0] = pk;
      }
      if (outBf) {
#pragma unroll
        for (int r = 0; r < 4; ++r) {
          float rs = rowscale ? rowscale[row0 + r] : 1.f;
          outBf[(size_t)(row0 + r) * 128 + col] = f2bf(o[r] * rs);
        }
      }
      if (outBfRaw) {
#pragma unroll
        for (int r = 0; r < 4; ++r)
          outBfRaw[(size_t)(row0 + r) * 128 + col] = f2bf(o[r]);
      }
    }
  }
}

// ---------------- split-K MFMA kT@v (R3 structure) ----------------
__global__ __launch_bounds__(256) void ktv_mfma_kernel(
    const unsigned short* __restrict__ kT, const unsigned short* __restrict__ vT,
    float* __restrict__ part) {
  __shared__ unsigned short As[2][128][40];
  __shared__ unsigned short Bs[2][128][40];
  const int tid = threadIdx.x, lane = tid & 63, wave = tid >> 6;
  const int quad = lane >> 4, l16 = lane & 15;
  const int wm = (wave >> 1) * 64, wn = (wave & 1) * 64;
  const int srow = tid >> 1, skh = (tid & 1) * 16;

  f32x4 acc[4][4];
#pragma unroll
  for (int i = 0; i < 4; ++i)
#pragma unroll
    for (int j = 0; j < 4; ++j)
#pragma unroll
      for (int r = 0; r < 4; ++r) acc[i][j][r] = 0.f;

  const int nb0 = blockIdx.x * (CPB * 32);
  bf16x8 kA0, kA1, vA0, vA1, kB0, kB1, vB0, vB1;

  auto LOAD = [&](int c, bf16x8& k0, bf16x8& k1, bf16x8& v0, bf16x8& v1) {
    int nb = nb0 + c * 32;
    const unsigned short* kp = kT + (size_t)srow * MP + nb + skh;
    k0 = *(const bf16x8*)(kp);
    k1 = *(const bf16x8*)(kp + 8);
    const unsigned short* vp = vT + (size_t)srow * MP + nb + skh;
    v0 = *(const bf16x8*)(vp);
    v1 = *(const bf16x8*)(vp + 8);
  };
  auto STORE = [&](int buf, const bf16x8& k0, const bf16x8& k1, const bf16x8& v0, const bf16x8& v1) {
    *(bf16x8*)&As[buf][srow][skh] = k0;
    *(bf16x8*)&As[buf][srow][skh + 8] = k1;
    *(bf16x8*)&Bs[buf][srow][skh] = v0;
    *(bf16x8*)&Bs[buf][srow][skh + 8] = v1;
  };
  auto MFMA = [&](int buf) {
    bf16x8 af[4], bfr[4];
#pragma unroll
    for (int i = 0; i < 4; ++i) af[i] = *(const bf16x8*)&As[buf][wm + i * 16 + l16][quad * 8];
#pragma unroll
    for (int j = 0; j < 4; ++j) bfr[j] = *(const bf16x8*)&Bs[buf][wn + j * 16 + l16][quad * 8];
#pragma unroll
    for (int i = 0; i < 4; ++i)
#pragma unroll
      for (int j = 0; j < 4; ++j)
        acc[i][j] = __builtin_amdgcn_mfma_f32_16x16x32_bf16(af[i], bfr[j], acc[i][j], 0, 0, 0);
  };

  LOAD(0, kA0, kA1, vA0, vA1);
  LOAD(1, kB0, kB1, vB0, vB1);
  STORE(0, kA0, kA1, vA0, vA1);
  __syncthreads();

  for (int c = 0; c < CPB; c += 2) {
    if (c + 2 < CPB) LOAD(c + 2, kA0, kA1, vA0, vA1);
    MFMA(0);
    if (c + 1 < CPB) STORE(1, kB0, kB1, vB0, vB1);
    __syncthreads();
    if (c + 1 < CPB) {
      if (c + 3 < CPB) LOAD(c + 3, kB0, kB1, vB0, vB1);
      MFMA(1);
      if (c + 2 < CPB) STORE(0, kA0, kA1, vA0, vA1);
      __syncthreads();
    }
  }

  float* pb = part + (size_t)blockIdx.x * 16384;
#pragma unroll
  for (int j = 0; j < 4; ++j) {
    int col = wn + j * 16 + l16;
#pragma unroll
    for (int i = 0; i < 4; ++i) {
      int row0 = wm + i * 16 + quad * 4;
      *(f32x4*)&pb[col * 128 + row0] = acc[i][j];
    }
  }
}

__global__ void ktv_reduce_kernel(const float* __restrict__ part,
                                  unsigned short* __restrict__ Btktv) {
  int i = blockIdx.x * blockDim.x + threadIdx.x;
  if (i >= 16384) return;
  float s0 = 0.f, s1 = 0.f, s2 = 0.f, s3 = 0.f;
  int b = 0;
  for (; b + 3 < SKV; b += 4) {
    s0 += part[(size_t)b * 16384 + i];
    s1 += part[(size_t)(b + 1) * 16384 + i];
    s2 += part[(size_t)(b + 2) * 16384 + i];
    s3 += part[(size_t)(b + 3) * 16384 + i];
  }
  for (; b < SKV; ++b) s0 += part[(size_t)b * 16384 + i];
  Btktv[i] = f2bf((s0 + s1) + (s2 + s3));
}

// ---------------- env-weighted MFMA GEMM (conv & ctx) ----------------
// out[n,:] = sum_e env[n,e] * (hi[n,:] @ W_e), hi = [A1bf | A2bf] (bf16).
// e-OUTER / kc-inner: per env, accumulate hi @ W_e into acc; at env boundary
// fold accF += envT[e][row] * acc (output-side weighting). Staging is a pure
// bf16 copy (zero VALU), 2 register sets give a full-phase load->ds_write
// distance. A tiles re-read per env from L2 (64KB/block, L2-hot).
__global__ __launch_bounds__(256) void mconv_kernel(
    const unsigned short* __restrict__ A1bf, const unsigned short* __restrict__ A2bf,
    const float* __restrict__ envT,  // [KK][NN] transposed
    const unsigned short* __restrict__ Btc, int Kpe,
    int relu_resid, const float* __restrict__ resid, float* __restrict__ out,
    unsigned short* __restrict__ outBf, const float* __restrict__ rowscale,
    unsigned short* __restrict__ outBfRaw, int M) {
  __shared__ unsigned short As[2][128][40];
  __shared__ unsigned short Bs[2][128][40];
  const int tid = threadIdx.x, lane = tid & 63, wave = tid >> 6;
  const int quad = lane >> 4, l16 = lane & 15;
  const int wm = (wave >> 1) * 64, wn = (wave & 1) * 64;
  const int bm = blockIdx.x * 128;
  const int srow = tid >> 1, skh = (tid & 1) * 16;
  const int grow = bm + srow;
  const bool rowok = grow < M;
  const int nch = Kpe >> 5;            // K-chunks per env (8 conv / 4 ctx)
  const int lg = (nch == 8) ? 3 : 2;
  const int NPH = nch << 2;

  f32x4 acc[4][4], accF[4][4];
#pragma unroll
  for (int i = 0; i < 4; ++i)
#pragma unroll
    for (int j = 0; j < 4; ++j)
#pragma unroll
      for (int r = 0; r < 4; ++r) { acc[i][j][r] = 0.f; accF[i][j][r] = 0.f; }

  float4 fe[4];  // envT[e] for this thread's 4 row-quads, prefetched per env
  auto LOADEV = [&](int e) {
#pragma unroll
    for (int i = 0; i < 4; ++i) {
      int r0 = bm + wm + i * 16 + quad * 4;
      if (r0 > M - 4) r0 = M - 4;
      fe[i] = *(const float4*)&envT[(size_t)e * NN + r0];
    }
  };

  bf16x8 aS[2][2], bS[2][2];  // 2 register sets (phase-deep prefetch)

  auto LOADP = [&](int p, int s) {
    int e = p >> lg;
    int kc = p & (nch - 1);
    int kof = kc << 5;
    const unsigned short* Asrc = A1bf;
    int ks = kof;
    if (A2bf && kof >= 128) { Asrc = A2bf; ks = kof - 128; }
    if (rowok) {
      const unsigned short* ap = Asrc + (size_t)grow * 128 + ks + skh;
      aS[s][0] = *(const bf16x8*)(ap);
      aS[s][1] = *(const bf16x8*)(ap + 8);
    } else {
#pragma unroll
      for (int z = 0; z < 8; ++z) { aS[s][0][z] = 0; aS[s][1][z] = 0; }
    }
    const unsigned short* bp = Btc + ((size_t)e * 128 + srow) * Kpe + kof + skh;
    bS[s][0] = *(const bf16x8*)(bp);
    bS[s][1] = *(const bf16x8*)(bp + 8);
  };

  auto STORE = [&](int buf, int s) {
    *(bf16x8*)&As[buf][srow][skh] = aS[s][0];
    *(bf16x8*)&As[buf][srow][skh + 8] = aS[s][1];
    *(bf16x8*)&Bs[buf][srow][skh] = bS[s][0];
    *(bf16x8*)&Bs[buf][srow][skh + 8] = bS[s][1];
  };

  auto MFMA = [&](int buf) {
    bf16x8 af[4], bfr[4];
#pragma unroll
    for (int i = 0; i < 4; ++i) af[i] = *(const bf16x8*)&As[buf][wm + i * 16 + l16][quad * 8];
#pragma unroll
    for (int j = 0; j < 4; ++j) bfr[j] = *(const bf16x8*)&Bs[buf][wn + j * 16 + l16][quad * 8];
#pragma unroll
    for (int i = 0; i < 4; ++i)
#pragma unroll
      for (int j = 0; j < 4; ++j)
        acc[i][j] = __builtin_amdgcn_mfma_f32_16x16x32_bf16(af[i], bfr[j], acc[i][j], 0, 0, 0);
  };

  LOADEV(0);
  LOADP(0, 0);
  if (NPH > 1) LOADP(1, 1);
  STORE(0, 0);
  __syncthreads();

  for (int p = 0; p < NPH; ++p) {
    const int cur = p & 1;
    if (p + 2 < NPH) LOADP(p + 2, cur);        // set cur was stored last phase
    MFMA(cur);
    if ((p & (nch - 1)) == nch - 1) {
      // env boundary: fold acc into accF with per-row env weight, reset acc
#pragma unroll
      for (int i = 0; i < 4; ++i)
#pragma unroll
        for (int j = 0; j < 4; ++j)
#pragma unroll
          for (int r = 0; r < 4; ++r) {
            float ev = (r == 0) ? fe[i].x : (r == 1) ? fe[i].y : (r == 2) ? fe[i].z : fe[i].w;
            accF[i][j][r] += ev * acc[i][j][r];
            acc[i][j][r] = 0.f;
          }
      int e = p >> lg;
      if (e < 3) LOADEV(e + 1);
    }
    if (p + 1 < NPH) STORE(cur ^ 1, cur ^ 1);  // set loaded last phase -> full cover
    __syncthreads();
  }

#pragma unroll
  for (int j = 0; j < 4; ++j) {
    int col = wn + j * 16 + l16;
#pragma unroll
    for (int i = 0; i < 4; ++i) {
      int row0 = bm + wm + i * 16 + quad * 4;
      if (row0 >= M) continue;
#pragma unroll
      for (int r = 0; r < 4; ++r) {
        int row = row0 + r;
        float a = accF[i][j][r];
        float o = relu_resid ? fmaxf(a + resid[(size_t)row * 128 + col], 0.f) : a;
        out[(size_t)row * 128 + col] = o;
        if (outBf) {
          float rs = rowscale ? rowscale[row] : 1.f;
          outBf[(size_t)row * 128 + col] = f2bf(o * rs);
        }
        if (outBfRaw) outBfRaw[(size_t)row * 128 + col] = f2bf(o);
      }
    }
  }
}

// ---------------- graph kernels ----------------
__global__ void count_kernel(const int* ei, int* deg, int E) {
  int e = blockIdx.x * blockDim.x + threadIdx.x;
  if (e >= E) return;
  atomicAdd(&deg[ei[E + e]], 1);
}

__global__ __launch_bounds__(128) void scan1_kernel(const int* __restrict__ deg,
                                                    int* __restrict__ bsum, int n) {
  __shared__ int sh[128];
  int t = threadIdx.x;
  int i = blockIdx.x * 128 + t;
  sh[t] = (i < n) ? deg[i] : 0;
  __syncthreads();
  for (int off = 64; off > 0; off >>= 1) {
    if (t < off) sh[t] += sh[t + off];
    __syncthreads();
  }
  if (t == 0) bsum[blockIdx.x] = sh[0];
}

__global__ __launch_bounds__(512) void scan2_kernel(const int* __restrict__ bsum,
                                                    int* __restrict__ boff, int nb,
                                                    int* __restrict__ startN) {
  __shared__ int sh[512];
  int t = threadIdx.x;
  int v0 = (t < nb) ? bsum[t] : 0;
  sh[t] = v0;
  __syncthreads();
  for (int off = 1; off < 512; off <<= 1) {
    int v = sh[t];
    int add = (t >= off) ? sh[t - off] : 0;
    __syncthreads();
    sh[t] = v + add;
    __syncthreads();
  }
  if (t < nb) boff[t] = sh[t] - v0;
  if (t == nb - 1) *startN = sh[t];
}

__global__ __launch_bounds__(128) void scan3_kernel(const int* __restrict__ deg,
                                                    const int* __restrict__ boff,
                                                    int* __restrict__ start,
                                                    int* __restrict__ cursor,
                                                    float* __restrict__ inv, int n) {
  __shared__ int sh[128];
  int t = threadIdx.x;
  int i = blockIdx.x * 128 + t;
  int d = (i < n) ? deg[i] : 0;
  sh[t] = d;
  __syncthreads();
  for (int off = 1; off < 128; off <<= 1) {
    int v = sh[t];
    int add = (t >= off) ? sh[t - off] : 0;
    __syncthreads();
    sh[t] = v + add;
    __syncthreads();
  }
  if (i < n) {
    int p = boff[blockIdx.x] + sh[t] - d;
    start[i] = p; cursor[i] = p;
    inv[i] = (d > 0) ? rsqrtf((float)d) : 0.f;
  }
}

__global__ void fill_kernel(const int* ei, int* cursor, int* bucket, int E) {
  int e = blockIdx.x * blockDim.x + threadIdx.x;
  if (e >= E) return;
  int r = ei[e], c = ei[E + e];
  int pos = atomicAdd(&cursor[c], 1);
  bucket[pos] = r;
}

// gather from pre-scaled bf16 h -> bf16 agg: aggbf[n,f] = bf16(inv[n]*sum hs[src][f])
__global__ __launch_bounds__(256) void gather_kernel(
    const unsigned short* __restrict__ hs, const int* __restrict__ start,
    const int* __restrict__ bucket, const float* __restrict__ inv,
    unsigned short* __restrict__ aggbf, int n) {
  int node = blockIdx.x * 4 + (threadIdx.x >> 6);
  if (node >= n) return;
  const int lane = threadIdx.x & 63;
  const int half = lane >> 5, l32 = lane & 31;
  const int f4 = l32 * 4;
  int s0 = start[node], s1 = start[node + 1];
  float a0 = 0.f, a1 = 0.f, a2 = 0.f, a3 = 0.f;
  int j = s0 + half;
  for (; j + 2 < s1; j += 4) {
    int r0 = bucket[j], r1 = bucket[j + 2];
    uint2 u0 = *(const uint2*)&hs[(size_t)r0 * 128 + f4];
    uint2 u1 = *(const uint2*)&hs[(size_t)r1 * 128 + f4];
    a0 += bfbits2f(u0.x << 16); a1 += bfbits2f(u0.x & 0xFFFF0000u);
    a2 += bfbits2f(u0.y << 16); a3 += bfbits2f(u0.y & 0xFFFF0000u);
    a0 += bfbits2f(u1.x << 16); a1 += bfbits2f(u1.x & 0xFFFF0000u);
    a2 += bfbits2f(u1.y << 16); a3 += bfbits2f(u1.y & 0xFFFF0000u);
  }
  for (; j < s1; j += 2) {
    int r = bucket[j];
    uint2 u = *(const uint2*)&hs[(size_t)r * 128 + f4];
    a0 += bfbits2f(u.x << 16); a1 += bfbits2f(u.x & 0xFFFF0000u);
    a2 += bfbits2f(u.y << 16); a3 += bfbits2f(u.y & 0xFFFF0000u);
  }
  a0 += __shfl_xor(a0, 32);
  a1 += __shfl_xor(a1, 32);
  a2 += __shfl_xor(a2, 32);
  a3 += __shfl_xor(a3, 32);
  if (half == 0) {
    float iv = inv[node];
    ushort4 pk;
    pk.x = f2bf(iv * a0); pk.y = f2bf(iv * a1);
    pk.z = f2bf(iv * a2); pk.w = f2bf(iv * a3);
    *(ushort4*)&aggbf[(size_t)node * 128 + f4] = pk;
  }
}

// ---------------- env softmax (transposed output [KK][NN]) ----------------
__global__ __launch_bounds__(256) void env_softmax_kernel(const float* __restrict__ h,
                                                          const float* __restrict__ w,
                                                          const float* __restrict__ b,
                                                          float* __restrict__ envT, int M) {
  __shared__ float hsd[64][129];
  __shared__ float ws[HH * KK];
  int tid = threadIdx.x;
  int base = blockIdx.x * 64;
  for (int i = tid; i < HH * KK; i += 256) ws[i] = w[i];
  {
    int row = tid >> 2, q4 = (tid & 3) * 32;
    int g = base + row;
    if (g < M) {
      const float* hp = h + (size_t)g * HH + q4;
#pragma unroll
      for (int z = 0; z < 8; ++z) {
        float4 v = *(const float4*)(hp + z * 4);
        hsd[row][q4 + z * 4 + 0] = v.x; hsd[row][q4 + z * 4 + 1] = v.y;
        hsd[row][q4 + z * 4 + 2] = v.z; hsd[row][q4 + z * 4 + 3] = v.w;
      }
    }
  }
  __syncthreads();
  if (tid < 64 && base + tid < M) {
    float l0 = b[0], l1 = b[1], l2 = b[2], l3 = b[3];
    for (int d = 0; d < HH; ++d) {
      float hv = hsd[tid][d];
      l0 += hv * ws[d * 4 + 0]; l1 += hv * ws[d * 4 + 1];
      l2 += hv * ws[d * 4 + 2]; l3 += hv * ws[d * 4 + 3];
    }
    float m = fmaxf(fmaxf(l0, l1), fmaxf(l2, l3));
    float e0 = __expf(l0 - m), e1 = __expf(l1 - m), e2 = __expf(l2 - m), e3 = __expf(l3 - m);
    float s = 1.f / (e0 + e1 + e2 + e3);
    int g = base + tid;
    envT[0 * NN + g] = e0 * s;
    envT[1 * NN + g] = e1 * s;
    envT[2 * NN + g] = e2 * s;
    envT[3 * NN + g] = e3 * s;
  }
}

// ---------------- two-stage colstats ----------------
__global__ __launch_bounds__(256) void colstats1_kernel(
    const float* __restrict__ q, const float* __restrict__ k,
    float* __restrict__ partK, float* __restrict__ partS, int n) {
  int tid = threadIdx.x, ty = tid >> 7, tx = tid & 127;
  int lo = blockIdx.x * 128 + ty, hi = min(n, blockIdx.x * 128 + 128);
  float ks = 0.f, sq = 0.f, sk = 0.f;
  for (int r = lo; r < hi; r += 2) {
    float kv = k[(size_t)r * HH + tx];
    float qv = q[(size_t)r * HH + tx];
    ks += kv; sq += qv * qv; sk += kv * kv;
  }
  __shared__ float sks[2][128];
  __shared__ float ssq[256], ssk[256];
  sks[ty][tx] = ks; ssq[tid] = sq; ssk[tid] = sk;
  __syncthreads();
  if (ty == 0) partK[(size_t)blockIdx.x * 128 + tx] = sks[0][tx] + sks[1][tx];
  for (int off = 128; off > 0; off >>= 1) {
    if (tid < off) { ssq[tid] += ssq[tid + off]; ssk[tid] += ssk[tid + off]; }
    __syncthreads();
  }
  if (tid == 0) { partS[blockIdx.x * 2] = ssq[0]; partS[blockIdx.x * 2 + 1] = ssk[0]; }
}

__global__ __launch_bounds__(256) void colstats2_kernel(
    const float* __restrict__ partK, const float* __restrict__ partS,
    float* __restrict__ ksum, float* __restrict__ red) {
  int t = threadIdx.x;
  if (t < 128) {
    float s = 0.f;
    for (int b = 0; b < CSB; ++b) s += partK[(size_t)b * 128 + t];
    ksum[t] = s;
  } else if (t == 128 || t == 129) {
    float s = 0.f;
    for (int b = 0; b < CSB; ++b) s += partS[b * 2 + (t - 128)];
    red[t - 128] = s;
  }
}

__global__ void scale_kernel(float* red, int n) {
  float nq = fmaxf(sqrtf(red[0]), 1e-12f);
  float nk = fmaxf(sqrtf(red[1]), 1e-12f);
  red[2] = 1.f / (nq * nk * (float)n);
}

__global__ __launch_bounds__(256) void anorm_kernel(const float* q, const float* ksum,
                                                    const float* red, float* anorm, int M) {
  __shared__ float ks[HH];
  for (int i = threadIdx.x; i < HH; i += blockDim.x) ks[i] = ksum[i];
  __syncthreads();
  int n = blockIdx.x * blockDim.x + threadIdx.x;
  if (n >= M) return;
  const float* qp = q + (size_t)n * HH;
  float d = 0.f;
  for (int i = 0; i < HH; ++i) d += qp[i] * ks[i];
  float a = 1.f + d * red[2];
  anorm[n] = fmaxf(a, 1e-12f);
}

// ---------------- host launcher ----------------
extern "C" void kernel_launch(void* const* d_in, const int* in_sizes, int n_in,
                              void* d_out, int out_size, void* d_ws, size_t ws_size,
                              hipStream_t stream) {
  const float* x = (const float*)d_in[0];
  const int* ei = (const int*)d_in[1];
  const float* fc0_w = (const float*)d_in[2];
  const float* fc0_b = (const float*)d_in[3];
  const float* fc1_w = (const float*)d_in[4];
  const float* fc1_b = (const float*)d_in[5];
  const float* env_w = (const float*)d_in[6];
  const float* env_b = (const float*)d_in[7];
  const float* conv_w = (const float*)d_in[8];
  const float* q_w = (const float*)d_in[9];
  const float* q_b = (const float*)d_in[10];
  const float* k_w = (const float*)d_in[11];
  const float* k_b = (const float*)d_in[12];
  const float* v_w = (const float*)d_in[13];
  const float* v_b = (const float*)d_in[14];
  const float* envp_w = (const float*)d_in[15];
  const float* envp_b = (const float*)d_in[16];
  const float* genv_w = (const float*)d_in[17];
  const float* gt_w = (const float*)d_in[18];
  const float* gt_b = (const float*)d_in[19];
  float* out = (float*)d_out;

  const size_t NH = (size_t)NN * HH;
  float* W = (float*)d_ws;
  float* hA = W;             // final h
  float* hB = W + NH;        // layer buffer -> k -> ctx
  float* agg = W + 2 * NH;   // aggbf + h0bf (bf16) -> later q (f32)
  float* vbuf = W + 3 * NH;  // h1bf (bf16) -> later v -> gh
  float* gr = W + 4 * NH;
  float* env = W + 5 * NH;   // envT [KK][NN]
  float* genv = env + (size_t)NN * KK;  // genvT [KK][NN]
  float* inv = genv + (size_t)NN * KK;
  float* anorm = inv + NN;
  float* ksum = anorm + NN;
  float* red = ksum + HH;
  int* deg = (int*)(red + 4);
  int* start = deg + NN;
  int* cursor = start + NN + 1;
  int* bucket = cursor + NN;
  int* bsum = bucket + EE;          // CSB
  int* boff = bsum + CSB;           // CSB
  unsigned short* wb = (unsigned short*)(((uintptr_t)(boff + CSB) + 15) & ~(uintptr_t)15);
  unsigned short* Btfc0 = wb;                 // 256*128
  unsigned short* Btq = Btfc0 + 32768;
  unsigned short* Btk = Btq + 16384;
  unsigned short* Btv = Btk + 16384;
  unsigned short* Btgt = Btv + 16384;
  unsigned short* Btfc1 = Btgt + 16384;       // 40*128
  unsigned short* Btconv = Btfc1 + 5120;      // 2*4*128*256
  unsigned short* Btgenv = Btconv + 262144;   // 4*128*128
  unsigned short* Btktv = Btgenv + 65536;     // 128*128
  unsigned short* kTbf = Btktv + 16384;       // 128*MP
  unsigned short* vTbf = kTbf + (size_t)HH * MP;
  unsigned short* hsb = vTbf + (size_t)HH * MP;  // NN*128 bf16 (inv-scaled h)
  float* part = (float*)(((uintptr_t)(hsb + NH) + 15) & ~(uintptr_t)15);  // SKV*16384
  float* partK = part + (size_t)SKV * 16384;  // CSB*128
  float* partS = partK + (size_t)CSB * 128;   // CSB*2

  // bf16 twins carved from time-disjoint f32 regions:
  unsigned short* aggbf = (unsigned short*)agg;   // NH shorts (dead before q)
  unsigned short* h0bf = aggbf + NH;              // NH shorts (dead before q)
  unsigned short* h1bf = (unsigned short*)vbuf;   // NH shorts (dead before v)
  unsigned short* grbf = hsb;                     // reuse hsb after gather l=1

  float* q = agg;
  float* kb = hB;
  float* ctx = hB;
  float* gh = vbuf;
  float* envT = env;
  float* genvT = genv;

  dim3 b256(256);
  const int MB = (NN + 127) / 128;  // 391

  zero_i32_kernel<<<dim3((NN + 255) / 256), b256, 0, stream>>>(deg, NN);
  padzero_kernel<<<dim3((HH * (MP - NN) + 255) / 256), b256, 0, stream>>>(kTbf, vTbf);

  // CSR build (parallel 3-phase scan)
  count_kernel<<<dim3((EE + 255) / 256), b256, 0, stream>>>(ei, deg, EE);
  scan1_kernel<<<dim3(CSB), dim3(128), 0, stream>>>(deg, bsum, NN);
  scan2_kernel<<<dim3(1), dim3(512), 0, stream>>>(bsum, boff, CSB, start + NN);
  scan3_kernel<<<dim3(CSB), dim3(128), 0, stream>>>(deg, boff, start, cursor, inv, NN);
  fill_kernel<<<dim3((EE + 255) / 256), b256, 0, stream>>>(ei, cursor, bucket, EE);

  // weight prep
  tcvt_kernel<<<dim3((32768 + 255) / 256), b256, 0, stream>>>(fc0_w, Btfc0, 256, 128, 1);
  tcvt_kernel<<<dim3((16384 + 255) / 256), b256, 0, stream>>>(q_w, Btq, 128, 128, 1);
  tcvt_kernel<<<dim3((16384 + 255) / 256), b256, 0, stream>>>(k_w, Btk, 128, 128, 1);
  tcvt_kernel<<<dim3((16384 + 255) / 256), b256, 0, stream>>>(v_w, Btv, 128, 128, 1);
  tcvt_kernel<<<dim3((16384 + 255) / 256), b256, 0, stream>>>(gt_w, Btgt, 128, 128, 1);
  tcvt_kernel<<<dim3((5120 + 255) / 256), b256, 0, stream>>>(fc1_w, Btfc1, 128, 40, 1);
  tcvt_kernel<<<dim3((262144 + 255) / 256), b256, 0, stream>>>(conv_w, Btconv, 256, 128, 8);
  tcvt_kernel<<<dim3((65536 + 255) / 256), b256, 0, stream>>>(genv_w, Btgenv, 128, 128, 4);

  // fc0: h = relu(x @ fc0_w + b); emit hsb = bf16(inv*h) and h0bf = bf16(h)
  mgemm_kernel<<<dim3(MB), b256, 0, stream>>>(
      x, nullptr, DD, Btfc0, 256, 1, hA, HH, fc0_b, nullptr, 0, nullptr, nullptr,
      nullptr, hsb, inv, h0bf, NN, HH);

  // conv layers
  float* hcur = hA;
  float* hnext = hB;
  unsigned short* hbf_cur = h0bf;
  unsigned short* hbf_next = h1bf;
  for (int l = 0; l < 2; ++l) {
    env_softmax_kernel<<<dim3((NN + 63) / 64), b256, 0, stream>>>(
        hcur, env_w + (size_t)l * HH * KK, env_b + (size_t)l * KK, envT, NN);
    gather_kernel<<<dim3(NN / 4), b256, 0, stream>>>(hsb, start, bucket, inv, aggbf, NN);
    mconv_kernel<<<dim3(MB), b256, 0, stream>>>(
        aggbf, hbf_cur, envT, Btconv + (size_t)l * 131072, 256, 1, hcur, hnext,
        (l == 0) ? hsb : nullptr, inv, (l == 0) ? hbf_next : nullptr, NN);
    float* t = hcur; hcur = hnext; hnext = t;
    unsigned short* tb = hbf_cur; hbf_cur = hbf_next; hbf_next = tb;
  }
  // hcur == hA

  // q, k, v (k/v also emit transposed bf16 copies)
  mgemm_kernel<<<dim3(MB), b256, 0, stream>>>(
      hcur, nullptr, HH, Btq, 128, 0, q, HH, q_b, nullptr, 0, nullptr, nullptr,
      nullptr, nullptr, nullptr, nullptr, NN, HH);
  mgemm_kernel<<<dim3(MB), b256, 0, stream>>>(
      hcur, nullptr, HH, Btk, 128, 0, kb, HH, k_b, nullptr, 0, nullptr, nullptr,
      kTbf, nullptr, nullptr, nullptr, NN, HH);
  mgemm_kernel<<<dim3(MB), b256, 0, stream>>>(
      hcur, nullptr, HH, Btv, 128, 0, vbuf, HH, v_b, nullptr, 0, nullptr, nullptr,
      vTbf, nullptr, nullptr, nullptr, NN, HH);

  colstats1_kernel<<<dim3(CSB), b256, 0, stream>>>(q, kb, partK, partS, NN);
  colstats2_kernel<<<dim3(1), b256, 0, stream>>>(partK, partS, ksum, red);
  ktv_mfma_kernel<<<dim3(SKV), b256, 0, stream>>>(kTbf, vTbf, part);
  ktv_reduce_kernel<<<dim3(64), b256, 0, stream>>>(part, Btktv);
  scale_kernel<<<dim3(1), dim3(1), 0, stream>>>(red, NN);
  anorm_kernel<<<dim3((NN + 255) / 256), b256, 0, stream>>>(q, ksum, red, anorm, NN);

  // gr = (v + q @ ktv * red[2]) / anorm; emit grbf = bf16(gr)
  mgemm_kernel<<<dim3(MB), b256, 0, stream>>>(
      q, nullptr, HH, Btktv, 128, 3, gr, HH, nullptr, vbuf, HH, anorm, red,
      nullptr, nullptr, nullptr, grbf, NN, HH);

  // genvT = softmax(gr @ envp_w + envp_b), transposed
  env_softmax_kernel<<<dim3((NN + 63) / 64), b256, 0, stream>>>(gr, envp_w, envp_b, genvT, NN);

  // ctx = sum_k genv[:,k] * (gr @ genv_w[k])
  mconv_kernel<<<dim3(MB), b256, 0, stream>>>(
      grbf, nullptr, genvT, Btgenv, 128, 0, nullptr, ctx, nullptr, nullptr,
      nullptr, NN);

  // gh = relu(ctx @ gt_w + gt_b)
  mgemm_kernel<<<dim3(MB), b256, 0, stream>>>(
      ctx, nullptr, HH, Btgt, 128, 1, gh, HH, gt_b, nullptr, 0, nullptr, nullptr,
      nullptr, nullptr, nullptr, nullptr, NN, HH);

  // out = 0.5*((h+gh) @ fc1_w) + fc1_b
  mgemm_kernel<<<dim3(MB), b256, 0, stream>>>(
      hcur, gh, HH, Btfc1, 128, 5, out, CC, fc1_b, nullptr, 0, nullptr, nullptr,
      nullptr, nullptr, nullptr, nullptr, NN, CC);
}

// Round 10
// 779.803 us; speedup vs baseline: 4.8170x; 4.8170x over previous
//
#include <hip/hip_runtime.h>

#define DEV __device__ __forceinline__

static constexpr int NN = 50000;   // nodes
static constexpr int DD = 256;     // input dim
static constexpr int HH = 128;     // hidden
static constexpr int CC = 40;      // classes
static constexpr int KK = 4;       // envs
static constexpr int EE = 800000;  // edges
static constexpr int MP = 50176;   // padded node count (196*256, mult of 32)
static constexpr int SKV = 196;    // split-K blocks for ktv
static constexpr int CPB = 8;      // 32-node chunks per ktv block
static constexpr int CSB = 391;    // colstats / scan blocks (ceil(NN/128))

typedef __attribute__((ext_vector_type(8))) short bf16x8;
typedef __attribute__((ext_vector_type(4))) float f32x4;

DEV unsigned short f2bf(float f) {
  union { float f; unsigned int i; } c; c.f = f;
  unsigned int x = c.i;
  x += 0x7FFFu + ((x >> 16) & 1u);   // round-to-nearest-even
  return (unsigned short)(x >> 16);
}
DEV float bfbits2f(unsigned int hi16bits) {
  union { unsigned int i; float f; } c; c.i = hi16bits; return c.f;
}

// harness-named kernel (unused in pipeline)
__global__ void MLEI_12970801234193_kernel(float* out, int n) {
  int i = blockIdx.x * blockDim.x + threadIdx.x;
  if (i < n) out[i] = 7.0f;
}

__global__ void zero_i32_kernel(int* p, int n) {
  int i = blockIdx.x * blockDim.x + threadIdx.x;
  if (i < n) p[i] = 0;
}

// zero the pad columns [NN, MP) of the transposed bf16 k/v buffers
__global__ void padzero_kernel(unsigned short* kT, unsigned short* vT) {
  int i = blockIdx.x * blockDim.x + threadIdx.x;
  const int PW = MP - NN;  // 176
  if (i >= HH * PW) return;
  int f = i / PW, c = i - f * PW;
  kT[(size_t)f * MP + NN + c] = 0;
  vT[(size_t)f * MP + NN + c] = 0;
}

// transpose-convert: dst[m][n][k] = bf16(src[m][k][n]); nm matrices of K x N
__global__ void tcvt_kernel(const float* __restrict__ src, unsigned short* __restrict__ dst,
                            int K, int N, int nm) {
  int i = blockIdx.x * blockDim.x + threadIdx.x;
  int tot = nm * K * N;
  if (i >= tot) return;
  int m = i / (K * N);
  int rem = i - m * K * N;
  int k = rem / N;
  int n = rem - k * N;
  dst[(size_t)m * K * N + (size_t)n * K + k] = f2bf(src[i]);
}

// ---------------- generic bf16-MFMA GEMM (R3 structure + raw bf16 twin out) ----------------
__global__ __launch_bounds__(256) void mgemm_kernel(
    const float* __restrict__ A, const float* __restrict__ Aadd, int lda,
    const unsigned short* __restrict__ Bt, int K,
    int emode, float* __restrict__ out, int ldo,
    const float* __restrict__ bias, const float* __restrict__ resid, int ldr,
    const float* __restrict__ anorm, const float* __restrict__ red,
    unsigned short* __restrict__ outT,
    unsigned short* __restrict__ outBf, const float* __restrict__ rowscale,
    unsigned short* __restrict__ outBfRaw,
    int M, int Nd) {
  __shared__ unsigned short As[2][128][40];
  __shared__ unsigned short Bs[2][128][40];
  const int tid = threadIdx.x, lane = tid & 63, wave = tid >> 6;
  const int quad = lane >> 4, l16 = lane & 15;
  const int wm = (wave >> 1) * 64, wn = (wave & 1) * 64;
  const int bm = blockIdx.x * 128;
  const int srow = tid >> 1, skh = (tid & 1) * 16;
  const int grow = bm + srow;
  const bool rowok = grow < M;
  const bool colok = srow < Nd;
  const int NCH = K >> 5;

  f32x4 acc[4][4];
#pragma unroll
  for (int i = 0; i < 4; ++i)
#pragma unroll
    for (int j = 0; j < 4; ++j)
#pragma unroll
      for (int r = 0; r < 4; ++r) acc[i][j][r] = 0.f;

  float vaA[16], vaB[16];
  bf16x8 bA0, bA1, bB0, bB1;

  auto LOAD = [&](int kc, float (&va)[16], bf16x8& b0, bf16x8& b1) {
    int k0 = kc << 5;
    if (rowok) {
      const float* ap = A + (size_t)grow * lda + k0 + skh;
      float4 v0 = *(const float4*)(ap + 0), v1 = *(const float4*)(ap + 4);
      float4 v2 = *(const float4*)(ap + 8), v3 = *(const float4*)(ap + 12);
      va[0] = v0.x; va[1] = v0.y; va[2] = v0.z; va[3] = v0.w;
      va[4] = v1.x; va[5] = v1.y; va[6] = v1.z; va[7] = v1.w;
      va[8] = v2.x; va[9] = v2.y; va[10] = v2.z; va[11] = v2.w;
      va[12] = v3.x; va[13] = v3.y; va[14] = v3.z; va[15] = v3.w;
      if (Aadd) {
        const float* ap2 = Aadd + (size_t)grow * lda + k0 + skh;
        float4 w0 = *(const float4*)(ap2 + 0), w1 = *(const float4*)(ap2 + 4);
        float4 w2 = *(const float4*)(ap2 + 8), w3 = *(const float4*)(ap2 + 12);
        va[0] += w0.x; va[1] += w0.y; va[2] += w0.z; va[3] += w0.w;
        va[4] += w1.x; va[5] += w1.y; va[6] += w1.z; va[7] += w1.w;
        va[8] += w2.x; va[9] += w2.y; va[10] += w2.z; va[11] += w2.w;
        va[12] += w3.x; va[13] += w3.y; va[14] += w3.z; va[15] += w3.w;
      }
    }
    if (colok) {
      const unsigned short* bp = Bt + (size_t)srow * K + k0 + skh;
      b0 = *(const bf16x8*)(bp);
      b1 = *(const bf16x8*)(bp + 8);
    } else {
#pragma unroll
      for (int z = 0; z < 8; ++z) { b0[z] = 0; b1[z] = 0; }
    }
  };

  auto STORE = [&](int buf, const float (&va)[16], const bf16x8& b0, const bf16x8& b1) {
    bf16x8 p0, p1;
    if (rowok) {
#pragma unroll
      for (int z = 0; z < 8; ++z) { p0[z] = (short)f2bf(va[z]); p1[z] = (short)f2bf(va[z + 8]); }
    } else {
#pragma unroll
      for (int z = 0; z < 8; ++z) { p0[z] = 0; p1[z] = 0; }
    }
    *(bf16x8*)&As[buf][srow][skh] = p0;
    *(bf16x8*)&As[buf][srow][skh + 8] = p1;
    *(bf16x8*)&Bs[buf][srow][skh] = b0;
    *(bf16x8*)&Bs[buf][srow][skh + 8] = b1;
  };

  auto MFMA = [&](int buf) {
    bf16x8 af[4], bfr[4];
#pragma unroll
    for (int i = 0; i < 4; ++i) af[i] = *(const bf16x8*)&As[buf][wm + i * 16 + l16][quad * 8];
#pragma unroll
    for (int j = 0; j < 4; ++j) bfr[j] = *(const bf16x8*)&Bs[buf][wn + j * 16 + l16][quad * 8];
#pragma unroll
    for (int i = 0; i < 4; ++i)
#pragma unroll
      for (int j = 0; j < 4; ++j)
        acc[i][j] = __builtin_amdgcn_mfma_f32_16x16x32_bf16(af[i], bfr[j], acc[i][j], 0, 0, 0);
  };

  LOAD(0, vaA, bA0, bA1);
  if (NCH > 1) LOAD(1, vaB, bB0, bB1);
  STORE(0, vaA, bA0, bA1);
  __syncthreads();

  for (int kc = 0; kc < NCH; kc += 2) {
    if (kc + 2 < NCH) LOAD(kc + 2, vaA, bA0, bA1);
    MFMA(0);
    if (kc + 1 < NCH) STORE(1, vaB, bB0, bB1);
    __syncthreads();
    if (kc + 1 < NCH) {
      if (kc + 3 < NCH) LOAD(kc + 3, vaB, bB0, bB1);
      MFMA(1);
      if (kc + 2 < NCH) STORE(0, vaA, bA0, bA1);
      __syncthreads();
    }
  }

  float s2 = (emode == 3) ? red[2] : 0.f;
#pragma unroll
  for (int j = 0; j < 4; ++j) {
    int col = wn + j * 16 + l16;
    if (col >= Nd) continue;
    float bv = bias ? bias[col] : 0.f;
#pragma unroll
    for (int i = 0; i < 4; ++i) {
      int row0 = bm + wm + i * 16 + quad * 4;
      if (row0 >= M) continue;
      float o[4];
#pragma unroll
      for (int r = 0; r < 4; ++r) {
        float a = acc[i][j][r];
        int row = row0 + r;
        if (emode == 0) o[r] = a + bv;
        else if (emode == 1) o[r] = fmaxf(a + bv, 0.f);
        else if (emode == 3) o[r] = (resid[(size_t)row * ldr + col] + a * s2) / anorm[row];
        else o[r] = 0.5f * a + bv;
        out[(size_t)row * ldo + col] = o[r];
      }
      if (outT) {
        ushort4 pk;
        pk.x = f2bf(o[0]); pk.y = f2bf(o[1]); pk.z = f2bf(o[2]); pk.w = f2bf(o[3]);
        *(ushort4*)&outT[(size_t)col * MP + row0] = pk;
      }
      if (outBf) {
#pragma unroll
        for (int r = 0; r < 4; ++r) {
          float rs = rowscale ? rowscale[row0 + r] : 1.f;
          outBf[(size_t)(row0 + r) * 128 + col] = f2bf(o[r] * rs);
        }
      }
      if (outBfRaw) {
#pragma unroll
        for (int r = 0; r < 4; ++r)
          outBfRaw[(size_t)(row0 + r) * 128 + col] = f2bf(o[r]);
      }
    }
  }
}

// ---------------- split-K MFMA kT@v (R3 structure) ----------------
__global__ __launch_bounds__(256) void ktv_mfma_kernel(
    const unsigned short* __restrict__ kT, const unsigned short* __restrict__ vT,
    float* __restrict__ part) {
  __shared__ unsigned short As[2][128][40];
  __shared__ unsigned short Bs[2][128][40];
  const int tid = threadIdx.x, lane = tid & 63, wave = tid >> 6;
  const int quad = lane >> 4, l16 = lane & 15;
  const int wm = (wave >> 1) * 64, wn = (wave & 1) * 64;
  const int srow = tid >> 1, skh = (tid & 1) * 16;

  f32x4 acc[4][4];
#pragma unroll
  for (int i = 0; i < 4; ++i)
#pragma unroll
    for (int j = 0; j < 4; ++j)
#pragma unroll
      for (int r = 0; r < 4; ++r) acc[i][j][r] = 0.f;

  const int nb0 = blockIdx.x * (CPB * 32);
  bf16x8 kA0, kA1, vA0, vA1, kB0, kB1, vB0, vB1;

  auto LOAD = [&](int c, bf16x8& k0, bf16x8& k1, bf16x8& v0, bf16x8& v1) {
    int nb = nb0 + c * 32;
    const unsigned short* kp = kT + (size_t)srow * MP + nb + skh;
    k0 = *(const bf16x8*)(kp);
    k1 = *(const bf16x8*)(kp + 8);
    const unsigned short* vp = vT + (size_t)srow * MP + nb + skh;
    v0 = *(const bf16x8*)(vp);
    v1 = *(const bf16x8*)(vp + 8);
  };
  auto STORE = [&](int buf, const bf16x8& k0, const bf16x8& k1, const bf16x8& v0, const bf16x8& v1) {
    *(bf16x8*)&As[buf][srow][skh] = k0;
    *(bf16x8*)&As[buf][srow][skh + 8] = k1;
    *(bf16x8*)&Bs[buf][srow][skh] = v0;
    *(bf16x8*)&Bs[buf][srow][skh + 8] = v1;
  };
  auto MFMA = [&](int buf) {
    bf16x8 af[4], bfr[4];
#pragma unroll
    for (int i = 0; i < 4; ++i) af[i] = *(const bf16x8*)&As[buf][wm + i * 16 + l16][quad * 8];
#pragma unroll
    for (int j = 0; j < 4; ++j) bfr[j] = *(const bf16x8*)&Bs[buf][wn + j * 16 + l16][quad * 8];
#pragma unroll
    for (int i = 0; i < 4; ++i)
#pragma unroll
      for (int j = 0; j < 4; ++j)
        acc[i][j] = __builtin_amdgcn_mfma_f32_16x16x32_bf16(af[i], bfr[j], acc[i][j], 0, 0, 0);
  };

  LOAD(0, kA0, kA1, vA0, vA1);
  LOAD(1, kB0, kB1, vB0, vB1);
  STORE(0, kA0, kA1, vA0, vA1);
  __syncthreads();

  for (int c = 0; c < CPB; c += 2) {
    if (c + 2 < CPB) LOAD(c + 2, kA0, kA1, vA0, vA1);
    MFMA(0);
    if (c + 1 < CPB) STORE(1, kB0, kB1, vB0, vB1);
    __syncthreads();
    if (c + 1 < CPB) {
      if (c + 3 < CPB) LOAD(c + 3, kB0, kB1, vB0, vB1);
      MFMA(1);
      if (c + 2 < CPB) STORE(0, kA0, kA1, vA0, vA1);
      __syncthreads();
    }
  }

  float* pb = part + (size_t)blockIdx.x * 16384;
#pragma unroll
  for (int j = 0; j < 4; ++j) {
    int col = wn + j * 16 + l16;
#pragma unroll
    for (int i = 0; i < 4; ++i) {
      int row0 = wm + i * 16 + quad * 4;
      *(f32x4*)&pb[col * 128 + row0] = acc[i][j];
    }
  }
}

__global__ void ktv_reduce_kernel(const float* __restrict__ part,
                                  unsigned short* __restrict__ Btktv) {
  int i = blockIdx.x * blockDim.x + threadIdx.x;
  if (i >= 16384) return;
  float s0 = 0.f, s1 = 0.f, s2 = 0.f, s3 = 0.f;
  int b = 0;
  for (; b + 3 < SKV; b += 4) {
    s0 += part[(size_t)b * 16384 + i];
    s1 += part[(size_t)(b + 1) * 16384 + i];
    s2 += part[(size_t)(b + 2) * 16384 + i];
    s3 += part[(size_t)(b + 3) * 16384 + i];
  }
  for (; b < SKV; ++b) s0 += part[(size_t)b * 16384 + i];
  Btktv[i] = f2bf((s0 + s1) + (s2 + s3));
}

// ---------------- env-weighted MFMA GEMM (conv & ctx) ----------------
// out[n,:] = sum_e env[n,e] * (hi[n,:] @ W_e), hi = [A1bf | A2bf] (bf16).
// e-OUTER / kc-inner with output-side env fold. Staging = pure bf16 copy
// (zero VALU). Phase loop statically unrolled x2 with NAMED register sets
// (rule #20: no runtime-indexed register arrays -> no scratch).
__global__ __launch_bounds__(256) void mconv_kernel(
    const unsigned short* __restrict__ A1bf, const unsigned short* __restrict__ A2bf,
    const float* __restrict__ envT,  // [KK][NN] transposed
    const unsigned short* __restrict__ Btc, int Kpe,
    int relu_resid, const float* __restrict__ resid, float* __restrict__ out,
    unsigned short* __restrict__ outBf, const float* __restrict__ rowscale,
    unsigned short* __restrict__ outBfRaw, int M) {
  __shared__ unsigned short As[2][128][40];
  __shared__ unsigned short Bs[2][128][40];
  const int tid = threadIdx.x, lane = tid & 63, wave = tid >> 6;
  const int quad = lane >> 4, l16 = lane & 15;
  const int wm = (wave >> 1) * 64, wn = (wave & 1) * 64;
  const int bm = blockIdx.x * 128;
  const int srow = tid >> 1, skh = (tid & 1) * 16;
  const int grow = bm + srow;
  const bool rowok = grow < M;
  const int nch = Kpe >> 5;            // K-chunks per env (8 conv / 4 ctx)
  const int lg = (nch == 8) ? 3 : 2;
  const int NPH = nch << 2;            // 32 or 16 (always even)

  f32x4 acc[4][4], accF[4][4];
#pragma unroll
  for (int i = 0; i < 4; ++i)
#pragma unroll
    for (int j = 0; j < 4; ++j)
#pragma unroll
      for (int r = 0; r < 4; ++r) { acc[i][j][r] = 0.f; accF[i][j][r] = 0.f; }

  float4 fe[4];  // envT[e] for this thread's 4 row-quads, prefetched per env
  auto LOADEV = [&](int e) {
#pragma unroll
    for (int i = 0; i < 4; ++i) {
      int r0 = bm + wm + i * 16 + quad * 4;
      if (r0 > M - 4) r0 = M - 4;
      fe[i] = *(const float4*)&envT[(size_t)e * NN + r0];
    }
  };

  // two NAMED register sets (static indexing only)
  bf16x8 aA0, aA1, bA0, bA1;
  bf16x8 aB0, aB1, bB0, bB1;

  auto LOADP = [&](int p, bf16x8& a0, bf16x8& a1, bf16x8& b0, bf16x8& b1) {
    int e = p >> lg;
    int kc = p & (nch - 1);
    int kof = kc << 5;
    const unsigned short* Asrc = A1bf;
    int ks = kof;
    if (A2bf && kof >= 128) { Asrc = A2bf; ks = kof - 128; }
    if (rowok) {
      const unsigned short* ap = Asrc + (size_t)grow * 128 + ks + skh;
      a0 = *(const bf16x8*)(ap);
      a1 = *(const bf16x8*)(ap + 8);
    } else {
#pragma unroll
      for (int z = 0; z < 8; ++z) { a0[z] = 0; a1[z] = 0; }
    }
    const unsigned short* bp = Btc + ((size_t)e * 128 + srow) * Kpe + kof + skh;
    b0 = *(const bf16x8*)(bp);
    b1 = *(const bf16x8*)(bp + 8);
  };

  auto STORE = [&](int buf, const bf16x8& a0, const bf16x8& a1,
                   const bf16x8& b0, const bf16x8& b1) {
    *(bf16x8*)&As[buf][srow][skh] = a0;
    *(bf16x8*)&As[buf][srow][skh + 8] = a1;
    *(bf16x8*)&Bs[buf][srow][skh] = b0;
    *(bf16x8*)&Bs[buf][srow][skh + 8] = b1;
  };

  auto MFMA = [&](int buf) {
    bf16x8 af[4], bfr[4];
#pragma unroll
    for (int i = 0; i < 4; ++i) af[i] = *(const bf16x8*)&As[buf][wm + i * 16 + l16][quad * 8];
#pragma unroll
    for (int j = 0; j < 4; ++j) bfr[j] = *(const bf16x8*)&Bs[buf][wn + j * 16 + l16][quad * 8];
#pragma unroll
    for (int i = 0; i < 4; ++i)
#pragma unroll
      for (int j = 0; j < 4; ++j)
        acc[i][j] = __builtin_amdgcn_mfma_f32_16x16x32_bf16(af[i], bfr[j], acc[i][j], 0, 0, 0);
  };

  auto FOLD = [&]() {
#pragma unroll
    for (int i = 0; i < 4; ++i)
#pragma unroll
      for (int j = 0; j < 4; ++j)
#pragma unroll
        for (int r = 0; r < 4; ++r) {
          float ev = (r == 0) ? fe[i].x : (r == 1) ? fe[i].y : (r == 2) ? fe[i].z : fe[i].w;
          accF[i][j][r] += ev * acc[i][j][r];
          acc[i][j][r] = 0.f;
        }
  };

  // prologue: set A = phase 0 (staged), set B = phase 1 (in registers)
  LOADEV(0);
  LOADP(0, aA0, aA1, bA0, bA1);
  LOADP(1, aB0, aB1, bB0, bB1);
  STORE(0, aA0, aA1, bA0, bA1);
  __syncthreads();

  for (int p = 0; p < NPH; p += 2) {
    // even phase p: compute buf0; prefetch p+2 into set A; stage set B -> buf1
    if (p + 2 < NPH) LOADP(p + 2, aA0, aA1, bA0, bA1);
    MFMA(0);
    STORE(1, aB0, aB1, bB0, bB1);
    __syncthreads();
    // odd phase p+1: compute buf1; prefetch p+3 into set B; stage set A -> buf0
    if (p + 3 < NPH) LOADP(p + 3, aB0, aB1, bB0, bB1);
    MFMA(1);
    if (((p + 1) & (nch - 1)) == (nch - 1)) {
      FOLD();
      int e = (p + 1) >> lg;
      if (e < 3) LOADEV(e + 1);
    }
    if (p + 2 < NPH) STORE(0, aA0, aA1, bA0, bA1);
    __syncthreads();
  }

#pragma unroll
  for (int j = 0; j < 4; ++j) {
    int col = wn + j * 16 + l16;
#pragma unroll
    for (int i = 0; i < 4; ++i) {
      int row0 = bm + wm + i * 16 + quad * 4;
      if (row0 >= M) continue;
#pragma unroll
      for (int r = 0; r < 4; ++r) {
        int row = row0 + r;
        float a = accF[i][j][r];
        float o = relu_resid ? fmaxf(a + resid[(size_t)row * 128 + col], 0.f) : a;
        out[(size_t)row * 128 + col] = o;
        if (outBf) {
          float rs = rowscale ? rowscale[row] : 1.f;
          outBf[(size_t)row * 128 + col] = f2bf(o * rs);
        }
        if (outBfRaw) outBfRaw[(size_t)row * 128 + col] = f2bf(o);
      }
    }
  }
}

// ---------------- graph kernels ----------------
__global__ void count_kernel(const int* ei, int* deg, int E) {
  int e = blockIdx.x * blockDim.x + threadIdx.x;
  if (e >= E) return;
  atomicAdd(&deg[ei[E + e]], 1);
}

__global__ __launch_bounds__(128) void scan1_kernel(const int* __restrict__ deg,
                                                    int* __restrict__ bsum, int n) {
  __shared__ int sh[128];
  int t = threadIdx.x;
  int i = blockIdx.x * 128 + t;
  sh[t] = (i < n) ? deg[i] : 0;
  __syncthreads();
  for (int off = 64; off > 0; off >>= 1) {
    if (t < off) sh[t] += sh[t + off];
    __syncthreads();
  }
  if (t == 0) bsum[blockIdx.x] = sh[0];
}

__global__ __launch_bounds__(512) void scan2_kernel(const int* __restrict__ bsum,
                                                    int* __restrict__ boff, int nb,
                                                    int* __restrict__ startN) {
  __shared__ int sh[512];
  int t = threadIdx.x;
  int v0 = (t < nb) ? bsum[t] : 0;
  sh[t] = v0;
  __syncthreads();
  for (int off = 1; off < 512; off <<= 1) {
    int v = sh[t];
    int add = (t >= off) ? sh[t - off] : 0;
    __syncthreads();
    sh[t] = v + add;
    __syncthreads();
  }
  if (t < nb) boff[t] = sh[t] - v0;
  if (t == nb - 1) *startN = sh[t];
}

__global__ __launch_bounds__(128) void scan3_kernel(const int* __restrict__ deg,
                                                    const int* __restrict__ boff,
                                                    int* __restrict__ start,
                                                    int* __restrict__ cursor,
                                                    float* __restrict__ inv, int n) {
  __shared__ int sh[128];
  int t = threadIdx.x;
  int i = blockIdx.x * 128 + t;
  int d = (i < n) ? deg[i] : 0;
  sh[t] = d;
  __syncthreads();
  for (int off = 1; off < 128; off <<= 1) {
    int v = sh[t];
    int add = (t >= off) ? sh[t - off] : 0;
    __syncthreads();
    sh[t] = v + add;
    __syncthreads();
  }
  if (i < n) {
    int p = boff[blockIdx.x] + sh[t] - d;
    start[i] = p; cursor[i] = p;
    inv[i] = (d > 0) ? rsqrtf((float)d) : 0.f;
  }
}

__global__ void fill_kernel(const int* ei, int* cursor, int* bucket, int E) {
  int e = blockIdx.x * blockDim.x + threadIdx.x;
  if (e >= E) return;
  int r = ei[e], c = ei[E + e];
  int pos = atomicAdd(&cursor[c], 1);
  bucket[pos] = r;
}

// gather from pre-scaled bf16 h -> bf16 agg: aggbf[n,f] = bf16(inv[n]*sum hs[src][f])
__global__ __launch_bounds__(256) void gather_kernel(
    const unsigned short* __restrict__ hs, const int* __restrict__ start,
    const int* __restrict__ bucket, const float* __restrict__ inv,
    unsigned short* __restrict__ aggbf, int n) {
  int node = blockIdx.x * 4 + (threadIdx.x >> 6);
  if (node >= n) return;
  const int lane = threadIdx.x & 63;
  const int half = lane >> 5, l32 = lane & 31;
  const int f4 = l32 * 4;
  int s0 = start[node], s1 = start[node + 1];
  float a0 = 0.f, a1 = 0.f, a2 = 0.f, a3 = 0.f;
  int j = s0 + half;
  for (; j + 2 < s1; j += 4) {
    int r0 = bucket[j], r1 = bucket[j + 2];
    uint2 u0 = *(const uint2*)&hs[(size_t)r0 * 128 + f4];
    uint2 u1 = *(const uint2*)&hs[(size_t)r1 * 128 + f4];
    a0 += bfbits2f(u0.x << 16); a1 += bfbits2f(u0.x & 0xFFFF0000u);
    a2 += bfbits2f(u0.y << 16); a3 += bfbits2f(u0.y & 0xFFFF0000u);
    a0 += bfbits2f(u1.x << 16); a1 += bfbits2f(u1.x & 0xFFFF0000u);
    a2 += bfbits2f(u1.y << 16); a3 += bfbits2f(u1.y & 0xFFFF0000u);
  }
  for (; j < s1; j += 2) {
    int r = bucket[j];
    uint2 u = *(const uint2*)&hs[(size_t)r * 128 + f4];
    a0 += bfbits2f(u.x << 16); a1 += bfbits2f(u.x & 0xFFFF0000u);
    a2 += bfbits2f(u.y << 16); a3 += bfbits2f(u.y & 0xFFFF0000u);
  }
  a0 += __shfl_xor(a0, 32);
  a1 += __shfl_xor(a1, 32);
  a2 += __shfl_xor(a2, 32);
  a3 += __shfl_xor(a3, 32);
  if (half == 0) {
    float iv = inv[node];
    ushort4 pk;
    pk.x = f2bf(iv * a0); pk.y = f2bf(iv * a1);
    pk.z = f2bf(iv * a2); pk.w = f2bf(iv * a3);
    *(ushort4*)&aggbf[(size_t)node * 128 + f4] = pk;
  }
}

// ---------------- env softmax (transposed output [KK][NN]) ----------------
__global__ __launch_bounds__(256) void env_softmax_kernel(const float* __restrict__ h,
                                                          const float* __restrict__ w,
                                                          const float* __restrict__ b,
                                                          float* __restrict__ envT, int M) {
  __shared__ float hsd[64][129];
  __shared__ float ws[HH * KK];
  int tid = threadIdx.x;
  int base = blockIdx.x * 64;
  for (int i = tid; i < HH * KK; i += 256) ws[i] = w[i];
  {
    int row = tid >> 2, q4 = (tid & 3) * 32;
    int g = base + row;
    if (g < M) {
      const float* hp = h + (size_t)g * HH + q4;
#pragma unroll
      for (int z = 0; z < 8; ++z) {
        float4 v = *(const float4*)(hp + z * 4);
        hsd[row][q4 + z * 4 + 0] = v.x; hsd[row][q4 + z * 4 + 1] = v.y;
        hsd[row][q4 + z * 4 + 2] = v.z; hsd[row][q4 + z * 4 + 3] = v.w;
      }
    }
  }
  __syncthreads();
  if (tid < 64 && base + tid < M) {
    float l0 = b[0], l1 = b[1], l2 = b[2], l3 = b[3];
    for (int d = 0; d < HH; ++d) {
      float hv = hsd[tid][d];
      l0 += hv * ws[d * 4 + 0]; l1 += hv * ws[d * 4 + 1];
      l2 += hv * ws[d * 4 + 2]; l3 += hv * ws[d * 4 + 3];
    }
    float m = fmaxf(fmaxf(l0, l1), fmaxf(l2, l3));
    float e0 = __expf(l0 - m), e1 = __expf(l1 - m), e2 = __expf(l2 - m), e3 = __expf(l3 - m);
    float s = 1.f / (e0 + e1 + e2 + e3);
    int g = base + tid;
    envT[0 * NN + g] = e0 * s;
    envT[1 * NN + g] = e1 * s;
    envT[2 * NN + g] = e2 * s;
    envT[3 * NN + g] = e3 * s;
  }
}

// ---------------- two-stage colstats ----------------
__global__ __launch_bounds__(256) void colstats1_kernel(
    const float* __restrict__ q, const float* __restrict__ k,
    float* __restrict__ partK, float* __restrict__ partS, int n) {
  int tid = threadIdx.x, ty = tid >> 7, tx = tid & 127;
  int lo = blockIdx.x * 128 + ty, hi = min(n, blockIdx.x * 128 + 128);
  float ks = 0.f, sq = 0.f, sk = 0.f;
  for (int r = lo; r < hi; r += 2) {
    float kv = k[(size_t)r * HH + tx];
    float qv = q[(size_t)r * HH + tx];
    ks += kv; sq += qv * qv; sk += kv * kv;
  }
  __shared__ float sks[2][128];
  __shared__ float ssq[256], ssk[256];
  sks[ty][tx] = ks; ssq[tid] = sq; ssk[tid] = sk;
  __syncthreads();
  if (ty == 0) partK[(size_t)blockIdx.x * 128 + tx] = sks[0][tx] + sks[1][tx];
  for (int off = 128; off > 0; off >>= 1) {
    if (tid < off) { ssq[tid] += ssq[tid + off]; ssk[tid] += ssk[tid + off]; }
    __syncthreads();
  }
  if (tid == 0) { partS[blockIdx.x * 2] = ssq[0]; partS[blockIdx.x * 2 + 1] = ssk[0]; }
}

__global__ __launch_bounds__(256) void colstats2_kernel(
    const float* __restrict__ partK, const float* __restrict__ partS,
    float* __restrict__ ksum, float* __restrict__ red) {
  int t = threadIdx.x;
  if (t < 128) {
    float s = 0.f;
    for (int b = 0; b < CSB; ++b) s += partK[(size_t)b * 128 + t];
    ksum[t] = s;
  } else if (t == 128 || t == 129) {
    float s = 0.f;
    for (int b = 0; b < CSB; ++b) s += partS[b * 2 + (t - 128)];
    red[t - 128] = s;
  }
}

__global__ void scale_kernel(float* red, int n) {
  float nq = fmaxf(sqrtf(red[0]), 1e-12f);
  float nk = fmaxf(sqrtf(red[1]), 1e-12f);
  red[2] = 1.f / (nq * nk * (float)n);
}

__global__ __launch_bounds__(256) void anorm_kernel(const float* q, const float* ksum,
                                                    const float* red, float* anorm, int M) {
  __shared__ float ks[HH];
  for (int i = threadIdx.x; i < HH; i += blockDim.x) ks[i] = ksum[i];
  __syncthreads();
  int n = blockIdx.x * blockDim.x + threadIdx.x;
  if (n >= M) return;
  const float* qp = q + (size_t)n * HH;
  float d = 0.f;
  for (int i = 0; i < HH; ++i) d += qp[i] * ks[i];
  float a = 1.f + d * red[2];
  anorm[n] = fmaxf(a, 1e-12f);
}

// ---------------- host launcher ----------------
extern "C" void kernel_launch(void* const* d_in, const int* in_sizes, int n_in,
                              void* d_out, int out_size, void* d_ws, size_t ws_size,
                              hipStream_t stream) {
  const float* x = (const float*)d_in[0];
  const int* ei = (const int*)d_in[1];
  const float* fc0_w = (const float*)d_in[2];
  const float* fc0_b = (const float*)d_in[3];
  const float* fc1_w = (const float*)d_in[4];
  const float* fc1_b = (const float*)d_in[5];
  const float* env_w = (const float*)d_in[6];
  const float* env_b = (const float*)d_in[7];
  const float* conv_w = (const float*)d_in[8];
  const float* q_w = (const float*)d_in[9];
  const float* q_b = (const float*)d_in[10];
  const float* k_w = (const float*)d_in[11];
  const float* k_b = (const float*)d_in[12];
  const float* v_w = (const float*)d_in[13];
  const float* v_b = (const float*)d_in[14];
  const float* envp_w = (const float*)d_in[15];
  const float* envp_b = (const float*)d_in[16];
  const float* genv_w = (const float*)d_in[17];
  const float* gt_w = (const float*)d_in[18];
  const float* gt_b = (const float*)d_in[19];
  float* out = (float*)d_out;

  const size_t NH = (size_t)NN * HH;
  float* W = (float*)d_ws;
  float* hA = W;             // final h
  float* hB = W + NH;        // layer buffer -> k -> ctx
  float* agg = W + 2 * NH;   // aggbf + h0bf (bf16) -> later q (f32)
  float* vbuf = W + 3 * NH;  // h1bf (bf16) -> later v -> gh
  float* gr = W + 4 * NH;
  float* env = W + 5 * NH;   // envT [KK][NN]
  float* genv = env + (size_t)NN * KK;  // genvT [KK][NN]
  float* inv = genv + (size_t)NN * KK;
  float* anorm = inv + NN;
  float* ksum = anorm + NN;
  float* red = ksum + HH;
  int* deg = (int*)(red + 4);
  int* start = deg + NN;
  int* cursor = start + NN + 1;
  int* bucket = cursor + NN;
  int* bsum = bucket + EE;          // CSB
  int* boff = bsum + CSB;           // CSB
  unsigned short* wb = (unsigned short*)(((uintptr_t)(boff + CSB) + 15) & ~(uintptr_t)15);
  unsigned short* Btfc0 = wb;                 // 256*128
  unsigned short* Btq = Btfc0 + 32768;
  unsigned short* Btk = Btq + 16384;
  unsigned short* Btv = Btk + 16384;
  unsigned short* Btgt = Btv + 16384;
  unsigned short* Btfc1 = Btgt + 16384;       // 40*128
  unsigned short* Btconv = Btfc1 + 5120;      // 2*4*128*256
  unsigned short* Btgenv = Btconv + 262144;   // 4*128*128
  unsigned short* Btktv = Btgenv + 65536;     // 128*128
  unsigned short* kTbf = Btktv + 16384;       // 128*MP
  unsigned short* vTbf = kTbf + (size_t)HH * MP;
  unsigned short* hsb = vTbf + (size_t)HH * MP;  // NN*128 bf16 (inv-scaled h)
  float* part = (float*)(((uintptr_t)(hsb + NH) + 15) & ~(uintptr_t)15);  // SKV*16384
  float* partK = part + (size_t)SKV * 16384;  // CSB*128
  float* partS = partK + (size_t)CSB * 128;   // CSB*2

  // bf16 twins carved from time-disjoint f32 regions:
  unsigned short* aggbf = (unsigned short*)agg;   // NH shorts (dead before q)
  unsigned short* h0bf = aggbf + NH;              // NH shorts (dead before q)
  unsigned short* h1bf = (unsigned short*)vbuf;   // NH shorts (dead before v)
  unsigned short* grbf = hsb;                     // reuse hsb after gather l=1

  float* q = agg;
  float* kb = hB;
  float* ctx = hB;
  float* gh = vbuf;
  float* envT = env;
  float* genvT = genv;

  dim3 b256(256);
  const int MB = (NN + 127) / 128;  // 391

  zero_i32_kernel<<<dim3((NN + 255) / 256), b256, 0, stream>>>(deg, NN);
  padzero_kernel<<<dim3((HH * (MP - NN) + 255) / 256), b256, 0, stream>>>(kTbf, vTbf);

  // CSR build (parallel 3-phase scan)
  count_kernel<<<dim3((EE + 255) / 256), b256, 0, stream>>>(ei, deg, EE);
  scan1_kernel<<<dim3(CSB), dim3(128), 0, stream>>>(deg, bsum, NN);
  scan2_kernel<<<dim3(1), dim3(512), 0, stream>>>(bsum, boff, CSB, start + NN);
  scan3_kernel<<<dim3(CSB), dim3(128), 0, stream>>>(deg, boff, start, cursor, inv, NN);
  fill_kernel<<<dim3((EE + 255) / 256), b256, 0, stream>>>(ei, cursor, bucket, EE);

  // weight prep
  tcvt_kernel<<<dim3((32768 + 255) / 256), b256, 0, stream>>>(fc0_w, Btfc0, 256, 128, 1);
  tcvt_kernel<<<dim3((16384 + 255) / 256), b256, 0, stream>>>(q_w, Btq, 128, 128, 1);
  tcvt_kernel<<<dim3((16384 + 255) / 256), b256, 0, stream>>>(k_w, Btk, 128, 128, 1);
  tcvt_kernel<<<dim3((16384 + 255) / 256), b256, 0, stream>>>(v_w, Btv, 128, 128, 1);
  tcvt_kernel<<<dim3((16384 + 255) / 256), b256, 0, stream>>>(gt_w, Btgt, 128, 128, 1);
  tcvt_kernel<<<dim3((5120 + 255) / 256), b256, 0, stream>>>(fc1_w, Btfc1, 128, 40, 1);
  tcvt_kernel<<<dim3((262144 + 255) / 256), b256, 0, stream>>>(conv_w, Btconv, 256, 128, 8);
  tcvt_kernel<<<dim3((65536 + 255) / 256), b256, 0, stream>>>(genv_w, Btgenv, 128, 128, 4);

  // fc0: h = relu(x @ fc0_w + b); emit hsb = bf16(inv*h) and h0bf = bf16(h)
  mgemm_kernel<<<dim3(MB), b256, 0, stream>>>(
      x, nullptr, DD, Btfc0, 256, 1, hA, HH, fc0_b, nullptr, 0, nullptr, nullptr,
      nullptr, hsb, inv, h0bf, NN, HH);

  // conv layers
  float* hcur = hA;
  float* hnext = hB;
  unsigned short* hbf_cur = h0bf;
  unsigned short* hbf_next = h1bf;
  for (int l = 0; l < 2; ++l) {
    env_softmax_kernel<<<dim3((NN + 63) / 64), b256, 0, stream>>>(
        hcur, env_w + (size_t)l * HH * KK, env_b + (size_t)l * KK, envT, NN);
    gather_kernel<<<dim3(NN / 4), b256, 0, stream>>>(hsb, start, bucket, inv, aggbf, NN);
    mconv_kernel<<<dim3(MB), b256, 0, stream>>>(
        aggbf, hbf_cur, envT, Btconv + (size_t)l * 131072, 256, 1, hcur, hnext,
        (l == 0) ? hsb : nullptr, inv, (l == 0) ? hbf_next : nullptr, NN);
    float* t = hcur; hcur = hnext; hnext = t;
    unsigned short* tb = hbf_cur; hbf_cur = hbf_next; hbf_next = tb;
  }
  // hcur == hA

  // q, k, v (k/v also emit transposed bf16 copies)
  mgemm_kernel<<<dim3(MB), b256, 0, stream>>>(
      hcur, nullptr, HH, Btq, 128, 0, q, HH, q_b, nullptr, 0, nullptr, nullptr,
      nullptr, nullptr, nullptr, nullptr, NN, HH);
  mgemm_kernel<<<dim3(MB), b256, 0, stream>>>(
      hcur, nullptr, HH, Btk, 128, 0, kb, HH, k_b, nullptr, 0, nullptr, nullptr,
      kTbf, nullptr, nullptr, nullptr, NN, HH);
  mgemm_kernel<<<dim3(MB), b256, 0, stream>>>(
      hcur, nullptr, HH, Btv, 128, 0, vbuf, HH, v_b, nullptr, 0, nullptr, nullptr,
      vTbf, nullptr, nullptr, nullptr, NN, HH);

  colstats1_kernel<<<dim3(CSB), b256, 0, stream>>>(q, kb, partK, partS, NN);
  colstats2_kernel<<<dim3(1), b256, 0, stream>>>(partK, partS, ksum, red);
  ktv_mfma_kernel<<<dim3(SKV), b256, 0, stream>>>(kTbf, vTbf, part);
  ktv_reduce_kernel<<<dim3(64), b256, 0, stream>>>(part, Btktv);
  scale_kernel<<<dim3(1), dim3(1), 0, stream>>>(red, NN);
  anorm_kernel<<<dim3((NN + 255) / 256), b256, 0, stream>>>(q, ksum, red, anorm, NN);

  // gr = (v + q @ ktv * red[2]) / anorm; emit grbf = bf16(gr)
  mgemm_kernel<<<dim3(MB), b256, 0, stream>>>(
      q, nullptr, HH, Btktv, 128, 3, gr, HH, nullptr, vbuf, HH, anorm, red,
      nullptr, nullptr, nullptr, grbf, NN, HH);

  // genvT = softmax(gr @ envp_w + envp_b), transposed
  env_softmax_kernel<<<dim3((NN + 63) / 64), b256, 0, stream>>>(gr, envp_w, envp_b, genvT, NN);

  // ctx = sum_k genv[:,k] * (gr @ genv_w[k])
  mconv_kernel<<<dim3(MB), b256, 0, stream>>>(
      grbf, nullptr, genvT, Btgenv, 128, 0, nullptr, ctx, nullptr, nullptr,
      nullptr, NN);

  // gh = relu(ctx @ gt_w + gt_b)
  mgemm_kernel<<<dim3(MB), b256, 0, stream>>>(
      ctx, nullptr, HH, Btgt, 128, 1, gh, HH, gt_b, nullptr, 0, nullptr, nullptr,
      nullptr, nullptr, nullptr, nullptr, NN, HH);

  // out = 0.5*((h+gh) @ fc1_w) + fc1_b
  mgemm_kernel<<<dim3(MB), b256, 0, stream>>>(
      hcur, gh, HH, Btfc1, 128, 5, out, CC, fc1_b, nullptr, 0, nullptr, nullptr,
      nullptr, nullptr, nullptr, nullptr, NN, CC);
}

// Round 11
// 697.912 us; speedup vs baseline: 5.3822x; 1.1173x over previous
//
#include <hip/hip_runtime.h>

#define DEV __device__ __forceinline__

static constexpr int NN = 50000;   // nodes
static constexpr int DD = 256;     // input dim
static constexpr int HH = 128;     // hidden
static constexpr int CC = 40;      // classes
static constexpr int KK = 4;       // envs
static constexpr int EE = 800000;  // edges
static constexpr int MP = 50176;   // padded node count (196*256, mult of 32)
static constexpr int SKV = 196;    // split-K blocks for ktv
static constexpr int CPB = 8;      // 32-node chunks per ktv block
static constexpr int CSB = 391;    // colstats / scan blocks (ceil(NN/128))
static constexpr int MBC = 391;    // row-tile blocks (ceil(NN/128))

typedef __attribute__((ext_vector_type(8))) short bf16x8;
typedef __attribute__((ext_vector_type(4))) float f32x4;

DEV unsigned short f2bf(float f) {
  union { float f; unsigned int i; } c; c.f = f;
  unsigned int x = c.i;
  x += 0x7FFFu + ((x >> 16) & 1u);   // round-to-nearest-even
  return (unsigned short)(x >> 16);
}
DEV float bfbits2f(unsigned int hi16bits) {
  union { unsigned int i; float f; } c; c.i = hi16bits; return c.f;
}

// harness-named kernel (unused in pipeline)
__global__ void MLEI_12970801234193_kernel(float* out, int n) {
  int i = blockIdx.x * blockDim.x + threadIdx.x;
  if (i < n) out[i] = 7.0f;
}

__global__ void zero_i32_kernel(int* p, int n) {
  int i = blockIdx.x * blockDim.x + threadIdx.x;
  if (i < n) p[i] = 0;
}

// zero the pad columns [NN, MP) of the transposed bf16 k/v buffers
__global__ void padzero_kernel(unsigned short* kT, unsigned short* vT) {
  int i = blockIdx.x * blockDim.x + threadIdx.x;
  const int PW = MP - NN;  // 176
  if (i >= HH * PW) return;
  int f = i / PW, c = i - f * PW;
  kT[(size_t)f * MP + NN + c] = 0;
  vT[(size_t)f * MP + NN + c] = 0;
}

// transpose-convert: dst[m][n][k] = bf16(src[m][k][n]); nm matrices of K x N
__global__ void tcvt_kernel(const float* __restrict__ src, unsigned short* __restrict__ dst,
                            int K, int N, int nm) {
  int i = blockIdx.x * blockDim.x + threadIdx.x;
  int tot = nm * K * N;
  if (i >= tot) return;
  int m = i / (K * N);
  int rem = i - m * K * N;
  int k = rem / N;
  int n = rem - k * N;
  dst[(size_t)m * K * N + (size_t)n * K + k] = f2bf(src[i]);
}

// ---------------- generic bf16-MFMA GEMM (2-deep prefetch, 1 barrier/chunk) ----------------
__global__ __launch_bounds__(256) void mgemm_kernel(
    const float* __restrict__ A, const float* __restrict__ Aadd, int lda,
    const unsigned short* __restrict__ Bt, int K,
    int emode, float* __restrict__ out, int ldo,
    const float* __restrict__ bias, const float* __restrict__ resid, int ldr,
    const float* __restrict__ anorm, const float* __restrict__ red,
    unsigned short* __restrict__ outT,
    unsigned short* __restrict__ outBf, const float* __restrict__ rowscale,
    int M, int Nd) {
  __shared__ unsigned short As[2][128][40];
  __shared__ unsigned short Bs[2][128][40];
  const int tid = threadIdx.x, lane = tid & 63, wave = tid >> 6;
  const int quad = lane >> 4, l16 = lane & 15;
  const int wm = (wave >> 1) * 64, wn = (wave & 1) * 64;
  const int bm = blockIdx.x * 128;
  const int srow = tid >> 1, skh = (tid & 1) * 16;
  const int grow = bm + srow;
  const bool rowok = grow < M;
  const bool colok = srow < Nd;
  const int NCH = K >> 5;

  f32x4 acc[4][4];
#pragma unroll
  for (int i = 0; i < 4; ++i)
#pragma unroll
    for (int j = 0; j < 4; ++j)
#pragma unroll
      for (int r = 0; r < 4; ++r) acc[i][j][r] = 0.f;

  float vaA[16], vaB[16];
  bf16x8 bA0, bA1, bB0, bB1;

  auto LOAD = [&](int kc, float (&va)[16], bf16x8& b0, bf16x8& b1) {
    int k0 = kc << 5;
    if (rowok) {
      const float* ap = A + (size_t)grow * lda + k0 + skh;
      float4 v0 = *(const float4*)(ap + 0), v1 = *(const float4*)(ap + 4);
      float4 v2 = *(const float4*)(ap + 8), v3 = *(const float4*)(ap + 12);
      va[0] = v0.x; va[1] = v0.y; va[2] = v0.z; va[3] = v0.w;
      va[4] = v1.x; va[5] = v1.y; va[6] = v1.z; va[7] = v1.w;
      va[8] = v2.x; va[9] = v2.y; va[10] = v2.z; va[11] = v2.w;
      va[12] = v3.x; va[13] = v3.y; va[14] = v3.z; va[15] = v3.w;
      if (Aadd) {
        const float* ap2 = Aadd + (size_t)grow * lda + k0 + skh;
        float4 w0 = *(const float4*)(ap2 + 0), w1 = *(const float4*)(ap2 + 4);
        float4 w2 = *(const float4*)(ap2 + 8), w3 = *(const float4*)(ap2 + 12);
        va[0] += w0.x; va[1] += w0.y; va[2] += w0.z; va[3] += w0.w;
        va[4] += w1.x; va[5] += w1.y; va[6] += w1.z; va[7] += w1.w;
        va[8] += w2.x; va[9] += w2.y; va[10] += w2.z; va[11] += w2.w;
        va[12] += w3.x; va[13] += w3.y; va[14] += w3.z; va[15] += w3.w;
      }
    }
    if (colok) {
      const unsigned short* bp = Bt + (size_t)srow * K + k0 + skh;
      b0 = *(const bf16x8*)(bp);
      b1 = *(const bf16x8*)(bp + 8);
    } else {
#pragma unroll
      for (int z = 0; z < 8; ++z) { b0[z] = 0; b1[z] = 0; }
    }
  };

  auto STORE = [&](int buf, const float (&va)[16], const bf16x8& b0, const bf16x8& b1) {
    bf16x8 p0, p1;
    if (rowok) {
#pragma unroll
      for (int z = 0; z < 8; ++z) { p0[z] = (short)f2bf(va[z]); p1[z] = (short)f2bf(va[z + 8]); }
    } else {
#pragma unroll
      for (int z = 0; z < 8; ++z) { p0[z] = 0; p1[z] = 0; }
    }
    *(bf16x8*)&As[buf][srow][skh] = p0;
    *(bf16x8*)&As[buf][srow][skh + 8] = p1;
    *(bf16x8*)&Bs[buf][srow][skh] = b0;
    *(bf16x8*)&Bs[buf][srow][skh + 8] = b1;
  };

  auto MFMA = [&](int buf) {
    bf16x8 af[4], bfr[4];
#pragma unroll
    for (int i = 0; i < 4; ++i) af[i] = *(const bf16x8*)&As[buf][wm + i * 16 + l16][quad * 8];
#pragma unroll
    for (int j = 0; j < 4; ++j) bfr[j] = *(const bf16x8*)&Bs[buf][wn + j * 16 + l16][quad * 8];
#pragma unroll
    for (int i = 0; i < 4; ++i)
#pragma unroll
      for (int j = 0; j < 4; ++j)
        acc[i][j] = __builtin_amdgcn_mfma_f32_16x16x32_bf16(af[i], bfr[j], acc[i][j], 0, 0, 0);
  };

  LOAD(0, vaA, bA0, bA1);
  if (NCH > 1) LOAD(1, vaB, bB0, bB1);
  STORE(0, vaA, bA0, bA1);
  __syncthreads();

  for (int kc = 0; kc < NCH; kc += 2) {
    if (kc + 2 < NCH) LOAD(kc + 2, vaA, bA0, bA1);
    MFMA(0);
    if (kc + 1 < NCH) STORE(1, vaB, bB0, bB1);
    __syncthreads();
    if (kc + 1 < NCH) {
      if (kc + 3 < NCH) LOAD(kc + 3, vaB, bB0, bB1);
      MFMA(1);
      if (kc + 2 < NCH) STORE(0, vaA, bA0, bA1);
      __syncthreads();
    }
  }

  float s2 = (emode == 3) ? red[2] : 0.f;
#pragma unroll
  for (int j = 0; j < 4; ++j) {
    int col = wn + j * 16 + l16;
    if (col >= Nd) continue;
    float bv = bias ? bias[col] : 0.f;
#pragma unroll
    for (int i = 0; i < 4; ++i) {
      int row0 = bm + wm + i * 16 + quad * 4;
      if (row0 >= M) continue;
      float o[4];
#pragma unroll
      for (int r = 0; r < 4; ++r) {
        float a = acc[i][j][r];
        int row = row0 + r;
        if (emode == 0) o[r] = a + bv;
        else if (emode == 1) o[r] = fmaxf(a + bv, 0.f);
        else if (emode == 3) o[r] = (resid[(size_t)row * ldr + col] + a * s2) / anorm[row];
        else o[r] = 0.5f * a + bv;
        out[(size_t)row * ldo + col] = o[r];
      }
      if (outT) {
        ushort4 pk;
        pk.x = f2bf(o[0]); pk.y = f2bf(o[1]); pk.z = f2bf(o[2]); pk.w = f2bf(o[3]);
        *(ushort4*)&outT[(size_t)col * MP + row0] = pk;
      }
      if (outBf) {
#pragma unroll
        for (int r = 0; r < 4; ++r) {
          float rs = rowscale ? rowscale[row0 + r] : 1.f;
          outBf[(size_t)(row0 + r) * 128 + col] = f2bf(o[r] * rs);
        }
      }
    }
  }
}

// ---------------- fused q/k/v GEMM: one dispatch, 3*MBC blocks ----------------
// which = blockIdx.x % 3 (consecutive blocks share the A row-tile -> L2 reuse).
__global__ __launch_bounds__(256) void mgemm_qkv_kernel(
    const float* __restrict__ A,
    const unsigned short* __restrict__ Btq, const unsigned short* __restrict__ Btk,
    const unsigned short* __restrict__ Btv,
    const float* __restrict__ q_b, const float* __restrict__ k_b,
    const float* __restrict__ v_b,
    float* __restrict__ outq, float* __restrict__ outk, float* __restrict__ outv,
    unsigned short* __restrict__ kT, unsigned short* __restrict__ vT, int M) {
  __shared__ unsigned short As[2][128][40];
  __shared__ unsigned short Bs[2][128][40];
  const int which = blockIdx.x % 3;
  const int bx = blockIdx.x / 3;
  const unsigned short* Bt = (which == 0) ? Btq : (which == 1) ? Btk : Btv;
  const float* bias = (which == 0) ? q_b : (which == 1) ? k_b : v_b;
  float* out = (which == 0) ? outq : (which == 1) ? outk : outv;
  unsigned short* outT = (which == 0) ? nullptr : (which == 1) ? kT : vT;

  const int tid = threadIdx.x, lane = tid & 63, wave = tid >> 6;
  const int quad = lane >> 4, l16 = lane & 15;
  const int wm = (wave >> 1) * 64, wn = (wave & 1) * 64;
  const int bm = bx * 128;
  const int srow = tid >> 1, skh = (tid & 1) * 16;
  const int grow = bm + srow;
  const bool rowok = grow < M;
  const int NCH = 4;  // K = 128

  f32x4 acc[4][4];
#pragma unroll
  for (int i = 0; i < 4; ++i)
#pragma unroll
    for (int j = 0; j < 4; ++j)
#pragma unroll
      for (int r = 0; r < 4; ++r) acc[i][j][r] = 0.f;

  float vaA[16], vaB[16];
  bf16x8 bA0, bA1, bB0, bB1;

  auto LOAD = [&](int kc, float (&va)[16], bf16x8& b0, bf16x8& b1) {
    int k0 = kc << 5;
    if (rowok) {
      const float* ap = A + (size_t)grow * 128 + k0 + skh;
      float4 v0 = *(const float4*)(ap + 0), v1 = *(const float4*)(ap + 4);
      float4 v2 = *(const float4*)(ap + 8), v3 = *(const float4*)(ap + 12);
      va[0] = v0.x; va[1] = v0.y; va[2] = v0.z; va[3] = v0.w;
      va[4] = v1.x; va[5] = v1.y; va[6] = v1.z; va[7] = v1.w;
      va[8] = v2.x; va[9] = v2.y; va[10] = v2.z; va[11] = v2.w;
      va[12] = v3.x; va[13] = v3.y; va[14] = v3.z; va[15] = v3.w;
    }
    const unsigned short* bp = Bt + (size_t)srow * 128 + k0 + skh;
    b0 = *(const bf16x8*)(bp);
    b1 = *(const bf16x8*)(bp + 8);
  };

  auto STORE = [&](int buf, const float (&va)[16], const bf16x8& b0, const bf16x8& b1) {
    bf16x8 p0, p1;
    if (rowok) {
#pragma unroll
      for (int z = 0; z < 8; ++z) { p0[z] = (short)f2bf(va[z]); p1[z] = (short)f2bf(va[z + 8]); }
    } else {
#pragma unroll
      for (int z = 0; z < 8; ++z) { p0[z] = 0; p1[z] = 0; }
    }
    *(bf16x8*)&As[buf][srow][skh] = p0;
    *(bf16x8*)&As[buf][srow][skh + 8] = p1;
    *(bf16x8*)&Bs[buf][srow][skh] = b0;
    *(bf16x8*)&Bs[buf][srow][skh + 8] = b1;
  };

  auto MFMA = [&](int buf) {
    bf16x8 af[4], bfr[4];
#pragma unroll
    for (int i = 0; i < 4; ++i) af[i] = *(const bf16x8*)&As[buf][wm + i * 16 + l16][quad * 8];
#pragma unroll
    for (int j = 0; j < 4; ++j) bfr[j] = *(const bf16x8*)&Bs[buf][wn + j * 16 + l16][quad * 8];
#pragma unroll
    for (int i = 0; i < 4; ++i)
#pragma unroll
      for (int j = 0; j < 4; ++j)
        acc[i][j] = __builtin_amdgcn_mfma_f32_16x16x32_bf16(af[i], bfr[j], acc[i][j], 0, 0, 0);
  };

  LOAD(0, vaA, bA0, bA1);
  LOAD(1, vaB, bB0, bB1);
  STORE(0, vaA, bA0, bA1);
  __syncthreads();

  for (int kc = 0; kc < NCH; kc += 2) {
    if (kc + 2 < NCH) LOAD(kc + 2, vaA, bA0, bA1);
    MFMA(0);
    if (kc + 1 < NCH) STORE(1, vaB, bB0, bB1);
    __syncthreads();
    if (kc + 1 < NCH) {
      if (kc + 3 < NCH) LOAD(kc + 3, vaB, bB0, bB1);
      MFMA(1);
      if (kc + 2 < NCH) STORE(0, vaA, bA0, bA1);
      __syncthreads();
    }
  }

#pragma unroll
  for (int j = 0; j < 4; ++j) {
    int col = wn + j * 16 + l16;
    float bv = bias[col];
#pragma unroll
    for (int i = 0; i < 4; ++i) {
      int row0 = bm + wm + i * 16 + quad * 4;
      if (row0 >= M) continue;
      float o[4];
#pragma unroll
      for (int r = 0; r < 4; ++r) {
        o[r] = acc[i][j][r] + bv;
        out[(size_t)(row0 + r) * 128 + col] = o[r];
      }
      if (outT) {
        ushort4 pk;
        pk.x = f2bf(o[0]); pk.y = f2bf(o[1]); pk.z = f2bf(o[2]); pk.w = f2bf(o[3]);
        *(ushort4*)&outT[(size_t)col * MP + row0] = pk;
      }
    }
  }
}

// ---------------- split-K MFMA kT@v (2-deep prefetch, 1 barrier/chunk) ----------------
__global__ __launch_bounds__(256) void ktv_mfma_kernel(
    const unsigned short* __restrict__ kT, const unsigned short* __restrict__ vT,
    float* __restrict__ part) {
  __shared__ unsigned short As[2][128][40];
  __shared__ unsigned short Bs[2][128][40];
  const int tid = threadIdx.x, lane = tid & 63, wave = tid >> 6;
  const int quad = lane >> 4, l16 = lane & 15;
  const int wm = (wave >> 1) * 64, wn = (wave & 1) * 64;
  const int srow = tid >> 1, skh = (tid & 1) * 16;

  f32x4 acc[4][4];
#pragma unroll
  for (int i = 0; i < 4; ++i)
#pragma unroll
    for (int j = 0; j < 4; ++j)
#pragma unroll
      for (int r = 0; r < 4; ++r) acc[i][j][r] = 0.f;

  const int nb0 = blockIdx.x * (CPB * 32);
  bf16x8 kA0, kA1, vA0, vA1, kB0, kB1, vB0, vB1;

  auto LOAD = [&](int c, bf16x8& k0, bf16x8& k1, bf16x8& v0, bf16x8& v1) {
    int nb = nb0 + c * 32;
    const unsigned short* kp = kT + (size_t)srow * MP + nb + skh;
    k0 = *(const bf16x8*)(kp);
    k1 = *(const bf16x8*)(kp + 8);
    const unsigned short* vp = vT + (size_t)srow * MP + nb + skh;
    v0 = *(const bf16x8*)(vp);
    v1 = *(const bf16x8*)(vp + 8);
  };
  auto STORE = [&](int buf, const bf16x8& k0, const bf16x8& k1, const bf16x8& v0, const bf16x8& v1) {
    *(bf16x8*)&As[buf][srow][skh] = k0;
    *(bf16x8*)&As[buf][srow][skh + 8] = k1;
    *(bf16x8*)&Bs[buf][srow][skh] = v0;
    *(bf16x8*)&Bs[buf][srow][skh + 8] = v1;
  };
  auto MFMA = [&](int buf) {
    bf16x8 af[4], bfr[4];
#pragma unroll
    for (int i = 0; i < 4; ++i) af[i] = *(const bf16x8*)&As[buf][wm + i * 16 + l16][quad * 8];
#pragma unroll
    for (int j = 0; j < 4; ++j) bfr[j] = *(const bf16x8*)&Bs[buf][wn + j * 16 + l16][quad * 8];
#pragma unroll
    for (int i = 0; i < 4; ++i)
#pragma unroll
      for (int j = 0; j < 4; ++j)
        acc[i][j] = __builtin_amdgcn_mfma_f32_16x16x32_bf16(af[i], bfr[j], acc[i][j], 0, 0, 0);
  };

  LOAD(0, kA0, kA1, vA0, vA1);
  LOAD(1, kB0, kB1, vB0, vB1);
  STORE(0, kA0, kA1, vA0, vA1);
  __syncthreads();

  for (int c = 0; c < CPB; c += 2) {
    if (c + 2 < CPB) LOAD(c + 2, kA0, kA1, vA0, vA1);
    MFMA(0);
    if (c + 1 < CPB) STORE(1, kB0, kB1, vB0, vB1);
    __syncthreads();
    if (c + 1 < CPB) {
      if (c + 3 < CPB) LOAD(c + 3, kB0, kB1, vB0, vB1);
      MFMA(1);
      if (c + 2 < CPB) STORE(0, kA0, kA1, vA0, vA1);
      __syncthreads();
    }
  }

  float* pb = part + (size_t)blockIdx.x * 16384;
#pragma unroll
  for (int j = 0; j < 4; ++j) {
    int col = wn + j * 16 + l16;
#pragma unroll
    for (int i = 0; i < 4; ++i) {
      int row0 = wm + i * 16 + quad * 4;
      *(f32x4*)&pb[col * 128 + row0] = acc[i][j];
    }
  }
}

__global__ void ktv_reduce_kernel(const float* __restrict__ part,
                                  unsigned short* __restrict__ Btktv) {
  int i = blockIdx.x * blockDim.x + threadIdx.x;
  if (i >= 16384) return;
  float s0 = 0.f, s1 = 0.f, s2 = 0.f, s3 = 0.f;
  int b = 0;
  for (; b + 3 < SKV; b += 4) {
    s0 += part[(size_t)b * 16384 + i];
    s1 += part[(size_t)(b + 1) * 16384 + i];
    s2 += part[(size_t)(b + 2) * 16384 + i];
    s3 += part[(size_t)(b + 3) * 16384 + i];
  }
  for (; b < SKV; ++b) s0 += part[(size_t)b * 16384 + i];
  Btktv[i] = f2bf((s0 + s1) + (s2 + s3));
}

// ---------------- env-weighted MFMA GEMM (conv & ctx) ----------------
// out[n,:] = sum_e env[n,e] * (hi[n,:] @ W_e)  ==  sum_e (env_e ⊙ hi) @ W_e
// kc-outer / e-inner: A chunk loaded from global ONCE per kc (4x traffic cut),
// re-staged to LDS scaled by env_e per phase. A prefetched one chunk ahead
// (4-phase latency budget); B prefetched 1 phase ahead.
__global__ __launch_bounds__(256) void mconv_kernel(
    const float* __restrict__ A1, const float* __restrict__ A2,
    const float* __restrict__ env, const unsigned short* __restrict__ Btc, int Kpe,
    int relu_resid, const float* __restrict__ resid, float* __restrict__ out,
    unsigned short* __restrict__ outBf, const float* __restrict__ rowscale, int M) {
  __shared__ unsigned short As[2][128][40];
  __shared__ unsigned short Bs[2][128][40];
  const int tid = threadIdx.x, lane = tid & 63, wave = tid >> 6;
  const int quad = lane >> 4, l16 = lane & 15;
  const int wm = (wave >> 1) * 64, wn = (wave & 1) * 64;
  const int bm = blockIdx.x * 128;
  const int srow = tid >> 1, skh = (tid & 1) * 16;
  const int grow = bm + srow;
  const bool rowok = grow < M;

  float ev0 = 0.f, ev1 = 0.f, ev2 = 0.f, ev3 = 0.f;
  if (rowok) {
    float4 e4 = *(const float4*)&env[(size_t)grow * 4];
    ev0 = e4.x; ev1 = e4.y; ev2 = e4.z; ev3 = e4.w;
  }

  const int npe = Kpe >> 5;             // K-chunks per env (8 or 4)
  const int NPH = npe << 2;             // total phases

  f32x4 acc[4][4];
#pragma unroll
  for (int i = 0; i < 4; ++i)
#pragma unroll
    for (int j = 0; j < 4; ++j)
#pragma unroll
      for (int r = 0; r < 4; ++r) acc[i][j][r] = 0.f;

  float aC[16], aN[16];
  bf16x8 b0, b1;

  auto LOADA = [&](int kc, float (&dst)[16]) {
    int kof = kc << 5;
    const float* Asrc = A1;
    int ks = kof;
    if (A2 && kof >= 128) { Asrc = A2; ks = kof - 128; }
    if (rowok) {
      const float* ap = Asrc + (size_t)grow * 128 + ks + skh;
      float4 v0 = *(const float4*)(ap + 0), v1 = *(const float4*)(ap + 4);
      float4 v2 = *(const float4*)(ap + 8), v3 = *(const float4*)(ap + 12);
      dst[0] = v0.x; dst[1] = v0.y; dst[2] = v0.z; dst[3] = v0.w;
      dst[4] = v1.x; dst[5] = v1.y; dst[6] = v1.z; dst[7] = v1.w;
      dst[8] = v2.x; dst[9] = v2.y; dst[10] = v2.z; dst[11] = v2.w;
      dst[12] = v3.x; dst[13] = v3.y; dst[14] = v3.z; dst[15] = v3.w;
    }
  };

  auto LOADB = [&](int e, int kc) {
    const unsigned short* bp = Btc + ((size_t)e * 128 + srow) * Kpe + (kc << 5) + skh;
    b0 = *(const bf16x8*)(bp);
    b1 = *(const bf16x8*)(bp + 8);
  };

  auto STORE = [&](int buf, const float (&a)[16], float ev) {
    bf16x8 p0, p1;
    if (rowok) {
#pragma unroll
      for (int z = 0; z < 8; ++z) {
        p0[z] = (short)f2bf(a[z] * ev);
        p1[z] = (short)f2bf(a[z + 8] * ev);
      }
    } else {
#pragma unroll
      for (int z = 0; z < 8; ++z) { p0[z] = 0; p1[z] = 0; }
    }
    *(bf16x8*)&As[buf][srow][skh] = p0;
    *(bf16x8*)&As[buf][srow][skh + 8] = p1;
    *(bf16x8*)&Bs[buf][srow][skh] = b0;
    *(bf16x8*)&Bs[buf][srow][skh + 8] = b1;
  };

  auto MFMA = [&](int buf) {
    bf16x8 af[4], bfr[4];
#pragma unroll
    for (int i = 0; i < 4; ++i) af[i] = *(const bf16x8*)&As[buf][wm + i * 16 + l16][quad * 8];
#pragma unroll
    for (int j = 0; j < 4; ++j) bfr[j] = *(const bf16x8*)&Bs[buf][wn + j * 16 + l16][quad * 8];
#pragma unroll
    for (int i = 0; i < 4; ++i)
#pragma unroll
      for (int j = 0; j < 4; ++j)
        acc[i][j] = __builtin_amdgcn_mfma_f32_16x16x32_bf16(af[i], bfr[j], acc[i][j], 0, 0, 0);
  };

  // prologue: A chunks 0 and 1 in flight, B(e=0,kc=0), stage phase 0
  LOADA(0, aC);
  LOADB(0, 0);
  if (npe > 1) LOADA(1, aN);
  STORE(0, aC, ev0);
  __syncthreads();

  for (int kc = 0; kc < npe; ++kc) {
#pragma unroll
    for (int e = 0; e < 4; ++e) {
      const int p = (kc << 2) + e;
      const int cur = e & 1;
      const bool more = (p + 1) < NPH;
      if (more) {
        LOADB((e + 1) & 3, kc + (e == 3 ? 1 : 0));
      }
      MFMA(cur);
      if (more) {
        if (e == 3) {
#pragma unroll
          for (int z = 0; z < 16; ++z) aC[z] = aN[z];
        }
        float evn = (e == 0) ? ev1 : (e == 1) ? ev2 : (e == 2) ? ev3 : ev0;
        STORE(cur ^ 1, aC, evn);
        if (e == 3 && kc + 2 < npe) LOADA(kc + 2, aN);
      }
      __syncthreads();
    }
  }

#pragma unroll
  for (int j = 0; j < 4; ++j) {
    int col = wn + j * 16 + l16;
#pragma unroll
    for (int i = 0; i < 4; ++i) {
      int row0 = bm + wm + i * 16 + quad * 4;
      if (row0 >= M) continue;
#pragma unroll
      for (int r = 0; r < 4; ++r) {
        int row = row0 + r;
        float a = acc[i][j][r];
        float o = relu_resid ? fmaxf(a + resid[(size_t)row * 128 + col], 0.f) : a;
        out[(size_t)row * 128 + col] = o;
        if (outBf) {
          float rs = rowscale ? rowscale[row] : 1.f;
          outBf[(size_t)row * 128 + col] = f2bf(o * rs);
        }
      }
    }
  }
}

// ---------------- graph kernels ----------------
__global__ void count_kernel(const int* ei, int* deg, int E) {
  int e = blockIdx.x * blockDim.x + threadIdx.x;
  if (e >= E) return;
  atomicAdd(&deg[ei[E + e]], 1);
}

// 3-phase parallel prefix scan over deg[0..n)
__global__ __launch_bounds__(128) void scan1_kernel(const int* __restrict__ deg,
                                                    int* __restrict__ bsum, int n) {
  __shared__ int sh[128];
  int t = threadIdx.x;
  int i = blockIdx.x * 128 + t;
  sh[t] = (i < n) ? deg[i] : 0;
  __syncthreads();
  for (int off = 64; off > 0; off >>= 1) {
    if (t < off) sh[t] += sh[t + off];
    __syncthreads();
  }
  if (t == 0) bsum[blockIdx.x] = sh[0];
}

__global__ __launch_bounds__(512) void scan2_kernel(const int* __restrict__ bsum,
                                                    int* __restrict__ boff, int nb,
                                                    int* __restrict__ startN) {
  __shared__ int sh[512];
  int t = threadIdx.x;
  int v0 = (t < nb) ? bsum[t] : 0;
  sh[t] = v0;
  __syncthreads();
  for (int off = 1; off < 512; off <<= 1) {
    int v = sh[t];
    int add = (t >= off) ? sh[t - off] : 0;
    __syncthreads();
    sh[t] = v + add;
    __syncthreads();
  }
  if (t < nb) boff[t] = sh[t] - v0;
  if (t == nb - 1) *startN = sh[t];
}

__global__ __launch_bounds__(128) void scan3_kernel(const int* __restrict__ deg,
                                                    const int* __restrict__ boff,
                                                    int* __restrict__ start,
                                                    int* __restrict__ cursor,
                                                    float* __restrict__ inv, int n) {
  __shared__ int sh[128];
  int t = threadIdx.x;
  int i = blockIdx.x * 128 + t;
  int d = (i < n) ? deg[i] : 0;
  sh[t] = d;
  __syncthreads();
  for (int off = 1; off < 128; off <<= 1) {
    int v = sh[t];
    int add = (t >= off) ? sh[t - off] : 0;
    __syncthreads();
    sh[t] = v + add;
    __syncthreads();
  }
  if (i < n) {
    int p = boff[blockIdx.x] + sh[t] - d;
    start[i] = p; cursor[i] = p;
    inv[i] = (d > 0) ? rsqrtf((float)d) : 0.f;
  }
}

__global__ void fill_kernel(const int* ei, int* cursor, int* bucket, int E) {
  int e = blockIdx.x * blockDim.x + threadIdx.x;
  if (e >= E) return;
  int r = ei[e], c = ei[E + e];
  int pos = atomicAdd(&cursor[c], 1);
  bucket[pos] = r;
}

// gather from pre-scaled bf16 h: agg[n,f] = inv[n] * sum_edges hs[src][f]
// wave split into two 32-lane halves over even/odd edges + unroll-by-2:
// 4 independent bucket->hs load chains in flight per wave.
__global__ __launch_bounds__(256) void gather_kernel(
    const unsigned short* __restrict__ hs, const int* __restrict__ start,
    const int* __restrict__ bucket, const float* __restrict__ inv,
    float* __restrict__ agg, int n) {
  int node = blockIdx.x * 4 + (threadIdx.x >> 6);
  if (node >= n) return;
  const int lane = threadIdx.x & 63;
  const int half = lane >> 5, l32 = lane & 31;
  const int f4 = l32 * 4;
  int s0 = start[node], s1 = start[node + 1];
  float a0 = 0.f, a1 = 0.f, a2 = 0.f, a3 = 0.f;
  int j = s0 + half;
  for (; j + 2 < s1; j += 4) {
    int r0 = bucket[j], r1 = bucket[j + 2];
    uint2 u0 = *(const uint2*)&hs[(size_t)r0 * 128 + f4];
    uint2 u1 = *(const uint2*)&hs[(size_t)r1 * 128 + f4];
    a0 += bfbits2f(u0.x << 16); a1 += bfbits2f(u0.x & 0xFFFF0000u);
    a2 += bfbits2f(u0.y << 16); a3 += bfbits2f(u0.y & 0xFFFF0000u);
    a0 += bfbits2f(u1.x << 16); a1 += bfbits2f(u1.x & 0xFFFF0000u);
    a2 += bfbits2f(u1.y << 16); a3 += bfbits2f(u1.y & 0xFFFF0000u);
  }
  for (; j < s1; j += 2) {
    int r = bucket[j];
    uint2 u = *(const uint2*)&hs[(size_t)r * 128 + f4];
    a0 += bfbits2f(u.x << 16); a1 += bfbits2f(u.x & 0xFFFF0000u);
    a2 += bfbits2f(u.y << 16); a3 += bfbits2f(u.y & 0xFFFF0000u);
  }
  a0 += __shfl_xor(a0, 32);
  a1 += __shfl_xor(a1, 32);
  a2 += __shfl_xor(a2, 32);
  a3 += __shfl_xor(a3, 32);
  if (half == 0) {
    float iv = inv[node];
    *(float4*)&agg[(size_t)node * 128 + f4] = make_float4(iv * a0, iv * a1, iv * a2, iv * a3);
  }
}

// ---------------- env softmax ----------------
__global__ __launch_bounds__(256) void env_softmax_kernel(const float* __restrict__ h,
                                                          const float* __restrict__ w,
                                                          const float* __restrict__ b,
                                                          float* __restrict__ env, int M) {
  __shared__ float hsd[64][129];
  __shared__ float ws[HH * KK];
  int tid = threadIdx.x;
  int base = blockIdx.x * 64;
  for (int i = tid; i < HH * KK; i += 256) ws[i] = w[i];
  {
    int row = tid >> 2, q4 = (tid & 3) * 32;
    int g = base + row;
    if (g < M) {
      const float* hp = h + (size_t)g * HH + q4;
#pragma unroll
      for (int z = 0; z < 8; ++z) {
        float4 v = *(const float4*)(hp + z * 4);
        hsd[row][q4 + z * 4 + 0] = v.x; hsd[row][q4 + z * 4 + 1] = v.y;
        hsd[row][q4 + z * 4 + 2] = v.z; hsd[row][q4 + z * 4 + 3] = v.w;
      }
    }
  }
  __syncthreads();
  if (tid < 64 && base + tid < M) {
    float l0 = b[0], l1 = b[1], l2 = b[2], l3 = b[3];
    for (int d = 0; d < HH; ++d) {
      float hv = hsd[tid][d];
      l0 += hv * ws[d * 4 + 0]; l1 += hv * ws[d * 4 + 1];
      l2 += hv * ws[d * 4 + 2]; l3 += hv * ws[d * 4 + 3];
    }
    float m = fmaxf(fmaxf(l0, l1), fmaxf(l2, l3));
    float e0 = __expf(l0 - m), e1 = __expf(l1 - m), e2 = __expf(l2 - m), e3 = __expf(l3 - m);
    float s = 1.f / (e0 + e1 + e2 + e3);
    *(float4*)(env + (size_t)(base + tid) * KK) = make_float4(e0 * s, e1 * s, e2 * s, e3 * s);
  }
}

// ---------------- two-stage colstats ----------------
__global__ __launch_bounds__(256) void colstats1_kernel(
    const float* __restrict__ q, const float* __restrict__ k,
    float* __restrict__ partK, float* __restrict__ partS, int n) {
  int tid = threadIdx.x, ty = tid >> 7, tx = tid & 127;
  int lo = blockIdx.x * 128 + ty, hi = min(n, blockIdx.x * 128 + 128);
  float ks = 0.f, sq = 0.f, sk = 0.f;
  for (int r = lo; r < hi; r += 2) {
    float kv = k[(size_t)r * HH + tx];
    float qv = q[(size_t)r * HH + tx];
    ks += kv; sq += qv * qv; sk += kv * kv;
  }
  __shared__ float sks[2][128];
  __shared__ float ssq[256], ssk[256];
  sks[ty][tx] = ks; ssq[tid] = sq; ssk[tid] = sk;
  __syncthreads();
  if (ty == 0) partK[(size_t)blockIdx.x * 128 + tx] = sks[0][tx] + sks[1][tx];
  for (int off = 128; off > 0; off >>= 1) {
    if (tid < off) { ssq[tid] += ssq[tid + off]; ssk[tid] += ssk[tid + off]; }
    __syncthreads();
  }
  if (tid == 0) { partS[blockIdx.x * 2] = ssq[0]; partS[blockIdx.x * 2 + 1] = ssk[0]; }
}

__global__ __launch_bounds__(256) void colstats2_kernel(
    const float* __restrict__ partK, const float* __restrict__ partS,
    float* __restrict__ ksum, float* __restrict__ red) {
  int t = threadIdx.x;
  if (t < 128) {
    float s = 0.f;
    for (int b = 0; b < CSB; ++b) s += partK[(size_t)b * 128 + t];
    ksum[t] = s;
  } else if (t == 128 || t == 129) {
    float s = 0.f;
    for (int b = 0; b < CSB; ++b) s += partS[b * 2 + (t - 128)];
    red[t - 128] = s;
  }
}

__global__ void scale_kernel(float* red, int n) {
  float nq = fmaxf(sqrtf(red[0]), 1e-12f);
  float nk = fmaxf(sqrtf(red[1]), 1e-12f);
  red[2] = 1.f / (nq * nk * (float)n);
}

__global__ __launch_bounds__(256) void anorm_kernel(const float* q, const float* ksum,
                                                    const float* red, float* anorm, int M) {
  __shared__ float ks[HH];
  for (int i = threadIdx.x; i < HH; i += blockDim.x) ks[i] = ksum[i];
  __syncthreads();
  int n = blockIdx.x * blockDim.x + threadIdx.x;
  if (n >= M) return;
  const float* qp = q + (size_t)n * HH;
  float d = 0.f;
  for (int i = 0; i < HH; ++i) d += qp[i] * ks[i];
  float a = 1.f + d * red[2];
  anorm[n] = fmaxf(a, 1e-12f);
}

// ---------------- host launcher ----------------
extern "C" void kernel_launch(void* const* d_in, const int* in_sizes, int n_in,
                              void* d_out, int out_size, void* d_ws, size_t ws_size,
                              hipStream_t stream) {
  const float* x = (const float*)d_in[0];
  const int* ei = (const int*)d_in[1];
  const float* fc0_w = (const float*)d_in[2];
  const float* fc0_b = (const float*)d_in[3];
  const float* fc1_w = (const float*)d_in[4];
  const float* fc1_b = (const float*)d_in[5];
  const float* env_w = (const float*)d_in[6];
  const float* env_b = (const float*)d_in[7];
  const float* conv_w = (const float*)d_in[8];
  const float* q_w = (const float*)d_in[9];
  const float* q_b = (const float*)d_in[10];
  const float* k_w = (const float*)d_in[11];
  const float* k_b = (const float*)d_in[12];
  const float* v_w = (const float*)d_in[13];
  const float* v_b = (const float*)d_in[14];
  const float* envp_w = (const float*)d_in[15];
  const float* envp_b = (const float*)d_in[16];
  const float* genv_w = (const float*)d_in[17];
  const float* gt_w = (const float*)d_in[18];
  const float* gt_b = (const float*)d_in[19];
  float* out = (float*)d_out;

  const size_t NH = (size_t)NN * HH;
  float* W = (float*)d_ws;
  float* hA = W;             // final h
  float* hB = W + NH;        // layer buffer -> k -> ctx
  float* agg = W + 2 * NH;   // agg -> q
  float* vbuf = W + 3 * NH;  // v -> gh
  float* gr = W + 4 * NH;
  float* env = W + 5 * NH;
  float* genv = env + (size_t)NN * KK;
  float* inv = genv + (size_t)NN * KK;
  float* anorm = inv + NN;
  float* ksum = anorm + NN;
  float* red = ksum + HH;
  int* deg = (int*)(red + 4);
  int* start = deg + NN;
  int* cursor = start + NN + 1;
  int* bucket = cursor + NN;
  int* bsum = bucket + EE;          // CSB
  int* boff = bsum + CSB;           // CSB
  unsigned short* wb = (unsigned short*)(((uintptr_t)(boff + CSB) + 15) & ~(uintptr_t)15);
  unsigned short* Btfc0 = wb;                 // 256*128
  unsigned short* Btq = Btfc0 + 32768;
  unsigned short* Btk = Btq + 16384;
  unsigned short* Btv = Btk + 16384;
  unsigned short* Btgt = Btv + 16384;
  unsigned short* Btfc1 = Btgt + 16384;       // 40*128
  unsigned short* Btconv = Btfc1 + 5120;      // 2*4*128*256
  unsigned short* Btgenv = Btconv + 262144;   // 4*128*128
  unsigned short* Btktv = Btgenv + 65536;     // 128*128
  unsigned short* kTbf = Btktv + 16384;       // 128*MP
  unsigned short* vTbf = kTbf + (size_t)HH * MP;
  unsigned short* hsb = vTbf + (size_t)HH * MP;  // NN*128 bf16 (scaled h)
  float* part = (float*)(((uintptr_t)(hsb + NH) + 15) & ~(uintptr_t)15);  // SKV*16384
  float* partK = part + (size_t)SKV * 16384;  // CSB*128
  float* partS = partK + (size_t)CSB * 128;   // CSB*2

  float* q = agg;
  float* kb = hB;
  float* ctx = hB;
  float* gh = vbuf;

  dim3 b256(256);
  const int MB = MBC;  // 391

  zero_i32_kernel<<<dim3((NN + 255) / 256), b256, 0, stream>>>(deg, NN);
  padzero_kernel<<<dim3((HH * (MP - NN) + 255) / 256), b256, 0, stream>>>(kTbf, vTbf);

  // CSR build (parallel 3-phase scan)
  count_kernel<<<dim3((EE + 255) / 256), b256, 0, stream>>>(ei, deg, EE);
  scan1_kernel<<<dim3(CSB), dim3(128), 0, stream>>>(deg, bsum, NN);
  scan2_kernel<<<dim3(1), dim3(512), 0, stream>>>(bsum, boff, CSB, start + NN);
  scan3_kernel<<<dim3(CSB), dim3(128), 0, stream>>>(deg, boff, start, cursor, inv, NN);
  fill_kernel<<<dim3((EE + 255) / 256), b256, 0, stream>>>(ei, cursor, bucket, EE);

  // weight prep
  tcvt_kernel<<<dim3((32768 + 255) / 256), b256, 0, stream>>>(fc0_w, Btfc0, 256, 128, 1);
  tcvt_kernel<<<dim3((16384 + 255) / 256), b256, 0, stream>>>(q_w, Btq, 128, 128, 1);
  tcvt_kernel<<<dim3((16384 + 255) / 256), b256, 0, stream>>>(k_w, Btk, 128, 128, 1);
  tcvt_kernel<<<dim3((16384 + 255) / 256), b256, 0, stream>>>(v_w, Btv, 128, 128, 1);
  tcvt_kernel<<<dim3((16384 + 255) / 256), b256, 0, stream>>>(gt_w, Btgt, 128, 128, 1);
  tcvt_kernel<<<dim3((5120 + 255) / 256), b256, 0, stream>>>(fc1_w, Btfc1, 128, 40, 1);
  tcvt_kernel<<<dim3((262144 + 255) / 256), b256, 0, stream>>>(conv_w, Btconv, 256, 128, 8);
  tcvt_kernel<<<dim3((65536 + 255) / 256), b256, 0, stream>>>(genv_w, Btgenv, 128, 128, 4);

  // fc0: h = relu(x @ fc0_w + b); also emit hs = bf16(inv*h) for gather
  mgemm_kernel<<<dim3(MB), b256, 0, stream>>>(
      x, nullptr, DD, Btfc0, 256, 1, hA, HH, fc0_b, nullptr, 0, nullptr, nullptr,
      nullptr, hsb, inv, NN, HH);

  // conv layers
  float* hcur = hA;
  float* hnext = hB;
  for (int l = 0; l < 2; ++l) {
    env_softmax_kernel<<<dim3((NN + 63) / 64), b256, 0, stream>>>(
        hcur, env_w + (size_t)l * HH * KK, env_b + (size_t)l * KK, env, NN);
    gather_kernel<<<dim3(NN / 4), b256, 0, stream>>>(hsb, start, bucket, inv, agg, NN);
    mconv_kernel<<<dim3(MB), b256, 0, stream>>>(
        agg, hcur, env, Btconv + (size_t)l * 131072, 256, 1, hcur, hnext,
        (l == 0) ? hsb : nullptr, inv, NN);
    float* t = hcur; hcur = hnext; hnext = t;
  }
  // hcur == hA

  // fused q/k/v: one dispatch, 3*MB blocks (k/v also emit transposed bf16)
  mgemm_qkv_kernel<<<dim3(3 * MB), b256, 0, stream>>>(
      hcur, Btq, Btk, Btv, q_b, k_b, v_b, q, kb, vbuf, kTbf, vTbf, NN);

  colstats1_kernel<<<dim3(CSB), b256, 0, stream>>>(q, kb, partK, partS, NN);
  colstats2_kernel<<<dim3(1), b256, 0, stream>>>(partK, partS, ksum, red);
  ktv_mfma_kernel<<<dim3(SKV), b256, 0, stream>>>(kTbf, vTbf, part);
  ktv_reduce_kernel<<<dim3(64), b256, 0, stream>>>(part, Btktv);
  scale_kernel<<<dim3(1), dim3(1), 0, stream>>>(red, NN);
  anorm_kernel<<<dim3((NN + 255) / 256), b256, 0, stream>>>(q, ksum, red, anorm, NN);

  // gr = (v + q @ ktv * red[2]) / anorm
  mgemm_kernel<<<dim3(MB), b256, 0, stream>>>(
      q, nullptr, HH, Btktv, 128, 3, gr, HH, nullptr, vbuf, HH, anorm, red,
      nullptr, nullptr, nullptr, NN, HH);

  // genv = softmax(gr @ envp_w + envp_b)
  env_softmax_kernel<<<dim3((NN + 63) / 64), b256, 0, stream>>>(gr, envp_w, envp_b, genv, NN);

  // ctx = sum_k genv[:,k] * (gr @ genv_w[k])
  mconv_kernel<<<dim3(MB), b256, 0, stream>>>(
      gr, nullptr, genv, Btgenv, 128, 0, nullptr, ctx, nullptr, nullptr, NN);

  // gh = relu(ctx @ gt_w + gt_b)
  mgemm_kernel<<<dim3(MB), b256, 0, stream>>>(
      ctx, nullptr, HH, Btgt, 128, 1, gh, HH, gt_b, nullptr, 0, nullptr, nullptr,
      nullptr, nullptr, nullptr, NN, HH);

  // out = 0.5*((h+gh) @ fc1_w) + fc1_b
  mgemm_kernel<<<dim3(MB), b256, 0, stream>>>(
      hcur, gh, HH, Btfc1, 128, 5, out, CC, fc1_b, nullptr, 0, nullptr, nullptr,
      nullptr, nullptr, nullptr, NN, CC);
}

// Round 12
// 657.265 us; speedup vs baseline: 5.7151x; 1.0618x over previous
//
#include <hip/hip_runtime.h>

#define DEV __device__ __forceinline__

static constexpr int NN = 50000;   // nodes
static constexpr int DD = 256;     // input dim
static constexpr int HH = 128;     // hidden
static constexpr int CC = 40;      // classes
static constexpr int KK = 4;       // envs
static constexpr int EE = 800000;  // edges
static constexpr int MP = 50176;   // padded node count (196*256, mult of 32)
static constexpr int SKV = 196;    // split-K blocks for ktv
static constexpr int CPB = 8;      // 32-node chunks per ktv block
static constexpr int CSB = 391;    // colstats / scan blocks (ceil(NN/128))
static constexpr int MBC = 391;    // row-tile blocks (ceil(NN/128))

typedef __attribute__((ext_vector_type(8))) short bf16x8;
typedef __attribute__((ext_vector_type(4))) float f32x4;

DEV unsigned short f2bf(float f) {
  union { float f; unsigned int i; } c; c.f = f;
  unsigned int x = c.i;
  x += 0x7FFFu + ((x >> 16) & 1u);   // round-to-nearest-even
  return (unsigned short)(x >> 16);
}
DEV float bfbits2f(unsigned int hi16bits) {
  union { unsigned int i; float f; } c; c.i = hi16bits; return c.f;
}

// harness-named kernel (unused in pipeline)
__global__ void MLEI_12970801234193_kernel(float* out, int n) {
  int i = blockIdx.x * blockDim.x + threadIdx.x;
  if (i < n) out[i] = 7.0f;
}

// one tcvt element: dst[m][n][k] = bf16(src[m][k][n]) for K x N matrices
DEV void tc(const float* __restrict__ src, unsigned short* __restrict__ dst,
            int i, int K, int N) {
  int m = i / (K * N);
  int rem = i - m * K * N;
  int k = rem / N;
  int n = rem - k * N;
  dst[(size_t)m * K * N + (size_t)n * K + k] = f2bf(src[i]);
}

// ---------------- fused prep: deg zero + kT/vT pad + ALL weight tcvt ----------------
// segments (elements): 50000 deg | 22528 pad | 32768 fc0 | 4x16384 q/k/v/gt |
// 5120 fc1 | 262144 conv | 65536 genv   => 503632 total
__global__ __launch_bounds__(256) void prep_kernel(
    int* __restrict__ deg, unsigned short* __restrict__ kT, unsigned short* __restrict__ vT,
    const float* __restrict__ fc0_w, unsigned short* __restrict__ Btfc0,
    const float* __restrict__ q_w, unsigned short* __restrict__ Btq,
    const float* __restrict__ k_w, unsigned short* __restrict__ Btk,
    const float* __restrict__ v_w, unsigned short* __restrict__ Btv,
    const float* __restrict__ gt_w, unsigned short* __restrict__ Btgt,
    const float* __restrict__ fc1_w, unsigned short* __restrict__ Btfc1,
    const float* __restrict__ conv_w, unsigned short* __restrict__ Btconv,
    const float* __restrict__ genv_w, unsigned short* __restrict__ Btgenv) {
  int i = blockIdx.x * 256 + threadIdx.x;
  if (i < NN) { deg[i] = 0; return; }
  i -= NN;
  const int PW = MP - NN;  // 176
  if (i < HH * PW) {
    int f = i / PW, c = i - f * PW;
    kT[(size_t)f * MP + NN + c] = 0;
    vT[(size_t)f * MP + NN + c] = 0;
    return;
  }
  i -= HH * PW;
  if (i < 32768) { tc(fc0_w, Btfc0, i, 256, 128); return; }
  i -= 32768;
  if (i < 16384) { tc(q_w, Btq, i, 128, 128); return; }
  i -= 16384;
  if (i < 16384) { tc(k_w, Btk, i, 128, 128); return; }
  i -= 16384;
  if (i < 16384) { tc(v_w, Btv, i, 128, 128); return; }
  i -= 16384;
  if (i < 16384) { tc(gt_w, Btgt, i, 128, 128); return; }
  i -= 16384;
  if (i < 5120) { tc(fc1_w, Btfc1, i, 128, 40); return; }
  i -= 5120;
  if (i < 262144) { tc(conv_w, Btconv, i, 256, 128); return; }
  i -= 262144;
  if (i < 65536) { tc(genv_w, Btgenv, i, 128, 128); }
}

// ---------------- generic bf16-MFMA GEMM (2-deep prefetch, 1 barrier/chunk) ----------------
__global__ __launch_bounds__(256) void mgemm_kernel(
    const float* __restrict__ A, const float* __restrict__ Aadd, int lda,
    const unsigned short* __restrict__ Bt, int K,
    int emode, float* __restrict__ out, int ldo,
    const float* __restrict__ bias, const float* __restrict__ resid, int ldr,
    const float* __restrict__ anorm, const float* __restrict__ red,
    unsigned short* __restrict__ outT,
    unsigned short* __restrict__ outBf, const float* __restrict__ rowscale,
    int M, int Nd) {
  __shared__ unsigned short As[2][128][40];
  __shared__ unsigned short Bs[2][128][40];
  const int tid = threadIdx.x, lane = tid & 63, wave = tid >> 6;
  const int quad = lane >> 4, l16 = lane & 15;
  const int wm = (wave >> 1) * 64, wn = (wave & 1) * 64;
  const int bm = blockIdx.x * 128;
  const int srow = tid >> 1, skh = (tid & 1) * 16;
  const int grow = bm + srow;
  const bool rowok = grow < M;
  const bool colok = srow < Nd;
  const int NCH = K >> 5;

  f32x4 acc[4][4];
#pragma unroll
  for (int i = 0; i < 4; ++i)
#pragma unroll
    for (int j = 0; j < 4; ++j)
#pragma unroll
      for (int r = 0; r < 4; ++r) acc[i][j][r] = 0.f;

  float vaA[16], vaB[16];
  bf16x8 bA0, bA1, bB0, bB1;

  auto LOAD = [&](int kc, float (&va)[16], bf16x8& b0, bf16x8& b1) {
    int k0 = kc << 5;
    if (rowok) {
      const float* ap = A + (size_t)grow * lda + k0 + skh;
      float4 v0 = *(const float4*)(ap + 0), v1 = *(const float4*)(ap + 4);
      float4 v2 = *(const float4*)(ap + 8), v3 = *(const float4*)(ap + 12);
      va[0] = v0.x; va[1] = v0.y; va[2] = v0.z; va[3] = v0.w;
      va[4] = v1.x; va[5] = v1.y; va[6] = v1.z; va[7] = v1.w;
      va[8] = v2.x; va[9] = v2.y; va[10] = v2.z; va[11] = v2.w;
      va[12] = v3.x; va[13] = v3.y; va[14] = v3.z; va[15] = v3.w;
      if (Aadd) {
        const float* ap2 = Aadd + (size_t)grow * lda + k0 + skh;
        float4 w0 = *(const float4*)(ap2 + 0), w1 = *(const float4*)(ap2 + 4);
        float4 w2 = *(const float4*)(ap2 + 8), w3 = *(const float4*)(ap2 + 12);
        va[0] += w0.x; va[1] += w0.y; va[2] += w0.z; va[3] += w0.w;
        va[4] += w1.x; va[5] += w1.y; va[6] += w1.z; va[7] += w1.w;
        va[8] += w2.x; va[9] += w2.y; va[10] += w2.z; va[11] += w2.w;
        va[12] += w3.x; va[13] += w3.y; va[14] += w3.z; va[15] += w3.w;
      }
    }
    if (colok) {
      const unsigned short* bp = Bt + (size_t)srow * K + k0 + skh;
      b0 = *(const bf16x8*)(bp);
      b1 = *(const bf16x8*)(bp + 8);
    } else {
#pragma unroll
      for (int z = 0; z < 8; ++z) { b0[z] = 0; b1[z] = 0; }
    }
  };

  auto STORE = [&](int buf, const float (&va)[16], const bf16x8& b0, const bf16x8& b1) {
    bf16x8 p0, p1;
    if (rowok) {
#pragma unroll
      for (int z = 0; z < 8; ++z) { p0[z] = (short)f2bf(va[z]); p1[z] = (short)f2bf(va[z + 8]); }
    } else {
#pragma unroll
      for (int z = 0; z < 8; ++z) { p0[z] = 0; p1[z] = 0; }
    }
    *(bf16x8*)&As[buf][srow][skh] = p0;
    *(bf16x8*)&As[buf][srow][skh + 8] = p1;
    *(bf16x8*)&Bs[buf][srow][skh] = b0;
    *(bf16x8*)&Bs[buf][srow][skh + 8] = b1;
  };

  auto MFMA = [&](int buf) {
    bf16x8 af[4], bfr[4];
#pragma unroll
    for (int i = 0; i < 4; ++i) af[i] = *(const bf16x8*)&As[buf][wm + i * 16 + l16][quad * 8];
#pragma unroll
    for (int j = 0; j < 4; ++j) bfr[j] = *(const bf16x8*)&Bs[buf][wn + j * 16 + l16][quad * 8];
#pragma unroll
    for (int i = 0; i < 4; ++i)
#pragma unroll
      for (int j = 0; j < 4; ++j)
        acc[i][j] = __builtin_amdgcn_mfma_f32_16x16x32_bf16(af[i], bfr[j], acc[i][j], 0, 0, 0);
  };

  LOAD(0, vaA, bA0, bA1);
  if (NCH > 1) LOAD(1, vaB, bB0, bB1);
  STORE(0, vaA, bA0, bA1);
  __syncthreads();

  for (int kc = 0; kc < NCH; kc += 2) {
    if (kc + 2 < NCH) LOAD(kc + 2, vaA, bA0, bA1);
    MFMA(0);
    if (kc + 1 < NCH) STORE(1, vaB, bB0, bB1);
    __syncthreads();
    if (kc + 1 < NCH) {
      if (kc + 3 < NCH) LOAD(kc + 3, vaB, bB0, bB1);
      MFMA(1);
      if (kc + 2 < NCH) STORE(0, vaA, bA0, bA1);
      __syncthreads();
    }
  }

  float s2 = (emode == 3) ? red[2] : 0.f;
#pragma unroll
  for (int j = 0; j < 4; ++j) {
    int col = wn + j * 16 + l16;
    if (col >= Nd) continue;
    float bv = bias ? bias[col] : 0.f;
#pragma unroll
    for (int i = 0; i < 4; ++i) {
      int row0 = bm + wm + i * 16 + quad * 4;
      if (row0 >= M) continue;
      float o[4];
#pragma unroll
      for (int r = 0; r < 4; ++r) {
        float a = acc[i][j][r];
        int row = row0 + r;
        if (emode == 0) o[r] = a + bv;
        else if (emode == 1) o[r] = fmaxf(a + bv, 0.f);
        else if (emode == 3) o[r] = (resid[(size_t)row * ldr + col] + a * s2) / anorm[row];
        else o[r] = 0.5f * a + bv;
        out[(size_t)row * ldo + col] = o[r];
      }
      if (outT) {
        ushort4 pk;
        pk.x = f2bf(o[0]); pk.y = f2bf(o[1]); pk.z = f2bf(o[2]); pk.w = f2bf(o[3]);
        *(ushort4*)&outT[(size_t)col * MP + row0] = pk;
      }
      if (outBf) {
#pragma unroll
        for (int r = 0; r < 4; ++r) {
          float rs = rowscale ? rowscale[row0 + r] : 1.f;
          outBf[(size_t)(row0 + r) * 128 + col] = f2bf(o[r] * rs);
        }
      }
    }
  }
}

// ---------------- fused q/k/v GEMM: one dispatch, 3*MBC blocks ----------------
__global__ __launch_bounds__(256) void mgemm_qkv_kernel(
    const float* __restrict__ A,
    const unsigned short* __restrict__ Btq, const unsigned short* __restrict__ Btk,
    const unsigned short* __restrict__ Btv,
    const float* __restrict__ q_b, const float* __restrict__ k_b,
    const float* __restrict__ v_b,
    float* __restrict__ outq, float* __restrict__ outk, float* __restrict__ outv,
    unsigned short* __restrict__ kT, unsigned short* __restrict__ vT, int M) {
  __shared__ unsigned short As[2][128][40];
  __shared__ unsigned short Bs[2][128][40];
  const int which = blockIdx.x % 3;
  const int bx = blockIdx.x / 3;
  const unsigned short* Bt = (which == 0) ? Btq : (which == 1) ? Btk : Btv;
  const float* bias = (which == 0) ? q_b : (which == 1) ? k_b : v_b;
  float* out = (which == 0) ? outq : (which == 1) ? outk : outv;
  unsigned short* outT = (which == 0) ? nullptr : (which == 1) ? kT : vT;

  const int tid = threadIdx.x, lane = tid & 63, wave = tid >> 6;
  const int quad = lane >> 4, l16 = lane & 15;
  const int wm = (wave >> 1) * 64, wn = (wave & 1) * 64;
  const int bm = bx * 128;
  const int srow = tid >> 1, skh = (tid & 1) * 16;
  const int grow = bm + srow;
  const bool rowok = grow < M;
  const int NCH = 4;  // K = 128

  f32x4 acc[4][4];
#pragma unroll
  for (int i = 0; i < 4; ++i)
#pragma unroll
    for (int j = 0; j < 4; ++j)
#pragma unroll
      for (int r = 0; r < 4; ++r) acc[i][j][r] = 0.f;

  float vaA[16], vaB[16];
  bf16x8 bA0, bA1, bB0, bB1;

  auto LOAD = [&](int kc, float (&va)[16], bf16x8& b0, bf16x8& b1) {
    int k0 = kc << 5;
    if (rowok) {
      const float* ap = A + (size_t)grow * 128 + k0 + skh;
      float4 v0 = *(const float4*)(ap + 0), v1 = *(const float4*)(ap + 4);
      float4 v2 = *(const float4*)(ap + 8), v3 = *(const float4*)(ap + 12);
      va[0] = v0.x; va[1] = v0.y; va[2] = v0.z; va[3] = v0.w;
      va[4] = v1.x; va[5] = v1.y; va[6] = v1.z; va[7] = v1.w;
      va[8] = v2.x; va[9] = v2.y; va[10] = v2.z; va[11] = v2.w;
      va[12] = v3.x; va[13] = v3.y; va[14] = v3.z; va[15] = v3.w;
    }
    const unsigned short* bp = Bt + (size_t)srow * 128 + k0 + skh;
    b0 = *(const bf16x8*)(bp);
    b1 = *(const bf16x8*)(bp + 8);
  };

  auto STORE = [&](int buf, const float (&va)[16], const bf16x8& b0, const bf16x8& b1) {
    bf16x8 p0, p1;
    if (rowok) {
#pragma unroll
      for (int z = 0; z < 8; ++z) { p0[z] = (short)f2bf(va[z]); p1[z] = (short)f2bf(va[z + 8]); }
    } else {
#pragma unroll
      for (int z = 0; z < 8; ++z) { p0[z] = 0; p1[z] = 0; }
    }
    *(bf16x8*)&As[buf][srow][skh] = p0;
    *(bf16x8*)&As[buf][srow][skh + 8] = p1;
    *(bf16x8*)&Bs[buf][srow][skh] = b0;
    *(bf16x8*)&Bs[buf][srow][skh + 8] = b1;
  };

  auto MFMA = [&](int buf) {
    bf16x8 af[4], bfr[4];
#pragma unroll
    for (int i = 0; i < 4; ++i) af[i] = *(const bf16x8*)&As[buf][wm + i * 16 + l16][quad * 8];
#pragma unroll
    for (int j = 0; j < 4; ++j) bfr[j] = *(const bf16x8*)&Bs[buf][wn + j * 16 + l16][quad * 8];
#pragma unroll
    for (int i = 0; i < 4; ++i)
#pragma unroll
      for (int j = 0; j < 4; ++j)
        acc[i][j] = __builtin_amdgcn_mfma_f32_16x16x32_bf16(af[i], bfr[j], acc[i][j], 0, 0, 0);
  };

  LOAD(0, vaA, bA0, bA1);
  LOAD(1, vaB, bB0, bB1);
  STORE(0, vaA, bA0, bA1);
  __syncthreads();

  for (int kc = 0; kc < NCH; kc += 2) {
    if (kc + 2 < NCH) LOAD(kc + 2, vaA, bA0, bA1);
    MFMA(0);
    if (kc + 1 < NCH) STORE(1, vaB, bB0, bB1);
    __syncthreads();
    if (kc + 1 < NCH) {
      if (kc + 3 < NCH) LOAD(kc + 3, vaB, bB0, bB1);
      MFMA(1);
      if (kc + 2 < NCH) STORE(0, vaA, bA0, bA1);
      __syncthreads();
    }
  }

#pragma unroll
  for (int j = 0; j < 4; ++j) {
    int col = wn + j * 16 + l16;
    float bv = bias[col];
#pragma unroll
    for (int i = 0; i < 4; ++i) {
      int row0 = bm + wm + i * 16 + quad * 4;
      if (row0 >= M) continue;
      float o[4];
#pragma unroll
      for (int r = 0; r < 4; ++r) {
        o[r] = acc[i][j][r] + bv;
        out[(size_t)(row0 + r) * 128 + col] = o[r];
      }
      if (outT) {
        ushort4 pk;
        pk.x = f2bf(o[0]); pk.y = f2bf(o[1]); pk.z = f2bf(o[2]); pk.w = f2bf(o[3]);
        *(ushort4*)&outT[(size_t)col * MP + row0] = pk;
      }
    }
  }
}

// ---------------- fused colstats1 + split-K kT@v (independent, one dispatch) ----------------
// blocks [0,SKV): ktv partial GEMM; blocks [SKV, SKV+CSB): colstats1.
__global__ __launch_bounds__(256) void colstats_ktv_kernel(
    const unsigned short* __restrict__ kT, const unsigned short* __restrict__ vT,
    float* __restrict__ part,
    const float* __restrict__ q, const float* __restrict__ k,
    float* __restrict__ partK, float* __restrict__ partS, int n) {
  __shared__ unsigned short As[2][128][40];
  __shared__ unsigned short Bs[2][128][40];
  const int tid = threadIdx.x;

  if (blockIdx.x < SKV) {
    const int lane = tid & 63, wave = tid >> 6;
    const int quad = lane >> 4, l16 = lane & 15;
    const int wm = (wave >> 1) * 64, wn = (wave & 1) * 64;
    const int srow = tid >> 1, skh = (tid & 1) * 16;

    f32x4 acc[4][4];
#pragma unroll
    for (int i = 0; i < 4; ++i)
#pragma unroll
      for (int j = 0; j < 4; ++j)
#pragma unroll
        for (int r = 0; r < 4; ++r) acc[i][j][r] = 0.f;

    const int nb0 = blockIdx.x * (CPB * 32);
    bf16x8 kA0, kA1, vA0, vA1, kB0, kB1, vB0, vB1;

    auto LOAD = [&](int c, bf16x8& k0, bf16x8& k1, bf16x8& v0, bf16x8& v1) {
      int nb = nb0 + c * 32;
      const unsigned short* kp = kT + (size_t)srow * MP + nb + skh;
      k0 = *(const bf16x8*)(kp);
      k1 = *(const bf16x8*)(kp + 8);
      const unsigned short* vp = vT + (size_t)srow * MP + nb + skh;
      v0 = *(const bf16x8*)(vp);
      v1 = *(const bf16x8*)(vp + 8);
    };
    auto STORE = [&](int buf, const bf16x8& k0, const bf16x8& k1, const bf16x8& v0, const bf16x8& v1) {
      *(bf16x8*)&As[buf][srow][skh] = k0;
      *(bf16x8*)&As[buf][srow][skh + 8] = k1;
      *(bf16x8*)&Bs[buf][srow][skh] = v0;
      *(bf16x8*)&Bs[buf][srow][skh + 8] = v1;
    };
    auto MFMA = [&](int buf) {
      bf16x8 af[4], bfr[4];
#pragma unroll
      for (int i = 0; i < 4; ++i) af[i] = *(const bf16x8*)&As[buf][wm + i * 16 + l16][quad * 8];
#pragma unroll
      for (int j = 0; j < 4; ++j) bfr[j] = *(const bf16x8*)&Bs[buf][wn + j * 16 + l16][quad * 8];
#pragma unroll
      for (int i = 0; i < 4; ++i)
#pragma unroll
        for (int j = 0; j < 4; ++j)
          acc[i][j] = __builtin_amdgcn_mfma_f32_16x16x32_bf16(af[i], bfr[j], acc[i][j], 0, 0, 0);
    };

    LOAD(0, kA0, kA1, vA0, vA1);
    LOAD(1, kB0, kB1, vB0, vB1);
    STORE(0, kA0, kA1, vA0, vA1);
    __syncthreads();

    for (int c = 0; c < CPB; c += 2) {
      if (c + 2 < CPB) LOAD(c + 2, kA0, kA1, vA0, vA1);
      MFMA(0);
      if (c + 1 < CPB) STORE(1, kB0, kB1, vB0, vB1);
      __syncthreads();
      if (c + 1 < CPB) {
        if (c + 3 < CPB) LOAD(c + 3, kB0, kB1, vB0, vB1);
        MFMA(1);
        if (c + 2 < CPB) STORE(0, kA0, kA1, vA0, vA1);
        __syncthreads();
      }
    }

    float* pb = part + (size_t)blockIdx.x * 16384;
#pragma unroll
    for (int j = 0; j < 4; ++j) {
      int col = wn + j * 16 + l16;
#pragma unroll
      for (int i = 0; i < 4; ++i) {
        int row0 = wm + i * 16 + quad * 4;
        *(f32x4*)&pb[col * 128 + row0] = acc[i][j];
      }
    }
  } else {
    const int bid = blockIdx.x - SKV;
    float* sks = (float*)&As[0][0][0];   // 256 floats
    float* ssq = sks + 256;              // 256 floats
    float* ssk = ssq + 256;              // 256 floats (3KB total, fits in As)
    int ty = tid >> 7, tx = tid & 127;
    int lo = bid * 128 + ty, hi = min(n, bid * 128 + 128);
    float ks = 0.f, sq = 0.f, sk = 0.f;
    for (int r = lo; r < hi; r += 2) {
      float kv = k[(size_t)r * HH + tx];
      float qv = q[(size_t)r * HH + tx];
      ks += kv; sq += qv * qv; sk += kv * kv;
    }
    sks[ty * 128 + tx] = ks; ssq[tid] = sq; ssk[tid] = sk;
    __syncthreads();
    if (ty == 0) partK[(size_t)bid * 128 + tx] = sks[tx] + sks[128 + tx];
    for (int off = 128; off > 0; off >>= 1) {
      if (tid < off) { ssq[tid] += ssq[tid + off]; ssk[tid] += ssk[tid + off]; }
      __syncthreads();
    }
    if (tid == 0) { partS[bid * 2] = ssq[0]; partS[bid * 2 + 1] = ssk[0]; }
  }
}

__global__ void ktv_reduce_kernel(const float* __restrict__ part,
                                  unsigned short* __restrict__ Btktv) {
  int i = blockIdx.x * blockDim.x + threadIdx.x;
  if (i >= 16384) return;
  float s0 = 0.f, s1 = 0.f, s2 = 0.f, s3 = 0.f;
  int b = 0;
  for (; b + 3 < SKV; b += 4) {
    s0 += part[(size_t)b * 16384 + i];
    s1 += part[(size_t)(b + 1) * 16384 + i];
    s2 += part[(size_t)(b + 2) * 16384 + i];
    s3 += part[(size_t)(b + 3) * 16384 + i];
  }
  for (; b < SKV; ++b) s0 += part[(size_t)b * 16384 + i];
  Btktv[i] = f2bf((s0 + s1) + (s2 + s3));
}

// ---------------- env-weighted MFMA GEMM (conv & ctx) ----------------
__global__ __launch_bounds__(256) void mconv_kernel(
    const float* __restrict__ A1, const float* __restrict__ A2,
    const float* __restrict__ env, const unsigned short* __restrict__ Btc, int Kpe,
    int relu_resid, const float* __restrict__ resid, float* __restrict__ out,
    unsigned short* __restrict__ outBf, const float* __restrict__ rowscale, int M) {
  __shared__ unsigned short As[2][128][40];
  __shared__ unsigned short Bs[2][128][40];
  const int tid = threadIdx.x, lane = tid & 63, wave = tid >> 6;
  const int quad = lane >> 4, l16 = lane & 15;
  const int wm = (wave >> 1) * 64, wn = (wave & 1) * 64;
  const int bm = blockIdx.x * 128;
  const int srow = tid >> 1, skh = (tid & 1) * 16;
  const int grow = bm + srow;
  const bool rowok = grow < M;

  float ev0 = 0.f, ev1 = 0.f, ev2 = 0.f, ev3 = 0.f;
  if (rowok) {
    float4 e4 = *(const float4*)&env[(size_t)grow * 4];
    ev0 = e4.x; ev1 = e4.y; ev2 = e4.z; ev3 = e4.w;
  }

  const int npe = Kpe >> 5;             // K-chunks per env (8 or 4)
  const int NPH = npe << 2;             // total phases

  f32x4 acc[4][4];
#pragma unroll
  for (int i = 0; i < 4; ++i)
#pragma unroll
    for (int j = 0; j < 4; ++j)
#pragma unroll
      for (int r = 0; r < 4; ++r) acc[i][j][r] = 0.f;

  float aC[16], aN[16];
  bf16x8 b0, b1;

  auto LOADA = [&](int kc, float (&dst)[16]) {
    int kof = kc << 5;
    const float* Asrc = A1;
    int ks = kof;
    if (A2 && kof >= 128) { Asrc = A2; ks = kof - 128; }
    if (rowok) {
      const float* ap = Asrc + (size_t)grow * 128 + ks + skh;
      float4 v0 = *(const float4*)(ap + 0), v1 = *(const float4*)(ap + 4);
      float4 v2 = *(const float4*)(ap + 8), v3 = *(const float4*)(ap + 12);
      dst[0] = v0.x; dst[1] = v0.y; dst[2] = v0.z; dst[3] = v0.w;
      dst[4] = v1.x; dst[5] = v1.y; dst[6] = v1.z; dst[7] = v1.w;
      dst[8] = v2.x; dst[9] = v2.y; dst[10] = v2.z; dst[11] = v2.w;
      dst[12] = v3.x; dst[13] = v3.y; dst[14] = v3.z; dst[15] = v3.w;
    }
  };

  auto LOADB = [&](int e, int kc) {
    const unsigned short* bp = Btc + ((size_t)e * 128 + srow) * Kpe + (kc << 5) + skh;
    b0 = *(const bf16x8*)(bp);
    b1 = *(const bf16x8*)(bp + 8);
  };

  auto STORE = [&](int buf, const float (&a)[16], float ev) {
    bf16x8 p0, p1;
    if (rowok) {
#pragma unroll
      for (int z = 0; z < 8; ++z) {
        p0[z] = (short)f2bf(a[z] * ev);
        p1[z] = (short)f2bf(a[z + 8] * ev);
      }
    } else {
#pragma unroll
      for (int z = 0; z < 8; ++z) { p0[z] = 0; p1[z] = 0; }
    }
    *(bf16x8*)&As[buf][srow][skh] = p0;
    *(bf16x8*)&As[buf][srow][skh + 8] = p1;
    *(bf16x8*)&Bs[buf][srow][skh] = b0;
    *(bf16x8*)&Bs[buf][srow][skh + 8] = b1;
  };

  auto MFMA = [&](int buf) {
    bf16x8 af[4], bfr[4];
#pragma unroll
    for (int i = 0; i < 4; ++i) af[i] = *(const bf16x8*)&As[buf][wm + i * 16 + l16][quad * 8];
#pragma unroll
    for (int j = 0; j < 4; ++j) bfr[j] = *(const bf16x8*)&Bs[buf][wn + j * 16 + l16][quad * 8];
#pragma unroll
    for (int i = 0; i < 4; ++i)
#pragma unroll
      for (int j = 0; j < 4; ++j)
        acc[i][j] = __builtin_amdgcn_mfma_f32_16x16x32_bf16(af[i], bfr[j], acc[i][j], 0, 0, 0);
  };

  LOADA(0, aC);
  LOADB(0, 0);
  if (npe > 1) LOADA(1, aN);
  STORE(0, aC, ev0);
  __syncthreads();

  for (int kc = 0; kc < npe; ++kc) {
#pragma unroll
    for (int e = 0; e < 4; ++e) {
      const int p = (kc << 2) + e;
      const int cur = e & 1;
      const bool more = (p + 1) < NPH;
      if (more) {
        LOADB((e + 1) & 3, kc + (e == 3 ? 1 : 0));
      }
      MFMA(cur);
      if (more) {
        if (e == 3) {
#pragma unroll
          for (int z = 0; z < 16; ++z) aC[z] = aN[z];
        }
        float evn = (e == 0) ? ev1 : (e == 1) ? ev2 : (e == 2) ? ev3 : ev0;
        STORE(cur ^ 1, aC, evn);
        if (e == 3 && kc + 2 < npe) LOADA(kc + 2, aN);
      }
      __syncthreads();
    }
  }

#pragma unroll
  for (int j = 0; j < 4; ++j) {
    int col = wn + j * 16 + l16;
#pragma unroll
    for (int i = 0; i < 4; ++i) {
      int row0 = bm + wm + i * 16 + quad * 4;
      if (row0 >= M) continue;
#pragma unroll
      for (int r = 0; r < 4; ++r) {
        int row = row0 + r;
        float a = acc[i][j][r];
        float o = relu_resid ? fmaxf(a + resid[(size_t)row * 128 + col], 0.f) : a;
        out[(size_t)row * 128 + col] = o;
        if (outBf) {
          float rs = rowscale ? rowscale[row] : 1.f;
          outBf[(size_t)row * 128 + col] = f2bf(o * rs);
        }
      }
    }
  }
}

// ---------------- graph kernels ----------------
__global__ void count_kernel(const int* ei, int* deg, int E) {
  int e = blockIdx.x * blockDim.x + threadIdx.x;
  if (e >= E) return;
  atomicAdd(&deg[ei[E + e]], 1);
}

__global__ __launch_bounds__(128) void scan1_kernel(const int* __restrict__ deg,
                                                    int* __restrict__ bsum, int n) {
  __shared__ int sh[128];
  int t = threadIdx.x;
  int i = blockIdx.x * 128 + t;
  sh[t] = (i < n) ? deg[i] : 0;
  __syncthreads();
  for (int off = 64; off > 0; off >>= 1) {
    if (t < off) sh[t] += sh[t + off];
    __syncthreads();
  }
  if (t == 0) bsum[blockIdx.x] = sh[0];
}

__global__ __launch_bounds__(512) void scan2_kernel(const int* __restrict__ bsum,
                                                    int* __restrict__ boff, int nb,
                                                    int* __restrict__ startN) {
  __shared__ int sh[512];
  int t = threadIdx.x;
  int v0 = (t < nb) ? bsum[t] : 0;
  sh[t] = v0;
  __syncthreads();
  for (int off = 1; off < 512; off <<= 1) {
    int v = sh[t];
    int add = (t >= off) ? sh[t - off] : 0;
    __syncthreads();
    sh[t] = v + add;
    __syncthreads();
  }
  if (t < nb) boff[t] = sh[t] - v0;
  if (t == nb - 1) *startN = sh[t];
}

__global__ __launch_bounds__(128) void scan3_kernel(const int* __restrict__ deg,
                                                    const int* __restrict__ boff,
                                                    int* __restrict__ start,
                                                    int* __restrict__ cursor,
                                                    float* __restrict__ inv, int n) {
  __shared__ int sh[128];
  int t = threadIdx.x;
  int i = blockIdx.x * 128 + t;
  int d = (i < n) ? deg[i] : 0;
  sh[t] = d;
  __syncthreads();
  for (int off = 1; off < 128; off <<= 1) {
    int v = sh[t];
    int add = (t >= off) ? sh[t - off] : 0;
    __syncthreads();
    sh[t] = v + add;
    __syncthreads();
  }
  if (i < n) {
    int p = boff[blockIdx.x] + sh[t] - d;
    start[i] = p; cursor[i] = p;
    inv[i] = (d > 0) ? rsqrtf((float)d) : 0.f;
  }
}

__global__ void fill_kernel(const int* ei, int* cursor, int* bucket, int E) {
  int e = blockIdx.x * blockDim.x + threadIdx.x;
  if (e >= E) return;
  int r = ei[e], c = ei[E + e];
  int pos = atomicAdd(&cursor[c], 1);
  bucket[pos] = r;
}

// ---------------- fused gather + env-softmax (per wave: both for one node) ----------------
// Softmax partials (lane-parallel, zero LDS) ride in the latency shadow of the
// gather's dependent bucket->hs load chains.
__global__ __launch_bounds__(256) void gather_env_kernel(
    const unsigned short* __restrict__ hs, const int* __restrict__ start,
    const int* __restrict__ bucket, const float* __restrict__ inv,
    const float* __restrict__ h, const float* __restrict__ w,
    const float* __restrict__ b,
    float* __restrict__ agg, float* __restrict__ env, int n) {
  int node = blockIdx.x * 4 + (threadIdx.x >> 6);
  if (node >= n) return;
  const int lane = threadIdx.x & 63;
  const int half = lane >> 5, l32 = lane & 31;
  const int f4 = l32 * 4;

  // env partials: lane handles feature dims 2*lane, 2*lane+1
  float2 hv = *(const float2*)&h[(size_t)node * 128 + 2 * lane];
  float4 w0 = *(const float4*)&w[(size_t)(2 * lane) * 4];
  float4 w1 = *(const float4*)&w[(size_t)(2 * lane + 1) * 4];
  float p0 = hv.x * w0.x + hv.y * w1.x;
  float p1 = hv.x * w0.y + hv.y * w1.y;
  float p2 = hv.x * w0.z + hv.y * w1.z;
  float p3 = hv.x * w0.w + hv.y * w1.w;

  // gather (two 32-lane halves over even/odd edges, unroll-by-2)
  int s0 = start[node], s1 = start[node + 1];
  float a0 = 0.f, a1 = 0.f, a2 = 0.f, a3 = 0.f;
  int j = s0 + half;
  for (; j + 2 < s1; j += 4) {
    int r0 = bucket[j], r1 = bucket[j + 2];
    uint2 u0 = *(const uint2*)&hs[(size_t)r0 * 128 + f4];
    uint2 u1 = *(const uint2*)&hs[(size_t)r1 * 128 + f4];
    a0 += bfbits2f(u0.x << 16); a1 += bfbits2f(u0.x & 0xFFFF0000u);
    a2 += bfbits2f(u0.y << 16); a3 += bfbits2f(u0.y & 0xFFFF0000u);
    a0 += bfbits2f(u1.x << 16); a1 += bfbits2f(u1.x & 0xFFFF0000u);
    a2 += bfbits2f(u1.y << 16); a3 += bfbits2f(u1.y & 0xFFFF0000u);
  }
  for (; j < s1; j += 2) {
    int r = bucket[j];
    uint2 u = *(const uint2*)&hs[(size_t)r * 128 + f4];
    a0 += bfbits2f(u.x << 16); a1 += bfbits2f(u.x & 0xFFFF0000u);
    a2 += bfbits2f(u.y << 16); a3 += bfbits2f(u.y & 0xFFFF0000u);
  }

  // wave-reduce softmax partials (all 64 lanes)
#pragma unroll
  for (int s = 1; s <= 32; s <<= 1) {
    p0 += __shfl_xor(p0, s);
    p1 += __shfl_xor(p1, s);
    p2 += __shfl_xor(p2, s);
    p3 += __shfl_xor(p3, s);
  }

  a0 += __shfl_xor(a0, 32);
  a1 += __shfl_xor(a1, 32);
  a2 += __shfl_xor(a2, 32);
  a3 += __shfl_xor(a3, 32);
  if (half == 0) {
    float iv = inv[node];
    *(float4*)&agg[(size_t)node * 128 + f4] = make_float4(iv * a0, iv * a1, iv * a2, iv * a3);
  }
  if (lane == 0) {
    float l0 = p0 + b[0], l1 = p1 + b[1], l2 = p2 + b[2], l3 = p3 + b[3];
    float m = fmaxf(fmaxf(l0, l1), fmaxf(l2, l3));
    float e0 = __expf(l0 - m), e1 = __expf(l1 - m), e2 = __expf(l2 - m), e3 = __expf(l3 - m);
    float s = 1.f / (e0 + e1 + e2 + e3);
    *(float4*)&env[(size_t)node * 4] = make_float4(e0 * s, e1 * s, e2 * s, e3 * s);
  }
}

// ---------------- env softmax (standalone, for genv) ----------------
__global__ __launch_bounds__(256) void env_softmax_kernel(const float* __restrict__ h,
                                                          const float* __restrict__ w,
                                                          const float* __restrict__ b,
                                                          float* __restrict__ env, int M) {
  __shared__ float hsd[64][129];
  __shared__ float ws[HH * KK];
  int tid = threadIdx.x;
  int base = blockIdx.x * 64;
  for (int i = tid; i < HH * KK; i += 256) ws[i] = w[i];
  {
    int row = tid >> 2, q4 = (tid & 3) * 32;
    int g = base + row;
    if (g < M) {
      const float* hp = h + (size_t)g * HH + q4;
#pragma unroll
      for (int z = 0; z < 8; ++z) {
        float4 v = *(const float4*)(hp + z * 4);
        hsd[row][q4 + z * 4 + 0] = v.x; hsd[row][q4 + z * 4 + 1] = v.y;
        hsd[row][q4 + z * 4 + 2] = v.z; hsd[row][q4 + z * 4 + 3] = v.w;
      }
    }
  }
  __syncthreads();
  if (tid < 64 && base + tid < M) {
    float l0 = b[0], l1 = b[1], l2 = b[2], l3 = b[3];
    for (int d = 0; d < HH; ++d) {
      float hv = hsd[tid][d];
      l0 += hv * ws[d * 4 + 0]; l1 += hv * ws[d * 4 + 1];
      l2 += hv * ws[d * 4 + 2]; l3 += hv * ws[d * 4 + 3];
    }
    float m = fmaxf(fmaxf(l0, l1), fmaxf(l2, l3));
    float e0 = __expf(l0 - m), e1 = __expf(l1 - m), e2 = __expf(l2 - m), e3 = __expf(l3 - m);
    float s = 1.f / (e0 + e1 + e2 + e3);
    *(float4*)(env + (size_t)(base + tid) * KK) = make_float4(e0 * s, e1 * s, e2 * s, e3 * s);
  }
}

__global__ __launch_bounds__(256) void colstats2_kernel(
    const float* __restrict__ partK, const float* __restrict__ partS,
    float* __restrict__ ksum, float* __restrict__ red) {
  int t = threadIdx.x;
  if (t < 128) {
    float s = 0.f;
    for (int b = 0; b < CSB; ++b) s += partK[(size_t)b * 128 + t];
    ksum[t] = s;
  } else if (t == 128 || t == 129) {
    float s = 0.f;
    for (int b = 0; b < CSB; ++b) s += partS[b * 2 + (t - 128)];
    red[t - 128] = s;
  }
}

__global__ void scale_kernel(float* red, int n) {
  float nq = fmaxf(sqrtf(red[0]), 1e-12f);
  float nk = fmaxf(sqrtf(red[1]), 1e-12f);
  red[2] = 1.f / (nq * nk * (float)n);
}

__global__ __launch_bounds__(256) void anorm_kernel(const float* q, const float* ksum,
                                                    const float* red, float* anorm, int M) {
  __shared__ float ks[HH];
  for (int i = threadIdx.x; i < HH; i += blockDim.x) ks[i] = ksum[i];
  __syncthreads();
  int n = blockIdx.x * blockDim.x + threadIdx.x;
  if (n >= M) return;
  const float* qp = q + (size_t)n * HH;
  float d = 0.f;
  for (int i = 0; i < HH; ++i) d += qp[i] * ks[i];
  float a = 1.f + d * red[2];
  anorm[n] = fmaxf(a, 1e-12f);
}

// ---------------- host launcher ----------------
extern "C" void kernel_launch(void* const* d_in, const int* in_sizes, int n_in,
                              void* d_out, int out_size, void* d_ws, size_t ws_size,
                              hipStream_t stream) {
  const float* x = (const float*)d_in[0];
  const int* ei = (const int*)d_in[1];
  const float* fc0_w = (const float*)d_in[2];
  const float* fc0_b = (const float*)d_in[3];
  const float* fc1_w = (const float*)d_in[4];
  const float* fc1_b = (const float*)d_in[5];
  const float* env_w = (const float*)d_in[6];
  const float* env_b = (const float*)d_in[7];
  const float* conv_w = (const float*)d_in[8];
  const float* q_w = (const float*)d_in[9];
  const float* q_b = (const float*)d_in[10];
  const float* k_w = (const float*)d_in[11];
  const float* k_b = (const float*)d_in[12];
  const float* v_w = (const float*)d_in[13];
  const float* v_b = (const float*)d_in[14];
  const float* envp_w = (const float*)d_in[15];
  const float* envp_b = (const float*)d_in[16];
  const float* genv_w = (const float*)d_in[17];
  const float* gt_w = (const float*)d_in[18];
  const float* gt_b = (const float*)d_in[19];
  float* out = (float*)d_out;

  const size_t NH = (size_t)NN * HH;
  float* W = (float*)d_ws;
  float* hA = W;             // final h
  float* hB = W + NH;        // layer buffer -> k -> ctx
  float* agg = W + 2 * NH;   // agg -> q
  float* vbuf = W + 3 * NH;  // v -> gh
  float* gr = W + 4 * NH;
  float* env = W + 5 * NH;
  float* genv = env + (size_t)NN * KK;
  float* inv = genv + (size_t)NN * KK;
  float* anorm = inv + NN;
  float* ksum = anorm + NN;
  float* red = ksum + HH;
  int* deg = (int*)(red + 4);
  int* start = deg + NN;
  int* cursor = start + NN + 1;
  int* bucket = cursor + NN;
  int* bsum = bucket + EE;          // CSB
  int* boff = bsum + CSB;           // CSB
  unsigned short* wb = (unsigned short*)(((uintptr_t)(boff + CSB) + 15) & ~(uintptr_t)15);
  unsigned short* Btfc0 = wb;                 // 256*128
  unsigned short* Btq = Btfc0 + 32768;
  unsigned short* Btk = Btq + 16384;
  unsigned short* Btv = Btk + 16384;
  unsigned short* Btgt = Btv + 16384;
  unsigned short* Btfc1 = Btgt + 16384;       // 40*128
  unsigned short* Btconv = Btfc1 + 5120;      // 2*4*128*256
  unsigned short* Btgenv = Btconv + 262144;   // 4*128*128
  unsigned short* Btktv = Btgenv + 65536;     // 128*128
  unsigned short* kTbf = Btktv + 16384;       // 128*MP
  unsigned short* vTbf = kTbf + (size_t)HH * MP;
  unsigned short* hsb = vTbf + (size_t)HH * MP;  // NN*128 bf16 (scaled h)
  float* part = (float*)(((uintptr_t)(hsb + NH) + 15) & ~(uintptr_t)15);  // SKV*16384
  float* partK = part + (size_t)SKV * 16384;  // CSB*128
  float* partS = partK + (size_t)CSB * 128;   // CSB*2

  float* q = agg;
  float* kb = hB;
  float* ctx = hB;
  float* gh = vbuf;

  dim3 b256(256);
  const int MB = MBC;  // 391
  const int PREP_TOT = NN + HH * (MP - NN) + 32768 + 4 * 16384 + 5120 + 262144 + 65536;

  // fused prep: deg zero + pad + all weight conversions (one dispatch)
  prep_kernel<<<dim3((PREP_TOT + 255) / 256), b256, 0, stream>>>(
      deg, kTbf, vTbf, fc0_w, Btfc0, q_w, Btq, k_w, Btk, v_w, Btv,
      gt_w, Btgt, fc1_w, Btfc1, conv_w, Btconv, genv_w, Btgenv);

  // CSR build (parallel 3-phase scan)
  count_kernel<<<dim3((EE + 255) / 256), b256, 0, stream>>>(ei, deg, EE);
  scan1_kernel<<<dim3(CSB), dim3(128), 0, stream>>>(deg, bsum, NN);
  scan2_kernel<<<dim3(1), dim3(512), 0, stream>>>(bsum, boff, CSB, start + NN);
  scan3_kernel<<<dim3(CSB), dim3(128), 0, stream>>>(deg, boff, start, cursor, inv, NN);
  fill_kernel<<<dim3((EE + 255) / 256), b256, 0, stream>>>(ei, cursor, bucket, EE);

  // fc0: h = relu(x @ fc0_w + b); also emit hs = bf16(inv*h) for gather
  mgemm_kernel<<<dim3(MB), b256, 0, stream>>>(
      x, nullptr, DD, Btfc0, 256, 1, hA, HH, fc0_b, nullptr, 0, nullptr, nullptr,
      nullptr, hsb, inv, NN, HH);

  // conv layers (gather + env-softmax fused per wave)
  float* hcur = hA;
  float* hnext = hB;
  for (int l = 0; l < 2; ++l) {
    gather_env_kernel<<<dim3(NN / 4), b256, 0, stream>>>(
        hsb, start, bucket, inv, hcur, env_w + (size_t)l * HH * KK,
        env_b + (size_t)l * KK, agg, env, NN);
    mconv_kernel<<<dim3(MB), b256, 0, stream>>>(
        agg, hcur, env, Btconv + (size_t)l * 131072, 256, 1, hcur, hnext,
        (l == 0) ? hsb : nullptr, inv, NN);
    float* t = hcur; hcur = hnext; hnext = t;
  }
  // hcur == hA

  // fused q/k/v: one dispatch, 3*MB blocks (k/v also emit transposed bf16)
  mgemm_qkv_kernel<<<dim3(3 * MB), b256, 0, stream>>>(
      hcur, Btq, Btk, Btv, q_b, k_b, v_b, q, kb, vbuf, kTbf, vTbf, NN);

  // fused colstats1 + ktv split-K (independent work, one dispatch)
  colstats_ktv_kernel<<<dim3(SKV + CSB), b256, 0, stream>>>(
      kTbf, vTbf, part, q, kb, partK, partS, NN);
  colstats2_kernel<<<dim3(1), b256, 0, stream>>>(partK, partS, ksum, red);
  ktv_reduce_kernel<<<dim3(64), b256, 0, stream>>>(part, Btktv);
  scale_kernel<<<dim3(1), dim3(1), 0, stream>>>(red, NN);
  anorm_kernel<<<dim3((NN + 255) / 256), b256, 0, stream>>>(q, ksum, red, anorm, NN);

  // gr = (v + q @ ktv * red[2]) / anorm
  mgemm_kernel<<<dim3(MB), b256, 0, stream>>>(
      q, nullptr, HH, Btktv, 128, 3, gr, HH, nullptr, vbuf, HH, anorm, red,
      nullptr, nullptr, nullptr, NN, HH);

  // genv = softmax(gr @ envp_w + envp_b)
  env_softmax_kernel<<<dim3((NN + 63) / 64), b256, 0, stream>>>(gr, envp_w, envp_b, genv, NN);

  // ctx = sum_k genv[:,k] * (gr @ genv_w[k])
  mconv_kernel<<<dim3(MB), b256, 0, stream>>>(
      gr, nullptr, genv, Btgenv, 128, 0, nullptr, ctx, nullptr, nullptr, NN);

  // gh = relu(ctx @ gt_w + gt_b)
  mgemm_kernel<<<dim3(MB), b256, 0, stream>>>(
      ctx, nullptr, HH, Btgt, 128, 1, gh, HH, gt_b, nullptr, 0, nullptr, nullptr,
      nullptr, nullptr, nullptr, NN, HH);

  // out = 0.5*((h+gh) @ fc1_w) + fc1_b
  mgemm_kernel<<<dim3(MB), b256, 0, stream>>>(
      hcur, gh, HH, Btfc1, 128, 5, out, CC, fc1_b, nullptr, 0, nullptr, nullptr,
      nullptr, nullptr, nullptr, NN, CC);
}

// Round 13
// 612.729 us; speedup vs baseline: 6.1305x; 1.0727x over previous
//
#include <hip/hip_runtime.h>

#define DEV __device__ __forceinline__

static constexpr int NN = 50000;   // nodes
static constexpr int DD = 256;     // input dim
static constexpr int HH = 128;     // hidden
static constexpr int CC = 40;      // classes
static constexpr int KK = 4;       // envs
static constexpr int EE = 800000;  // edges
static constexpr int MP = 50176;   // padded node count (196*256, mult of 32)
static constexpr int SKV = 196;    // split-K blocks for ktv
static constexpr int CPB = 8;      // 32-node chunks per ktv block
static constexpr int CSB = 391;    // colstats / scan blocks (ceil(NN/128))
static constexpr int MBC = 391;    // row-tile blocks (ceil(NN/128))
static constexpr int FILLB = (EE + 255) / 256;  // 3125

typedef __attribute__((ext_vector_type(8))) short bf16x8;
typedef __attribute__((ext_vector_type(4))) float f32x4;

DEV unsigned short f2bf(float f) {
  union { float f; unsigned int i; } c; c.f = f;
  unsigned int x = c.i;
  x += 0x7FFFu + ((x >> 16) & 1u);   // round-to-nearest-even
  return (unsigned short)(x >> 16);
}
DEV float bfbits2f(unsigned int hi16bits) {
  union { unsigned int i; float f; } c; c.i = hi16bits; return c.f;
}

// harness-named kernel (unused in pipeline)
__global__ void MLEI_12970801234193_kernel(float* out, int n) {
  int i = blockIdx.x * blockDim.x + threadIdx.x;
  if (i < n) out[i] = 7.0f;
}

// one tcvt element: dst[m][n][k] = bf16(src[m][k][n]) for K x N matrices
DEV void tc(const float* __restrict__ src, unsigned short* __restrict__ dst,
            int i, int K, int N) {
  int m = i / (K * N);
  int rem = i - m * K * N;
  int k = rem / N;
  int n = rem - k * N;
  dst[(size_t)m * K * N + (size_t)n * K + k] = f2bf(src[i]);
}

// ---------------- fused prep: deg zero + kT/vT pad + ALL weight tcvt ----------------
__global__ __launch_bounds__(256) void prep_kernel(
    int* __restrict__ deg, unsigned short* __restrict__ kT, unsigned short* __restrict__ vT,
    const float* __restrict__ fc0_w, unsigned short* __restrict__ Btfc0,
    const float* __restrict__ q_w, unsigned short* __restrict__ Btq,
    const float* __restrict__ k_w, unsigned short* __restrict__ Btk,
    const float* __restrict__ v_w, unsigned short* __restrict__ Btv,
    const float* __restrict__ gt_w, unsigned short* __restrict__ Btgt,
    const float* __restrict__ fc1_w, unsigned short* __restrict__ Btfc1,
    const float* __restrict__ conv_w, unsigned short* __restrict__ Btconv,
    const float* __restrict__ genv_w, unsigned short* __restrict__ Btgenv) {
  int i = blockIdx.x * 256 + threadIdx.x;
  if (i < NN) { deg[i] = 0; return; }
  i -= NN;
  const int PW = MP - NN;  // 176
  if (i < HH * PW) {
    int f = i / PW, c = i - f * PW;
    kT[(size_t)f * MP + NN + c] = 0;
    vT[(size_t)f * MP + NN + c] = 0;
    return;
  }
  i -= HH * PW;
  if (i < 32768) { tc(fc0_w, Btfc0, i, 256, 128); return; }
  i -= 32768;
  if (i < 16384) { tc(q_w, Btq, i, 128, 128); return; }
  i -= 16384;
  if (i < 16384) { tc(k_w, Btk, i, 128, 128); return; }
  i -= 16384;
  if (i < 16384) { tc(v_w, Btv, i, 128, 128); return; }
  i -= 16384;
  if (i < 16384) { tc(gt_w, Btgt, i, 128, 128); return; }
  i -= 16384;
  if (i < 5120) { tc(fc1_w, Btfc1, i, 128, 40); return; }
  i -= 5120;
  if (i < 262144) { tc(conv_w, Btconv, i, 256, 128); return; }
  i -= 262144;
  if (i < 65536) { tc(genv_w, Btgenv, i, 128, 128); }
}

// ---------------- generic bf16-MFMA GEMM body (2-deep prefetch, 1 barrier/chunk) ----------------
DEV void mgemm_body(
    const float* __restrict__ A, const float* __restrict__ Aadd, int lda,
    const unsigned short* __restrict__ Bt, int K,
    int emode, float* __restrict__ out, int ldo,
    const float* __restrict__ bias, const float* __restrict__ resid, int ldr,
    const float* __restrict__ anorm, const float* __restrict__ red,
    unsigned short* __restrict__ outT,
    unsigned short* __restrict__ outBf, const float* __restrict__ rowscale,
    int M, int Nd, int bx) {
  __shared__ unsigned short As[2][128][40];
  __shared__ unsigned short Bs[2][128][40];
  const int tid = threadIdx.x, lane = tid & 63, wave = tid >> 6;
  const int quad = lane >> 4, l16 = lane & 15;
  const int wm = (wave >> 1) * 64, wn = (wave & 1) * 64;
  const int bm = bx * 128;
  const int srow = tid >> 1, skh = (tid & 1) * 16;
  const int grow = bm + srow;
  const bool rowok = grow < M;
  const bool colok = srow < Nd;
  const int NCH = K >> 5;

  f32x4 acc[4][4];
#pragma unroll
  for (int i = 0; i < 4; ++i)
#pragma unroll
    for (int j = 0; j < 4; ++j)
#pragma unroll
      for (int r = 0; r < 4; ++r) acc[i][j][r] = 0.f;

  float vaA[16], vaB[16];
  bf16x8 bA0, bA1, bB0, bB1;

  auto LOAD = [&](int kc, float (&va)[16], bf16x8& b0, bf16x8& b1) {
    int k0 = kc << 5;
    if (rowok) {
      const float* ap = A + (size_t)grow * lda + k0 + skh;
      float4 v0 = *(const float4*)(ap + 0), v1 = *(const float4*)(ap + 4);
      float4 v2 = *(const float4*)(ap + 8), v3 = *(const float4*)(ap + 12);
      va[0] = v0.x; va[1] = v0.y; va[2] = v0.z; va[3] = v0.w;
      va[4] = v1.x; va[5] = v1.y; va[6] = v1.z; va[7] = v1.w;
      va[8] = v2.x; va[9] = v2.y; va[10] = v2.z; va[11] = v2.w;
      va[12] = v3.x; va[13] = v3.y; va[14] = v3.z; va[15] = v3.w;
      if (Aadd) {
        const float* ap2 = Aadd + (size_t)grow * lda + k0 + skh;
        float4 w0 = *(const float4*)(ap2 + 0), w1 = *(const float4*)(ap2 + 4);
        float4 w2 = *(const float4*)(ap2 + 8), w3 = *(const float4*)(ap2 + 12);
        va[0] += w0.x; va[1] += w0.y; va[2] += w0.z; va[3] += w0.w;
        va[4] += w1.x; va[5] += w1.y; va[6] += w1.z; va[7] += w1.w;
        va[8] += w2.x; va[9] += w2.y; va[10] += w2.z; va[11] += w2.w;
        va[12] += w3.x; va[13] += w3.y; va[14] += w3.z; va[15] += w3.w;
      }
    }
    if (colok) {
      const unsigned short* bp = Bt + (size_t)srow * K + k0 + skh;
      b0 = *(const bf16x8*)(bp);
      b1 = *(const bf16x8*)(bp + 8);
    } else {
#pragma unroll
      for (int z = 0; z < 8; ++z) { b0[z] = 0; b1[z] = 0; }
    }
  };

  auto STORE = [&](int buf, const float (&va)[16], const bf16x8& b0, const bf16x8& b1) {
    bf16x8 p0, p1;
    if (rowok) {
#pragma unroll
      for (int z = 0; z < 8; ++z) { p0[z] = (short)f2bf(va[z]); p1[z] = (short)f2bf(va[z + 8]); }
    } else {
#pragma unroll
      for (int z = 0; z < 8; ++z) { p0[z] = 0; p1[z] = 0; }
    }
    *(bf16x8*)&As[buf][srow][skh] = p0;
    *(bf16x8*)&As[buf][srow][skh + 8] = p1;
    *(bf16x8*)&Bs[buf][srow][skh] = b0;
    *(bf16x8*)&Bs[buf][srow][skh + 8] = b1;
  };

  auto MFMA = [&](int buf) {
    bf16x8 af[4], bfr[4];
#pragma unroll
    for (int i = 0; i < 4; ++i) af[i] = *(const bf16x8*)&As[buf][wm + i * 16 + l16][quad * 8];
#pragma unroll
    for (int j = 0; j < 4; ++j) bfr[j] = *(const bf16x8*)&Bs[buf][wn + j * 16 + l16][quad * 8];
#pragma unroll
    for (int i = 0; i < 4; ++i)
#pragma unroll
      for (int j = 0; j < 4; ++j)
        acc[i][j] = __builtin_amdgcn_mfma_f32_16x16x32_bf16(af[i], bfr[j], acc[i][j], 0, 0, 0);
  };

  LOAD(0, vaA, bA0, bA1);
  if (NCH > 1) LOAD(1, vaB, bB0, bB1);
  STORE(0, vaA, bA0, bA1);
  __syncthreads();

  for (int kc = 0; kc < NCH; kc += 2) {
    if (kc + 2 < NCH) LOAD(kc + 2, vaA, bA0, bA1);
    MFMA(0);
    if (kc + 1 < NCH) STORE(1, vaB, bB0, bB1);
    __syncthreads();
    if (kc + 1 < NCH) {
      if (kc + 3 < NCH) LOAD(kc + 3, vaB, bB0, bB1);
      MFMA(1);
      if (kc + 2 < NCH) STORE(0, vaA, bA0, bA1);
      __syncthreads();
    }
  }

  float s2 = 0.f;
  if (emode == 3) {
    float nq = fmaxf(sqrtf(red[0]), 1e-12f);
    float nk = fmaxf(sqrtf(red[1]), 1e-12f);
    s2 = 1.f / (nq * nk * (float)M);
  }
#pragma unroll
  for (int j = 0; j < 4; ++j) {
    int col = wn + j * 16 + l16;
    if (col >= Nd) continue;
    float bv = bias ? bias[col] : 0.f;
#pragma unroll
    for (int i = 0; i < 4; ++i) {
      int row0 = bm + wm + i * 16 + quad * 4;
      if (row0 >= M) continue;
      float o[4];
#pragma unroll
      for (int r = 0; r < 4; ++r) {
        float a = acc[i][j][r];
        int row = row0 + r;
        if (emode == 0) o[r] = a + bv;
        else if (emode == 1) o[r] = fmaxf(a + bv, 0.f);
        else if (emode == 3) o[r] = (resid[(size_t)row * ldr + col] + a * s2) / anorm[row];
        else o[r] = 0.5f * a + bv;
        out[(size_t)row * ldo + col] = o[r];
      }
      if (outT) {
        ushort4 pk;
        pk.x = f2bf(o[0]); pk.y = f2bf(o[1]); pk.z = f2bf(o[2]); pk.w = f2bf(o[3]);
        *(ushort4*)&outT[(size_t)col * MP + row0] = pk;
      }
      if (outBf) {
#pragma unroll
        for (int r = 0; r < 4; ++r) {
          float rs = rowscale ? rowscale[row0 + r] : 1.f;
          outBf[(size_t)(row0 + r) * 128 + col] = f2bf(o[r] * rs);
        }
      }
    }
  }
}

__global__ __launch_bounds__(256) void mgemm_kernel(
    const float* __restrict__ A, const float* __restrict__ Aadd, int lda,
    const unsigned short* __restrict__ Bt, int K,
    int emode, float* __restrict__ out, int ldo,
    const float* __restrict__ bias, const float* __restrict__ resid, int ldr,
    const float* __restrict__ anorm, const float* __restrict__ red,
    unsigned short* __restrict__ outT,
    unsigned short* __restrict__ outBf, const float* __restrict__ rowscale,
    int M, int Nd) {
  mgemm_body(A, Aadd, lda, Bt, K, emode, out, ldo, bias, resid, ldr, anorm, red,
             outT, outBf, rowscale, M, Nd, blockIdx.x);
}

// ---------------- fused fc0 GEMM + CSR fill (independent work, one dispatch) ----------------
// blocks [0,MBC): fc0 (h = relu(x@fc0_w+b), emits hsb); blocks [MBC, MBC+FILLB): fill.
__global__ __launch_bounds__(256) void fc0_fill_kernel(
    const float* __restrict__ x, const unsigned short* __restrict__ Btfc0,
    const float* __restrict__ fc0_b, float* __restrict__ hA,
    unsigned short* __restrict__ hsb, const float* __restrict__ inv,
    const int* __restrict__ ei, int* __restrict__ cursor, int* __restrict__ bucket) {
  if (blockIdx.x < MBC) {
    mgemm_body(x, nullptr, DD, Btfc0, 256, 1, hA, HH, fc0_b, nullptr, 0, nullptr,
               nullptr, nullptr, hsb, inv, NN, HH, blockIdx.x);
  } else {
    int e = (blockIdx.x - MBC) * 256 + threadIdx.x;
    if (e >= EE) return;
    int r = ei[e], c = ei[EE + e];
    int pos = atomicAdd(&cursor[c], 1);
    bucket[pos] = r;
  }
}

// ---------------- fused q/k/v GEMM: one dispatch, 3*MBC blocks ----------------
__global__ __launch_bounds__(256) void mgemm_qkv_kernel(
    const float* __restrict__ A,
    const unsigned short* __restrict__ Btq, const unsigned short* __restrict__ Btk,
    const unsigned short* __restrict__ Btv,
    const float* __restrict__ q_b, const float* __restrict__ k_b,
    const float* __restrict__ v_b,
    float* __restrict__ outq, float* __restrict__ outk, float* __restrict__ outv,
    unsigned short* __restrict__ kT, unsigned short* __restrict__ vT, int M) {
  __shared__ unsigned short As[2][128][40];
  __shared__ unsigned short Bs[2][128][40];
  const int which = blockIdx.x % 3;
  const int bx = blockIdx.x / 3;
  const unsigned short* Bt = (which == 0) ? Btq : (which == 1) ? Btk : Btv;
  const float* bias = (which == 0) ? q_b : (which == 1) ? k_b : v_b;
  float* out = (which == 0) ? outq : (which == 1) ? outk : outv;
  unsigned short* outT = (which == 0) ? nullptr : (which == 1) ? kT : vT;

  const int tid = threadIdx.x, lane = tid & 63, wave = tid >> 6;
  const int quad = lane >> 4, l16 = lane & 15;
  const int wm = (wave >> 1) * 64, wn = (wave & 1) * 64;
  const int bm = bx * 128;
  const int srow = tid >> 1, skh = (tid & 1) * 16;
  const int grow = bm + srow;
  const bool rowok = grow < M;
  const int NCH = 4;  // K = 128

  f32x4 acc[4][4];
#pragma unroll
  for (int i = 0; i < 4; ++i)
#pragma unroll
    for (int j = 0; j < 4; ++j)
#pragma unroll
      for (int r = 0; r < 4; ++r) acc[i][j][r] = 0.f;

  float vaA[16], vaB[16];
  bf16x8 bA0, bA1, bB0, bB1;

  auto LOAD = [&](int kc, float (&va)[16], bf16x8& b0, bf16x8& b1) {
    int k0 = kc << 5;
    if (rowok) {
      const float* ap = A + (size_t)grow * 128 + k0 + skh;
      float4 v0 = *(const float4*)(ap + 0), v1 = *(const float4*)(ap + 4);
      float4 v2 = *(const float4*)(ap + 8), v3 = *(const float4*)(ap + 12);
      va[0] = v0.x; va[1] = v0.y; va[2] = v0.z; va[3] = v0.w;
      va[4] = v1.x; va[5] = v1.y; va[6] = v1.z; va[7] = v1.w;
      va[8] = v2.x; va[9] = v2.y; va[10] = v2.z; va[11] = v2.w;
      va[12] = v3.x; va[13] = v3.y; va[14] = v3.z; va[15] = v3.w;
    }
    const unsigned short* bp = Bt + (size_t)srow * 128 + k0 + skh;
    b0 = *(const bf16x8*)(bp);
    b1 = *(const bf16x8*)(bp + 8);
  };

  auto STORE = [&](int buf, const float (&va)[16], const bf16x8& b0, const bf16x8& b1) {
    bf16x8 p0, p1;
    if (rowok) {
#pragma unroll
      for (int z = 0; z < 8; ++z) { p0[z] = (short)f2bf(va[z]); p1[z] = (short)f2bf(va[z + 8]); }
    } else {
#pragma unroll
      for (int z = 0; z < 8; ++z) { p0[z] = 0; p1[z] = 0; }
    }
    *(bf16x8*)&As[buf][srow][skh] = p0;
    *(bf16x8*)&As[buf][srow][skh + 8] = p1;
    *(bf16x8*)&Bs[buf][srow][skh] = b0;
    *(bf16x8*)&Bs[buf][srow][skh + 8] = b1;
  };

  auto MFMA = [&](int buf) {
    bf16x8 af[4], bfr[4];
#pragma unroll
    for (int i = 0; i < 4; ++i) af[i] = *(const bf16x8*)&As[buf][wm + i * 16 + l16][quad * 8];
#pragma unroll
    for (int j = 0; j < 4; ++j) bfr[j] = *(const bf16x8*)&Bs[buf][wn + j * 16 + l16][quad * 8];
#pragma unroll
    for (int i = 0; i < 4; ++i)
#pragma unroll
      for (int j = 0; j < 4; ++j)
        acc[i][j] = __builtin_amdgcn_mfma_f32_16x16x32_bf16(af[i], bfr[j], acc[i][j], 0, 0, 0);
  };

  LOAD(0, vaA, bA0, bA1);
  LOAD(1, vaB, bB0, bB1);
  STORE(0, vaA, bA0, bA1);
  __syncthreads();

  for (int kc = 0; kc < NCH; kc += 2) {
    if (kc + 2 < NCH) LOAD(kc + 2, vaA, bA0, bA1);
    MFMA(0);
    if (kc + 1 < NCH) STORE(1, vaB, bB0, bB1);
    __syncthreads();
    if (kc + 1 < NCH) {
      if (kc + 3 < NCH) LOAD(kc + 3, vaB, bB0, bB1);
      MFMA(1);
      if (kc + 2 < NCH) STORE(0, vaA, bA0, bA1);
      __syncthreads();
    }
  }

#pragma unroll
  for (int j = 0; j < 4; ++j) {
    int col = wn + j * 16 + l16;
    float bv = bias[col];
#pragma unroll
    for (int i = 0; i < 4; ++i) {
      int row0 = bm + wm + i * 16 + quad * 4;
      if (row0 >= M) continue;
      float o[4];
#pragma unroll
      for (int r = 0; r < 4; ++r) {
        o[r] = acc[i][j][r] + bv;
        out[(size_t)(row0 + r) * 128 + col] = o[r];
      }
      if (outT) {
        ushort4 pk;
        pk.x = f2bf(o[0]); pk.y = f2bf(o[1]); pk.z = f2bf(o[2]); pk.w = f2bf(o[3]);
        *(ushort4*)&outT[(size_t)col * MP + row0] = pk;
      }
    }
  }
}

// ---------------- fused colstats1 + split-K kT@v (independent, one dispatch) ----------------
__global__ __launch_bounds__(256) void colstats_ktv_kernel(
    const unsigned short* __restrict__ kT, const unsigned short* __restrict__ vT,
    float* __restrict__ part,
    const float* __restrict__ q, const float* __restrict__ k,
    float* __restrict__ partK, float* __restrict__ partS, int n) {
  __shared__ unsigned short As[2][128][40];
  __shared__ unsigned short Bs[2][128][40];
  const int tid = threadIdx.x;

  if (blockIdx.x < SKV) {
    const int lane = tid & 63, wave = tid >> 6;
    const int quad = lane >> 4, l16 = lane & 15;
    const int wm = (wave >> 1) * 64, wn = (wave & 1) * 64;
    const int srow = tid >> 1, skh = (tid & 1) * 16;

    f32x4 acc[4][4];
#pragma unroll
    for (int i = 0; i < 4; ++i)
#pragma unroll
      for (int j = 0; j < 4; ++j)
#pragma unroll
        for (int r = 0; r < 4; ++r) acc[i][j][r] = 0.f;

    const int nb0 = blockIdx.x * (CPB * 32);
    bf16x8 kA0, kA1, vA0, vA1, kB0, kB1, vB0, vB1;

    auto LOAD = [&](int c, bf16x8& k0, bf16x8& k1, bf16x8& v0, bf16x8& v1) {
      int nb = nb0 + c * 32;
      const unsigned short* kp = kT + (size_t)srow * MP + nb + skh;
      k0 = *(const bf16x8*)(kp);
      k1 = *(const bf16x8*)(kp + 8);
      const unsigned short* vp = vT + (size_t)srow * MP + nb + skh;
      v0 = *(const bf16x8*)(vp);
      v1 = *(const bf16x8*)(vp + 8);
    };
    auto STORE = [&](int buf, const bf16x8& k0, const bf16x8& k1, const bf16x8& v0, const bf16x8& v1) {
      *(bf16x8*)&As[buf][srow][skh] = k0;
      *(bf16x8*)&As[buf][srow][skh + 8] = k1;
      *(bf16x8*)&Bs[buf][srow][skh] = v0;
      *(bf16x8*)&Bs[buf][srow][skh + 8] = v1;
    };
    auto MFMA = [&](int buf) {
      bf16x8 af[4], bfr[4];
#pragma unroll
      for (int i = 0; i < 4; ++i) af[i] = *(const bf16x8*)&As[buf][wm + i * 16 + l16][quad * 8];
#pragma unroll
      for (int j = 0; j < 4; ++j) bfr[j] = *(const bf16x8*)&Bs[buf][wn + j * 16 + l16][quad * 8];
#pragma unroll
      for (int i = 0; i < 4; ++i)
#pragma unroll
        for (int j = 0; j < 4; ++j)
          acc[i][j] = __builtin_amdgcn_mfma_f32_16x16x32_bf16(af[i], bfr[j], acc[i][j], 0, 0, 0);
    };

    LOAD(0, kA0, kA1, vA0, vA1);
    LOAD(1, kB0, kB1, vB0, vB1);
    STORE(0, kA0, kA1, vA0, vA1);
    __syncthreads();

    for (int c = 0; c < CPB; c += 2) {
      if (c + 2 < CPB) LOAD(c + 2, kA0, kA1, vA0, vA1);
      MFMA(0);
      if (c + 1 < CPB) STORE(1, kB0, kB1, vB0, vB1);
      __syncthreads();
      if (c + 1 < CPB) {
        if (c + 3 < CPB) LOAD(c + 3, kB0, kB1, vB0, vB1);
        MFMA(1);
        if (c + 2 < CPB) STORE(0, kA0, kA1, vA0, vA1);
        __syncthreads();
      }
    }

    float* pb = part + (size_t)blockIdx.x * 16384;
#pragma unroll
    for (int j = 0; j < 4; ++j) {
      int col = wn + j * 16 + l16;
#pragma unroll
      for (int i = 0; i < 4; ++i) {
        int row0 = wm + i * 16 + quad * 4;
        *(f32x4*)&pb[col * 128 + row0] = acc[i][j];
      }
    }
  } else {
    const int bid = blockIdx.x - SKV;
    float* sks = (float*)&As[0][0][0];   // 256 floats
    float* ssq = sks + 256;              // 256 floats
    float* ssk = ssq + 256;              // 256 floats (3KB total, fits in As)
    int ty = tid >> 7, tx = tid & 127;
    int lo = bid * 128 + ty, hi = min(n, bid * 128 + 128);
    float ks = 0.f, sq = 0.f, sk = 0.f;
    for (int r = lo; r < hi; r += 2) {
      float kv = k[(size_t)r * HH + tx];
      float qv = q[(size_t)r * HH + tx];
      ks += kv; sq += qv * qv; sk += kv * kv;
    }
    sks[ty * 128 + tx] = ks; ssq[tid] = sq; ssk[tid] = sk;
    __syncthreads();
    if (ty == 0) partK[(size_t)bid * 128 + tx] = sks[tx] + sks[128 + tx];
    for (int off = 128; off > 0; off >>= 1) {
      if (tid < off) { ssq[tid] += ssq[tid + off]; ssk[tid] += ssk[tid + off]; }
      __syncthreads();
    }
    if (tid == 0) { partS[bid * 2] = ssq[0]; partS[bid * 2 + 1] = ssk[0]; }
  }
}

// ---------------- fused colstats2 + ktv reduce (independent, one dispatch) ----------------
// block 0: colstats2; blocks 1..64: ktv partial reduce -> Btktv bf16.
__global__ __launch_bounds__(256) void reduce2_kernel(
    const float* __restrict__ partK, const float* __restrict__ partS,
    float* __restrict__ ksum, float* __restrict__ red,
    const float* __restrict__ part, unsigned short* __restrict__ Btktv) {
  int t = threadIdx.x;
  if (blockIdx.x == 0) {
    if (t < 128) {
      float s = 0.f;
      for (int b = 0; b < CSB; ++b) s += partK[(size_t)b * 128 + t];
      ksum[t] = s;
    } else if (t == 128 || t == 129) {
      float s = 0.f;
      for (int b = 0; b < CSB; ++b) s += partS[b * 2 + (t - 128)];
      red[t - 128] = s;
    }
  } else {
    int i = (blockIdx.x - 1) * 256 + t;
    float s0 = 0.f, s1 = 0.f, s2 = 0.f, s3 = 0.f;
    int b = 0;
    for (; b + 3 < SKV; b += 4) {
      s0 += part[(size_t)b * 16384 + i];
      s1 += part[(size_t)(b + 1) * 16384 + i];
      s2 += part[(size_t)(b + 2) * 16384 + i];
      s3 += part[(size_t)(b + 3) * 16384 + i];
    }
    for (; b < SKV; ++b) s0 += part[(size_t)b * 16384 + i];
    Btktv[i] = f2bf((s0 + s1) + (s2 + s3));
  }
}

// ---------------- env-weighted MFMA GEMM (conv & ctx) ----------------
__global__ __launch_bounds__(256) void mconv_kernel(
    const float* __restrict__ A1, const float* __restrict__ A2,
    const float* __restrict__ env, const unsigned short* __restrict__ Btc, int Kpe,
    int relu_resid, const float* __restrict__ resid, float* __restrict__ out,
    unsigned short* __restrict__ outBf, const float* __restrict__ rowscale, int M) {
  __shared__ unsigned short As[2][128][40];
  __shared__ unsigned short Bs[2][128][40];
  const int tid = threadIdx.x, lane = tid & 63, wave = tid >> 6;
  const int quad = lane >> 4, l16 = lane & 15;
  const int wm = (wave >> 1) * 64, wn = (wave & 1) * 64;
  const int bm = blockIdx.x * 128;
  const int srow = tid >> 1, skh = (tid & 1) * 16;
  const int grow = bm + srow;
  const bool rowok = grow < M;

  float ev0 = 0.f, ev1 = 0.f, ev2 = 0.f, ev3 = 0.f;
  if (rowok) {
    float4 e4 = *(const float4*)&env[(size_t)grow * 4];
    ev0 = e4.x; ev1 = e4.y; ev2 = e4.z; ev3 = e4.w;
  }

  const int npe = Kpe >> 5;             // K-chunks per env (8 or 4)
  const int NPH = npe << 2;             // total phases

  f32x4 acc[4][4];
#pragma unroll
  for (int i = 0; i < 4; ++i)
#pragma unroll
    for (int j = 0; j < 4; ++j)
#pragma unroll
      for (int r = 0; r < 4; ++r) acc[i][j][r] = 0.f;

  float aC[16], aN[16];
  bf16x8 b0, b1;

  auto LOADA = [&](int kc, float (&dst)[16]) {
    int kof = kc << 5;
    const float* Asrc = A1;
    int ks = kof;
    if (A2 && kof >= 128) { Asrc = A2; ks = kof - 128; }
    if (rowok) {
      const float* ap = Asrc + (size_t)grow * 128 + ks + skh;
      float4 v0 = *(const float4*)(ap + 0), v1 = *(const float4*)(ap + 4);
      float4 v2 = *(const float4*)(ap + 8), v3 = *(const float4*)(ap + 12);
      dst[0] = v0.x; dst[1] = v0.y; dst[2] = v0.z; dst[3] = v0.w;
      dst[4] = v1.x; dst[5] = v1.y; dst[6] = v1.z; dst[7] = v1.w;
      dst[8] = v2.x; dst[9] = v2.y; dst[10] = v2.z; dst[11] = v2.w;
      dst[12] = v3.x; dst[13] = v3.y; dst[14] = v3.z; dst[15] = v3.w;
    }
  };

  auto LOADB = [&](int e, int kc) {
    const unsigned short* bp = Btc + ((size_t)e * 128 + srow) * Kpe + (kc << 5) + skh;
    b0 = *(const bf16x8*)(bp);
    b1 = *(const bf16x8*)(bp + 8);
  };

  auto STORE = [&](int buf, const float (&a)[16], float ev) {
    bf16x8 p0, p1;
    if (rowok) {
#pragma unroll
      for (int z = 0; z < 8; ++z) {
        p0[z] = (short)f2bf(a[z] * ev);
        p1[z] = (short)f2bf(a[z + 8] * ev);
      }
    } else {
#pragma unroll
      for (int z = 0; z < 8; ++z) { p0[z] = 0; p1[z] = 0; }
    }
    *(bf16x8*)&As[buf][srow][skh] = p0;
    *(bf16x8*)&As[buf][srow][skh + 8] = p1;
    *(bf16x8*)&Bs[buf][srow][skh] = b0;
    *(bf16x8*)&Bs[buf][srow][skh + 8] = b1;
  };

  auto MFMA = [&](int buf) {
    bf16x8 af[4], bfr[4];
#pragma unroll
    for (int i = 0; i < 4; ++i) af[i] = *(const bf16x8*)&As[buf][wm + i * 16 + l16][quad * 8];
#pragma unroll
    for (int j = 0; j < 4; ++j) bfr[j] = *(const bf16x8*)&Bs[buf][wn + j * 16 + l16][quad * 8];
#pragma unroll
    for (int i = 0; i < 4; ++i)
#pragma unroll
      for (int j = 0; j < 4; ++j)
        acc[i][j] = __builtin_amdgcn_mfma_f32_16x16x32_bf16(af[i], bfr[j], acc[i][j], 0, 0, 0);
  };

  LOADA(0, aC);
  LOADB(0, 0);
  if (npe > 1) LOADA(1, aN);
  STORE(0, aC, ev0);
  __syncthreads();

  for (int kc = 0; kc < npe; ++kc) {
#pragma unroll
    for (int e = 0; e < 4; ++e) {
      const int p = (kc << 2) + e;
      const int cur = e & 1;
      const bool more = (p + 1) < NPH;
      if (more) {
        LOADB((e + 1) & 3, kc + (e == 3 ? 1 : 0));
      }
      MFMA(cur);
      if (more) {
        if (e == 3) {
#pragma unroll
          for (int z = 0; z < 16; ++z) aC[z] = aN[z];
        }
        float evn = (e == 0) ? ev1 : (e == 1) ? ev2 : (e == 2) ? ev3 : ev0;
        STORE(cur ^ 1, aC, evn);
        if (e == 3 && kc + 2 < npe) LOADA(kc + 2, aN);
      }
      __syncthreads();
    }
  }

#pragma unroll
  for (int j = 0; j < 4; ++j) {
    int col = wn + j * 16 + l16;
#pragma unroll
    for (int i = 0; i < 4; ++i) {
      int row0 = bm + wm + i * 16 + quad * 4;
      if (row0 >= M) continue;
#pragma unroll
      for (int r = 0; r < 4; ++r) {
        int row = row0 + r;
        float a = acc[i][j][r];
        float o = relu_resid ? fmaxf(a + resid[(size_t)row * 128 + col], 0.f) : a;
        out[(size_t)row * 128 + col] = o;
        if (outBf) {
          float rs = rowscale ? rowscale[row] : 1.f;
          outBf[(size_t)row * 128 + col] = f2bf(o * rs);
        }
      }
    }
  }
}

// ---------------- graph kernels ----------------
__global__ void count_kernel(const int* ei, int* deg, int E) {
  int e = blockIdx.x * blockDim.x + threadIdx.x;
  if (e >= E) return;
  atomicAdd(&deg[ei[E + e]], 1);
}

__global__ __launch_bounds__(128) void scan1_kernel(const int* __restrict__ deg,
                                                    int* __restrict__ bsum, int n) {
  __shared__ int sh[128];
  int t = threadIdx.x;
  int i = blockIdx.x * 128 + t;
  sh[t] = (i < n) ? deg[i] : 0;
  __syncthreads();
  for (int off = 64; off > 0; off >>= 1) {
    if (t < off) sh[t] += sh[t + off];
    __syncthreads();
  }
  if (t == 0) bsum[blockIdx.x] = sh[0];
}

__global__ __launch_bounds__(512) void scan2_kernel(const int* __restrict__ bsum,
                                                    int* __restrict__ boff, int nb,
                                                    int* __restrict__ startN) {
  __shared__ int sh[512];
  int t = threadIdx.x;
  int v0 = (t < nb) ? bsum[t] : 0;
  sh[t] = v0;
  __syncthreads();
  for (int off = 1; off < 512; off <<= 1) {
    int v = sh[t];
    int add = (t >= off) ? sh[t - off] : 0;
    __syncthreads();
    sh[t] = v + add;
    __syncthreads();
  }
  if (t < nb) boff[t] = sh[t] - v0;
  if (t == nb - 1) *startN = sh[t];
}

__global__ __launch_bounds__(128) void scan3_kernel(const int* __restrict__ deg,
                                                    const int* __restrict__ boff,
                                                    int* __restrict__ start,
                                                    int* __restrict__ cursor,
                                                    float* __restrict__ inv, int n) {
  __shared__ int sh[128];
  int t = threadIdx.x;
  int i = blockIdx.x * 128 + t;
  int d = (i < n) ? deg[i] : 0;
  sh[t] = d;
  __syncthreads();
  for (int off = 1; off < 128; off <<= 1) {
    int v = sh[t];
    int add = (t >= off) ? sh[t - off] : 0;
    __syncthreads();
    sh[t] = v + add;
    __syncthreads();
  }
  if (i < n) {
    int p = boff[blockIdx.x] + sh[t] - d;
    start[i] = p; cursor[i] = p;
    inv[i] = (d > 0) ? rsqrtf((float)d) : 0.f;
  }
}

// ---------------- fused gather + env-softmax (per wave: both for one node) ----------------
// 4 quarter-waves x uint4 loads x unroll-2 = 8 independent bucket->hs chains.
__global__ __launch_bounds__(256) void gather_env_kernel(
    const unsigned short* __restrict__ hs, const int* __restrict__ start,
    const int* __restrict__ bucket, const float* __restrict__ inv,
    const float* __restrict__ h, const float* __restrict__ w,
    const float* __restrict__ b,
    float* __restrict__ agg, float* __restrict__ env, int n) {
  int node = blockIdx.x * 4 + (threadIdx.x >> 6);
  if (node >= n) return;
  const int lane = threadIdx.x & 63;
  const int quarter = lane >> 4, l16 = lane & 15;
  const int f8 = l16 * 8;

  // env partials: lane handles feature dims 2*lane, 2*lane+1
  float2 hv = *(const float2*)&h[(size_t)node * 128 + 2 * lane];
  float4 w0 = *(const float4*)&w[(size_t)(2 * lane) * 4];
  float4 w1 = *(const float4*)&w[(size_t)(2 * lane + 1) * 4];
  float p0 = hv.x * w0.x + hv.y * w1.x;
  float p1 = hv.x * w0.y + hv.y * w1.y;
  float p2 = hv.x * w0.z + hv.y * w1.z;
  float p3 = hv.x * w0.w + hv.y * w1.w;

  // gather: quarter q handles edges j = s0+q, step 4; unroll-by-2 -> step 8
  int s0 = start[node], s1 = start[node + 1];
  float a0 = 0.f, a1 = 0.f, a2 = 0.f, a3 = 0.f;
  float a4 = 0.f, a5 = 0.f, a6 = 0.f, a7 = 0.f;
  int j = s0 + quarter;
  for (; j + 4 < s1; j += 8) {
    int r0 = bucket[j], r1 = bucket[j + 4];
    uint4 u0 = *(const uint4*)&hs[(size_t)r0 * 128 + f8];
    uint4 u1 = *(const uint4*)&hs[(size_t)r1 * 128 + f8];
    a0 += bfbits2f(u0.x << 16); a1 += bfbits2f(u0.x & 0xFFFF0000u);
    a2 += bfbits2f(u0.y << 16); a3 += bfbits2f(u0.y & 0xFFFF0000u);
    a4 += bfbits2f(u0.z << 16); a5 += bfbits2f(u0.z & 0xFFFF0000u);
    a6 += bfbits2f(u0.w << 16); a7 += bfbits2f(u0.w & 0xFFFF0000u);
    a0 += bfbits2f(u1.x << 16); a1 += bfbits2f(u1.x & 0xFFFF0000u);
    a2 += bfbits2f(u1.y << 16); a3 += bfbits2f(u1.y & 0xFFFF0000u);
    a4 += bfbits2f(u1.z << 16); a5 += bfbits2f(u1.z & 0xFFFF0000u);
    a6 += bfbits2f(u1.w << 16); a7 += bfbits2f(u1.w & 0xFFFF0000u);
  }
  for (; j < s1; j += 4) {
    int r = bucket[j];
    uint4 u = *(const uint4*)&hs[(size_t)r * 128 + f8];
    a0 += bfbits2f(u.x << 16); a1 += bfbits2f(u.x & 0xFFFF0000u);
    a2 += bfbits2f(u.y << 16); a3 += bfbits2f(u.y & 0xFFFF0000u);
    a4 += bfbits2f(u.z << 16); a5 += bfbits2f(u.z & 0xFFFF0000u);
    a6 += bfbits2f(u.w << 16); a7 += bfbits2f(u.w & 0xFFFF0000u);
  }

  // wave-reduce softmax partials (all 64 lanes)
#pragma unroll
  for (int s = 1; s <= 32; s <<= 1) {
    p0 += __shfl_xor(p0, s);
    p1 += __shfl_xor(p1, s);
    p2 += __shfl_xor(p2, s);
    p3 += __shfl_xor(p3, s);
  }

  // combine the 4 quarter-waves
  a0 += __shfl_xor(a0, 16); a1 += __shfl_xor(a1, 16);
  a2 += __shfl_xor(a2, 16); a3 += __shfl_xor(a3, 16);
  a4 += __shfl_xor(a4, 16); a5 += __shfl_xor(a5, 16);
  a6 += __shfl_xor(a6, 16); a7 += __shfl_xor(a7, 16);
  a0 += __shfl_xor(a0, 32); a1 += __shfl_xor(a1, 32);
  a2 += __shfl_xor(a2, 32); a3 += __shfl_xor(a3, 32);
  a4 += __shfl_xor(a4, 32); a5 += __shfl_xor(a5, 32);
  a6 += __shfl_xor(a6, 32); a7 += __shfl_xor(a7, 32);

  if (lane < 16) {
    float iv = inv[node];
    *(float4*)&agg[(size_t)node * 128 + f8] = make_float4(iv * a0, iv * a1, iv * a2, iv * a3);
    *(float4*)&agg[(size_t)node * 128 + f8 + 4] = make_float4(iv * a4, iv * a5, iv * a6, iv * a7);
  }
  if (lane == 0) {
    float l0 = p0 + b[0], l1 = p1 + b[1], l2 = p2 + b[2], l3 = p3 + b[3];
    float m = fmaxf(fmaxf(l0, l1), fmaxf(l2, l3));
    float e0 = __expf(l0 - m), e1 = __expf(l1 - m), e2 = __expf(l2 - m), e3 = __expf(l3 - m);
    float s = 1.f / (e0 + e1 + e2 + e3);
    *(float4*)&env[(size_t)node * 4] = make_float4(e0 * s, e1 * s, e2 * s, e3 * s);
  }
}

// ---------------- env softmax (standalone, for genv) ----------------
__global__ __launch_bounds__(256) void env_softmax_kernel(const float* __restrict__ h,
                                                          const float* __restrict__ w,
                                                          const float* __restrict__ b,
                                                          float* __restrict__ env, int M) {
  __shared__ float hsd[64][129];
  __shared__ float ws[HH * KK];
  int tid = threadIdx.x;
  int base = blockIdx.x * 64;
  for (int i = tid; i < HH * KK; i += 256) ws[i] = w[i];
  {
    int row = tid >> 2, q4 = (tid & 3) * 32;
    int g = base + row;
    if (g < M) {
      const float* hp = h + (size_t)g * HH + q4;
#pragma unroll
      for (int z = 0; z < 8; ++z) {
        float4 v = *(const float4*)(hp + z * 4);
        hsd[row][q4 + z * 4 + 0] = v.x; hsd[row][q4 + z * 4 + 1] = v.y;
        hsd[row][q4 + z * 4 + 2] = v.z; hsd[row][q4 + z * 4 + 3] = v.w;
      }
    }
  }
  __syncthreads();
  if (tid < 64 && base + tid < M) {
    float l0 = b[0], l1 = b[1], l2 = b[2], l3 = b[3];
    for (int d = 0; d < HH; ++d) {
      float hv = hsd[tid][d];
      l0 += hv * ws[d * 4 + 0]; l1 += hv * ws[d * 4 + 1];
      l2 += hv * ws[d * 4 + 2]; l3 += hv * ws[d * 4 + 3];
    }
    float m = fmaxf(fmaxf(l0, l1), fmaxf(l2, l3));
    float e0 = __expf(l0 - m), e1 = __expf(l1 - m), e2 = __expf(l2 - m), e3 = __expf(l3 - m);
    float s = 1.f / (e0 + e1 + e2 + e3);
    *(float4*)(env + (size_t)(base + tid) * KK) = make_float4(e0 * s, e1 * s, e2 * s, e3 * s);
  }
}

__global__ __launch_bounds__(256) void anorm_kernel(const float* q, const float* ksum,
                                                    const float* red, float* anorm, int M) {
  __shared__ float ks[HH];
  for (int i = threadIdx.x; i < HH; i += blockDim.x) ks[i] = ksum[i];
  __syncthreads();
  int n = blockIdx.x * blockDim.x + threadIdx.x;
  if (n >= M) return;
  float nq = fmaxf(sqrtf(red[0]), 1e-12f);
  float nk = fmaxf(sqrtf(red[1]), 1e-12f);
  float s2 = 1.f / (nq * nk * (float)M);
  const float* qp = q + (size_t)n * HH;
  float d = 0.f;
  for (int i = 0; i < HH; ++i) d += qp[i] * ks[i];
  float a = 1.f + d * s2;
  anorm[n] = fmaxf(a, 1e-12f);
}

// ---------------- host launcher ----------------
extern "C" void kernel_launch(void* const* d_in, const int* in_sizes, int n_in,
                              void* d_out, int out_size, void* d_ws, size_t ws_size,
                              hipStream_t stream) {
  const float* x = (const float*)d_in[0];
  const int* ei = (const int*)d_in[1];
  const float* fc0_w = (const float*)d_in[2];
  const float* fc0_b = (const float*)d_in[3];
  const float* fc1_w = (const float*)d_in[4];
  const float* fc1_b = (const float*)d_in[5];
  const float* env_w = (const float*)d_in[6];
  const float* env_b = (const float*)d_in[7];
  const float* conv_w = (const float*)d_in[8];
  const float* q_w = (const float*)d_in[9];
  const float* q_b = (const float*)d_in[10];
  const float* k_w = (const float*)d_in[11];
  const float* k_b = (const float*)d_in[12];
  const float* v_w = (const float*)d_in[13];
  const float* v_b = (const float*)d_in[14];
  const float* envp_w = (const float*)d_in[15];
  const float* envp_b = (const float*)d_in[16];
  const float* genv_w = (const float*)d_in[17];
  const float* gt_w = (const float*)d_in[18];
  const float* gt_b = (const float*)d_in[19];
  float* out = (float*)d_out;

  const size_t NH = (size_t)NN * HH;
  float* W = (float*)d_ws;
  float* hA = W;             // final h
  float* hB = W + NH;        // layer buffer -> k -> ctx
  float* agg = W + 2 * NH;   // agg -> q
  float* vbuf = W + 3 * NH;  // v -> gh
  float* gr = W + 4 * NH;
  float* env = W + 5 * NH;
  float* genv = env + (size_t)NN * KK;
  float* inv = genv + (size_t)NN * KK;
  float* anorm = inv + NN;
  float* ksum = anorm + NN;
  float* red = ksum + HH;
  int* deg = (int*)(red + 4);
  int* start = deg + NN;
  int* cursor = start + NN + 1;
  int* bucket = cursor + NN;
  int* bsum = bucket + EE;          // CSB
  int* boff = bsum + CSB;           // CSB
  unsigned short* wb = (unsigned short*)(((uintptr_t)(boff + CSB) + 15) & ~(uintptr_t)15);
  unsigned short* Btfc0 = wb;                 // 256*128
  unsigned short* Btq = Btfc0 + 32768;
  unsigned short* Btk = Btq + 16384;
  unsigned short* Btv = Btk + 16384;
  unsigned short* Btgt = Btv + 16384;
  unsigned short* Btfc1 = Btgt + 16384;       // 40*128
  unsigned short* Btconv = Btfc1 + 5120;      // 2*4*128*256
  unsigned short* Btgenv = Btconv + 262144;   // 4*128*128
  unsigned short* Btktv = Btgenv + 65536;     // 128*128
  unsigned short* kTbf = Btktv + 16384;       // 128*MP
  unsigned short* vTbf = kTbf + (size_t)HH * MP;
  unsigned short* hsb = vTbf + (size_t)HH * MP;  // NN*128 bf16 (scaled h)
  float* part = (float*)(((uintptr_t)(hsb + NH) + 15) & ~(uintptr_t)15);  // SKV*16384
  float* partK = part + (size_t)SKV * 16384;  // CSB*128
  float* partS = partK + (size_t)CSB * 128;   // CSB*2

  float* q = agg;
  float* kb = hB;
  float* ctx = hB;
  float* gh = vbuf;

  dim3 b256(256);
  const int MB = MBC;  // 391
  const int PREP_TOT = NN + HH * (MP - NN) + 32768 + 4 * 16384 + 5120 + 262144 + 65536;

  // fused prep: deg zero + pad + all weight conversions (one dispatch)
  prep_kernel<<<dim3((PREP_TOT + 255) / 256), b256, 0, stream>>>(
      deg, kTbf, vTbf, fc0_w, Btfc0, q_w, Btq, k_w, Btk, v_w, Btv,
      gt_w, Btgt, fc1_w, Btfc1, conv_w, Btconv, genv_w, Btgenv);

  // CSR build (parallel 3-phase scan)
  count_kernel<<<dim3((EE + 255) / 256), b256, 0, stream>>>(ei, deg, EE);
  scan1_kernel<<<dim3(CSB), dim3(128), 0, stream>>>(deg, bsum, NN);
  scan2_kernel<<<dim3(1), dim3(512), 0, stream>>>(bsum, boff, CSB, start + NN);
  scan3_kernel<<<dim3(CSB), dim3(128), 0, stream>>>(deg, boff, start, cursor, inv, NN);

  // fused fc0 GEMM + CSR fill (independent; fill hides under fc0's MFMA)
  fc0_fill_kernel<<<dim3(MBC + FILLB), b256, 0, stream>>>(
      x, Btfc0, fc0_b, hA, hsb, inv, ei, cursor, bucket);

  // conv layers (gather + env-softmax fused per wave; 8 load chains)
  float* hcur = hA;
  float* hnext = hB;
  for (int l = 0; l < 2; ++l) {
    gather_env_kernel<<<dim3(NN / 4), b256, 0, stream>>>(
        hsb, start, bucket, inv, hcur, env_w + (size_t)l * HH * KK,
        env_b + (size_t)l * KK, agg, env, NN);
    mconv_kernel<<<dim3(MB), b256, 0, stream>>>(
        agg, hcur, env, Btconv + (size_t)l * 131072, 256, 1, hcur, hnext,
        (l == 0) ? hsb : nullptr, inv, NN);
    float* t = hcur; hcur = hnext; hnext = t;
  }
  // hcur == hA

  // fused q/k/v: one dispatch, 3*MB blocks (k/v also emit transposed bf16)
  mgemm_qkv_kernel<<<dim3(3 * MB), b256, 0, stream>>>(
      hcur, Btq, Btk, Btv, q_b, k_b, v_b, q, kb, vbuf, kTbf, vTbf, NN);

  // fused colstats1 + ktv split-K (independent work, one dispatch)
  colstats_ktv_kernel<<<dim3(SKV + CSB), b256, 0, stream>>>(
      kTbf, vTbf, part, q, kb, partK, partS, NN);
  // fused colstats2 + ktv reduce
  reduce2_kernel<<<dim3(65), b256, 0, stream>>>(partK, partS, ksum, red, part, Btktv);
  anorm_kernel<<<dim3((NN + 255) / 256), b256, 0, stream>>>(q, ksum, red, anorm, NN);

  // gr = (v + q @ ktv * s2) / anorm   (s2 computed inline from red[0..1])
  mgemm_kernel<<<dim3(MB), b256, 0, stream>>>(
      q, nullptr, HH, Btktv, 128, 3, gr, HH, nullptr, vbuf, HH, anorm, red,
      nullptr, nullptr, nullptr, NN, HH);

  // genv = softmax(gr @ envp_w + envp_b)
  env_softmax_kernel<<<dim3((NN + 63) / 64), b256, 0, stream>>>(gr, envp_w, envp_b, genv, NN);

  // ctx = sum_k genv[:,k] * (gr @ genv_w[k])
  mconv_kernel<<<dim3(MB), b256, 0, stream>>>(
      gr, nullptr, genv, Btgenv, 128, 0, nullptr, ctx, nullptr, nullptr, NN);

  // gh = relu(ctx @ gt_w + gt_b)
  mgemm_kernel<<<dim3(MB), b256, 0, stream>>>(
      ctx, nullptr, HH, Btgt, 128, 1, gh, HH, gt_b, nullptr, 0, nullptr, nullptr,
      nullptr, nullptr, nullptr, NN, HH);

  // out = 0.5*((h+gh) @ fc1_w) + fc1_b
  mgemm_kernel<<<dim3(MB), b256, 0, stream>>>(
      hcur, gh, HH, Btfc1, 128, 5, out, CC, fc1_b, nullptr, 0, nullptr, nullptr,
      nullptr, nullptr, nullptr, NN, CC);
}